// Round 6
// baseline (583.159 us; speedup 1.0000x reference)
//
#include <hip/hip_runtime.h>
#include <hip/hip_bf16.h>

// EnhancedOFTLinearLayer: out = x @ (W @ blockdiag(cayley(R)))^T + bias
//   cayley(A): S = 0.5(A - A^T); Q = (I - S) @ inv((1+1e-6)I + S)
// Round 5: k_gemm256 K-loop software-pipelined — phase p issues ds_reads for
// phase p+1 (alternating reg sets), MFMA consumes previous phase's reads with
// compiler-auto counted lgkmcnt. Cross-tile pre-read after ph3's vmcnt+barrier.
// Everything else identical to round 4.

typedef unsigned short u16;
typedef __attribute__((ext_vector_type(8))) __bf16 bf16x8;
typedef __attribute__((ext_vector_type(4))) float f32x4;
typedef __attribute__((ext_vector_type(8))) unsigned short u16x8;
typedef __attribute__((ext_vector_type(4))) unsigned short u16x4;

#define C0   1.000001f   /* 1 + 1e-6 */
#define C1Q  2.000001f   /* 1 + C0   */
#define AS1 __attribute__((address_space(1)))
#define AS3 __attribute__((address_space(3)))

__device__ __forceinline__ u16 f2bf(float x) {
  union { float f; unsigned u; } v; v.f = x;
  return (u16)((v.u + 0x7fffu + ((v.u >> 16) & 1u)) >> 16);
}
__device__ __forceinline__ float bf2f(u16 h) {
  union { float f; unsigned u; } v; v.u = ((unsigned)h) << 16; return v.f;
}

// ---------------- 1) M = (1+1e-6)I + 0.5(R - R^T) -> bf16 hi/lo pair --------
__global__ __launch_bounds__(256) void k_build_M(const float* __restrict__ R,
                                                 u16* __restrict__ Mh,
                                                 u16* __restrict__ Ml) {
  __shared__ float t1[32][33];
  const int n = blockIdx.z;
  const int tr = blockIdx.y * 32, tc = blockIdx.x * 32;
  const int ly = threadIdx.x >> 5, lx = threadIdx.x & 31;   // 8 x 32
  const float* Rb = R + (size_t)n * 262144;
  float a[4];
#pragma unroll
  for (int i = 0; i < 4; ++i) {
    a[i] = Rb[(size_t)(tr + ly + i * 8) * 512 + tc + lx];
    t1[ly + i * 8][lx] = Rb[(size_t)(tc + ly + i * 8) * 512 + tr + lx];
  }
  __syncthreads();
#pragma unroll
  for (int i = 0; i < 4; ++i) {
    const int r = tr + ly + i * 8, c = tc + lx;
    float m = 0.5f * (a[i] - t1[lx][ly + i * 8]) + (r == c ? C0 : 0.0f);
    u16 h = f2bf(m);
    const size_t idx = (size_t)n * 262144 + (size_t)r * 512 + c;
    Mh[idx] = h;
    Ml[idx] = f2bf(m - bf2f(h));
  }
}

// ---------------- 2b) alpha[n] = 2/(c0^2 + (||G4||_F^2)^(1/8)) --------------
__global__ __launch_bounds__(1024) void k_frob_alpha(const u16* __restrict__ G4,
                                                     float* __restrict__ alpha) {
  __shared__ float red[16];
  const int n = blockIdx.x, tid = threadIdx.x;
  const u16* src = G4 + (size_t)n * 262144;
  float s = 0.f;
  for (int i = tid; i < 32768; i += 1024) {
    u16x8 v = reinterpret_cast<const u16x8*>(src)[i];
#pragma unroll
    for (int e = 0; e < 8; ++e) { float f = bf2f(v[e]); s += f * f; }
  }
  for (int off = 32; off; off >>= 1) s += __shfl_down(s, off, 64);
  if ((tid & 63) == 0) red[tid >> 6] = s;
  __syncthreads();
  if (tid == 0) {
    float t = 0.f;
    for (int q = 0; q < 16; ++q) t += red[q];
    float lam = powf(t, 0.125f);            // >= lambda_max(M^T M)
    alpha[n] = 2.0f / (C0 * C0 + lam);
  }
}

// ---------------- 3a) X0 = alpha*(2c0 I - M) ; X0^T = alpha*M ---------------
__global__ __launch_bounds__(256) void k_init_X0(const u16* __restrict__ Mh,
                                                 const u16* __restrict__ Ml,
                                                 const float* __restrict__ alpha,
                                                 u16* __restrict__ X0,
                                                 u16* __restrict__ X0t) {
  int idx = blockIdx.x * 256 + threadIdx.x;
  int n = idx >> 18, r = (idx >> 9) & 511, c = idx & 511;
  float m = bf2f(Mh[idx]) + bf2f(Ml[idx]);
  float a = alpha[n];
  X0[idx]  = f2bf(a * ((r == c ? 2.0f * C0 : 0.0f) - m));
  X0t[idx] = f2bf(a * m);
}

// ---------------- batched bf16 mm: C = cd*D + cs*(A @ B^T) ------------------
// All matrices [8][512][512] bf16 row-major; B pre-transposed (k-contiguous).
// PROD3: A,B given as hi/lo pairs -> 3-MFMA split product (~fp21).
// DMODE: 0 none, 1 D=Dh, 2 D=Dh+Dl.  OMODE bits: 1 Cnh, 2 Cnl, 4 Cth, 8 Ctl,
// 16 Cf(f32).  Transposed outputs vectorize (4 rows -> one 8B store).
template <int PROD3, int DMODE, int OMODE>
__global__ __launch_bounds__(256)
void k_bmm(const u16* __restrict__ Ah, const u16* __restrict__ Al,
           const u16* __restrict__ Bh, const u16* __restrict__ Bl,
           const u16* __restrict__ Dh, const u16* __restrict__ Dl,
           u16* __restrict__ Cnh, u16* __restrict__ Cnl,
           u16* __restrict__ Cth, u16* __restrict__ Ctl,
           float* __restrict__ Cf, float cd, float cs) {
  __shared__ __align__(16) u16 sAh[2048], sBh[2048];
  __shared__ __align__(16) u16 sAl[PROD3 ? 2048 : 8], sBl[PROD3 ? 2048 : 8];
  const size_t zb = (size_t)blockIdx.z * 262144;
  const int tid = threadIdx.x, lane = tid & 63, wave = tid >> 6;
  const int m0 = blockIdx.y * 64, n0 = blockIdx.x * 64;
  const int wr = wave >> 1, wc = wave & 1;
  const int c15 = lane & 15, lk = lane >> 4;
  const int srow = tid >> 2;
  const int sg = (tid & 3) ^ (srow & 3);            // granule-XOR (involution)
  f32x4 acc[2][2] = {};
  const u16* pa = Ah + zb + (size_t)(m0 + srow) * 512 + sg * 8;
  const u16* pb = Bh + zb + (size_t)(n0 + srow) * 512 + sg * 8;

  for (int k0 = 0; k0 < 512; k0 += 32) {
    __builtin_amdgcn_global_load_lds((const AS1 void*)(pa + k0),
                                     (AS3 void*)(sAh + (size_t)tid * 8), 16, 0, 0);
    __builtin_amdgcn_global_load_lds((const AS1 void*)(pb + k0),
                                     (AS3 void*)(sBh + (size_t)tid * 8), 16, 0, 0);
    if constexpr (PROD3) {
      const u16* pal = Al + zb + (size_t)(m0 + srow) * 512 + sg * 8;
      const u16* pbl = Bl + zb + (size_t)(n0 + srow) * 512 + sg * 8;
      __builtin_amdgcn_global_load_lds((const AS1 void*)(pal + k0),
                                       (AS3 void*)(sAl + (size_t)tid * 8), 16, 0, 0);
      __builtin_amdgcn_global_load_lds((const AS1 void*)(pbl + k0),
                                       (AS3 void*)(sBl + (size_t)tid * 8), 16, 0, 0);
    }
    __syncthreads();
    bf16x8 a[2], b[2], al2[2], bl2[2];
#pragma unroll
    for (int i = 0; i < 2; ++i) {
      const int fr = wr * 32 + i * 16 + c15;
      const int ia = fr * 32 + ((lk ^ (fr & 3)) * 8);
      a[i] = *reinterpret_cast<const bf16x8*>(&sAh[ia]);
      if constexpr (PROD3) al2[i] = *reinterpret_cast<const bf16x8*>(&sAl[ia]);
    }
#pragma unroll
    for (int j = 0; j < 2; ++j) {
      const int fc = wc * 32 + j * 16 + c15;
      const int ib = fc * 32 + ((lk ^ (fc & 3)) * 8);
      b[j] = *reinterpret_cast<const bf16x8*>(&sBh[ib]);
      if constexpr (PROD3) bl2[j] = *reinterpret_cast<const bf16x8*>(&sBl[ib]);
    }
#pragma unroll
    for (int i = 0; i < 2; ++i)
#pragma unroll
      for (int j = 0; j < 2; ++j) {
        acc[i][j] = __builtin_amdgcn_mfma_f32_16x16x32_bf16(a[i], b[j], acc[i][j], 0, 0, 0);
        if constexpr (PROD3) {
          acc[i][j] = __builtin_amdgcn_mfma_f32_16x16x32_bf16(a[i],   bl2[j], acc[i][j], 0, 0, 0);
          acc[i][j] = __builtin_amdgcn_mfma_f32_16x16x32_bf16(al2[i], b[j],   acc[i][j], 0, 0, 0);
        }
      }
    __syncthreads();
  }
  // epilogue (C/D map: col=lane&15, row=(lane>>4)*4+r)
#pragma unroll
  for (int i = 0; i < 2; ++i)
#pragma unroll
    for (int j = 0; j < 2; ++j) {
      const int rowb = m0 + wr * 32 + i * 16 + lk * 4;
      const int col  = n0 + wc * 32 + j * 16 + c15;
      u16 hv[4], lv[4];
#pragma unroll
      for (int r = 0; r < 4; ++r) {
        float val = cs * acc[i][j][r];
        if constexpr (DMODE >= 1) {
          float d = bf2f(Dh[zb + (size_t)(rowb + r) * 512 + col]);
          if constexpr (DMODE == 2) d += bf2f(Dl[zb + (size_t)(rowb + r) * 512 + col]);
          val += cd * d;
        }
        if constexpr (OMODE & 16) Cf[zb + (size_t)(rowb + r) * 512 + col] = val;
        u16 h = f2bf(val);
        if constexpr (OMODE & 1) Cnh[zb + (size_t)(rowb + r) * 512 + col] = h;
        u16 l = 0;
        if constexpr (OMODE & 10) l = f2bf(val - bf2f(h));
        if constexpr (OMODE & 2) Cnl[zb + (size_t)(rowb + r) * 512 + col] = l;
        hv[r] = h; lv[r] = l;
      }
      if constexpr (OMODE & 4) {
        u16x4 v; v[0] = hv[0]; v[1] = hv[1]; v[2] = hv[2]; v[3] = hv[3];
        *reinterpret_cast<u16x4*>(&Cth[zb + (size_t)col * 512 + rowb]) = v;
      }
      if constexpr (OMODE & 8) {
        u16x4 v; v[0] = lv[0]; v[1] = lv[1]; v[2] = lv[2]; v[3] = lv[3];
        *reinterpret_cast<u16x4*>(&Ctl[zb + (size_t)col * 512 + rowb]) = v;
      }
    }
}

// ---------------- tw = W @ blockdiag(Q): f32-in batched mm (proven) ---------
template <int SPLIT, int BF16OUT>
__global__ __launch_bounds__(256)
void k_smm(const float* __restrict__ A, int lda, long long astride,
           const float* __restrict__ B, int ldb, long long bstride,
           void* __restrict__ Cv, int ldc, long long cstride,
           const float* __restrict__ D, int ldd, long long dstride,
           float c1, float sgn, int K) {
  __shared__ __align__(16) u16 lA  [128 * 40];
  __shared__ __align__(16) u16 lBT [128 * 40];
  const int nz = blockIdx.z;
  const float* Ab = A + (size_t)nz * astride;
  const float* Bb = B + (size_t)nz * bstride;
  const float* Db = D + (size_t)nz * dstride;
  const int tid = threadIdx.x, lane = tid & 63, wave = tid >> 6;
  const int m0 = blockIdx.y * 128, n0 = blockIdx.x * 128;
  const int wr = wave >> 1, wc = wave & 1;
  f32x4 acc[4][4] = {};

  for (int k0 = 0; k0 < K; k0 += 32) {
    if (k0) __syncthreads();
    {  // stage A tile [128 x 32]
      const int row = tid >> 1, ks = (tid & 1) * 16;
      const float* src = Ab + (size_t)(m0 + row) * lda + k0 + ks;
      float fv[16];
#pragma unroll
      for (int q = 0; q < 4; ++q) {
        float4 f = *(reinterpret_cast<const float4*>(src) + q);
        fv[q * 4 + 0] = f.x; fv[q * 4 + 1] = f.y; fv[q * 4 + 2] = f.z; fv[q * 4 + 3] = f.w;
      }
      u16x8 w0, w1;
#pragma unroll
      for (int e = 0; e < 8; ++e) { w0[e] = f2bf(fv[e]); w1[e] = f2bf(fv[e + 8]); }
      *reinterpret_cast<u16x8*>(&lA[row * 40 + ks])     = w0;
      *reinterpret_cast<u16x8*>(&lA[row * 40 + ks + 8]) = w1;
    }
    {  // stage B tile transposed
      const int kk = tid >> 3, nb = (tid & 7) * 16;
      const float* src = Bb + (size_t)(k0 + kk) * ldb + n0 + nb;
      float fv[16];
#pragma unroll
      for (int q = 0; q < 4; ++q) {
        float4 f = *(reinterpret_cast<const float4*>(src) + q);
        fv[q * 4 + 0] = f.x; fv[q * 4 + 1] = f.y; fv[q * 4 + 2] = f.z; fv[q * 4 + 3] = f.w;
      }
#pragma unroll
      for (int e = 0; e < 16; ++e) lBT[(nb + e) * 40 + kk] = f2bf(fv[e]);
    }
    __syncthreads();
    const int ks = (lane >> 4) * 8;
    bf16x8 af[4], bfr[4];
#pragma unroll
    for (int f = 0; f < 4; ++f) {
      const int ar = wr * 64 + f * 16 + (lane & 15);
      const int bc = wc * 64 + f * 16 + (lane & 15);
      af[f]  = *reinterpret_cast<const bf16x8*>(&lA [ar * 40 + ks]);
      bfr[f] = *reinterpret_cast<const bf16x8*>(&lBT[bc * 40 + ks]);
    }
#pragma unroll
    for (int i = 0; i < 4; ++i)
#pragma unroll
      for (int j = 0; j < 4; ++j)
        acc[i][j] = __builtin_amdgcn_mfma_f32_16x16x32_bf16(af[i], bfr[j], acc[i][j], 0, 0, 0);
  }
#pragma unroll
  for (int i = 0; i < 4; ++i) {
    const int rowb = m0 + wr * 64 + i * 16 + ((lane >> 4) << 2);
#pragma unroll
    for (int j = 0; j < 4; ++j) {
      const int col = n0 + wc * 64 + j * 16 + (lane & 15);
#pragma unroll
      for (int r = 0; r < 4; ++r) {
        float val = sgn * acc[i][j][r];
        if (c1 != 0.0f) val += c1 * Db[(size_t)(rowb + r) * ldd + col];
        if constexpr (BF16OUT)
          reinterpret_cast<u16*>(Cv)[(size_t)nz * cstride + (size_t)(rowb + r) * ldc + col] = f2bf(val);
        else
          reinterpret_cast<float*>(Cv)[(size_t)nz * cstride + (size_t)(rowb + r) * ldc + col] = val;
      }
    }
  }
}

// ---------------- 5a) x (f32) -> bf16 ----------------
__global__ __launch_bounds__(256) void k_f32_to_bf16(const float* __restrict__ in,
                                                     u16* __restrict__ out) {
  int idx = blockIdx.x * 256 + threadIdx.x;
  const float* src = in + (size_t)idx * 8;
  float4 f0 = *reinterpret_cast<const float4*>(src);
  float4 f1 = *reinterpret_cast<const float4*>(src + 4);
  u16x8 w;
  w[0] = f2bf(f0.x); w[1] = f2bf(f0.y); w[2] = f2bf(f0.z); w[3] = f2bf(f0.w);
  w[4] = f2bf(f1.x); w[5] = f2bf(f1.y); w[6] = f2bf(f1.z); w[7] = f2bf(f1.w);
  *reinterpret_cast<u16x8*>(out + (size_t)idx * 8) = w;
}

// ---------------- 5b) out = x_bf @ tw^T + bias (256^2 pipelined 4-phase) ----
// Phase p issues ds_reads for phase p+1 (alternating reg sets afA/afB,
// bf0/bf1); MFMA consumes previous phase's reads (compiler-auto lgkmcnt).
// ph3: stage, vmcnt, barrier, pre-read next tile's ph0 frags, MFMA, barrier.
#define NSLOT 9

#define RD_B(dst, G)                                                           \
  _Pragma("unroll")                                                            \
  for (int n = 0; n < 4; ++n)                                                  \
    dst[n] = *reinterpret_cast<const bf16x8*>(                                 \
        &lds[bslot * 8192 + (bro + n * 16) * 64 + (G) * 8]);

#define RD_A(dst, MH, G)                                                       \
  _Pragma("unroll")                                                            \
  for (int m = 0; m < 4; ++m)                                                  \
    dst[m] = *reinterpret_cast<const bf16x8*>(                                 \
        &lds[aslot * 8192 + ((MH) * 64 + m * 16 + c15) * 64 + (G) * 8]);

#define MFMA16(afX, bfX, MH)                                                   \
  __builtin_amdgcn_s_setprio(1);                                               \
  _Pragma("unroll")                                                            \
  for (int m = 0; m < 4; ++m)                                                  \
    _Pragma("unroll")                                                          \
    for (int n = 0; n < 4; ++n)                                                \
      acc[(MH) * 4 + m][n] = __builtin_amdgcn_mfma_f32_16x16x32_bf16(          \
          afX[m], bfX[n], acc[(MH) * 4 + m][n], 0, 0, 0);                      \
  __builtin_amdgcn_s_setprio(0);                                               \
  __builtin_amdgcn_sched_barrier(0);

#define SBAR() __builtin_amdgcn_s_barrier();
#define SCHB() __builtin_amdgcn_sched_barrier(0);

// WM: 1 = vmcnt(2) (steady), 2 = vmcnt(0) (drain at NT-2), 0 = none (last).
// LAST: skip the cross-tile pre-read.
#define TILEBODY(WM, LAST)                                                     \
  { /* ph0: MFMA(afA,bf0,MH0); read afB for ph1 */                             \
    STAGE();                                                                   \
    RD_A(afB, 1, gsA)                                                          \
    SCHB()                                                                     \
    MFMA16(afA, bf0, 0)                                                        \
    SBAR()                                                                     \
    /* ph1: MFMA(afB,bf0,MH1); read bf1,afA for ph2 */                         \
    STAGE();                                                                   \
    RD_B(bf1, gsB)                                                             \
    RD_A(afA, 0, gsB)                                                          \
    SCHB()                                                                     \
    MFMA16(afB, bf0, 1)                                                        \
    SBAR()                                                                     \
    /* ph2: MFMA(afA,bf1,MH0); read afB for ph3 */                             \
    STAGE();                                                                   \
    RD_A(afB, 1, gsB)                                                          \
    SCHB()                                                                     \
    MFMA16(afA, bf1, 0)                                                        \
    SBAR()                                                                     \
    /* ph3: stage, vmcnt, bar, pre-read next ph0, MFMA(afB,bf1,MH1), bar */    \
    STAGE();                                                                   \
    if ((WM) == 1) { asm volatile("s_waitcnt vmcnt(2)" ::: "memory"); SCHB() } \
    if ((WM) == 2) { asm volatile("s_waitcnt vmcnt(0)" ::: "memory"); SCHB() } \
    SBAR()                                                                     \
    ADV()                                                                      \
    if (!(LAST)) { RD_B(bf0, gsA) RD_A(afA, 0, gsA) }                          \
    SCHB()                                                                     \
    MFMA16(afB, bf1, 1)                                                        \
    SBAR()                                                                     \
  }

#define ADV()                                                                  \
  aslot += 4; if (aslot >= NSLOT) aslot -= NSLOT;                              \
  bslot += 4; if (bslot >= NSLOT) bslot -= NSLOT;

__global__ __launch_bounds__(512, 2)
void k_gemm256(const u16* __restrict__ A, const u16* __restrict__ B,
               const float* __restrict__ bias,
               float* __restrict__ C, int N, int K) {
  __shared__ __align__(16) u16 lds[NSLOT * 8192];   // 144 KiB
  const int tid = threadIdx.x, lane = tid & 63, wave = tid >> 6;
  int bid = blockIdx.y * gridDim.x + blockIdx.x;
  const int cpx = (gridDim.x * gridDim.y) >> 3;
  bid = (bid & 7) * cpx + (bid >> 3);
  const int nbx = N >> 8;
  const int bx = bid % nbx, by = bid / nbx;
  const int m0 = by << 8, n0 = bx << 8;
  const int wr = wave >> 2, wc = wave & 3;
  const int srow = tid >> 3;
  const int scg  = (tid & 7) ^ (srow & 7);
  const int c15 = lane & 15, lq = lane >> 4;
  const int gs0 = lq ^ (lane & 7);
  const int gsA = gs0, gsB = gs0 ^ 4;
  const int bro = (wc & 1) * 64 + c15;
  const int NT = K >> 6;

  f32x4 acc[8][4] = {};
  bf16x8 afA[4], afB[4], bf0[4], bf1[4];

  int jn = 0, jslot = 0;
  auto STAGE = [&]() {
    if (jn < 4 * NT) {
      const int tau_s = jn >> 2, qh = jn & 3;
      const u16* srcb = (qh < 2)
          ? A + (size_t)(m0 + (qh & 1) * 128 + srow) * (size_t)K
          : B + (size_t)(n0 + (qh & 1) * 128 + srow) * (size_t)K;
      const u16* src = srcb + (tau_s << 6) + scg * 8;
      u16* dst = (u16*)lds + jslot * 8192 + wave * 512;
      __builtin_amdgcn_global_load_lds(
          (const AS1 void*)src, (AS3 void*)dst, 16, 0, 0);
      __builtin_amdgcn_global_load_lds(
          (const AS1 void*)(src + (size_t)64 * K), (AS3 void*)(dst + 4096), 16, 0, 0);
    }
    ++jn; jslot = (jslot == NSLOT - 1) ? 0 : jslot + 1;
  };

  // prologue: tile0 (4 halves) + tile1 A0,A1 staged; wait tile0; pre-read ph0
  STAGE(); STAGE(); STAGE(); STAGE(); STAGE(); STAGE();
  asm volatile("s_waitcnt vmcnt(4)" ::: "memory");
  SCHB()
  SBAR()
  int aslot = wr, bslot = 2 + (wc >> 1);
  RD_B(bf0, gsA)
  RD_A(afA, 0, gsA)
  SCHB()

  for (int tau = 0; tau < NT - 2; ++tau) {
    TILEBODY(1, 0)
  }
  TILEBODY(2, 0)
  TILEBODY(0, 1)

  // epilogue: C = acc + bias
#pragma unroll
  for (int n = 0; n < 4; ++n) {
    const int col = n0 + wc * 64 + n * 16 + c15;
    const float bv = bias[col];
#pragma unroll
    for (int mi = 0; mi < 8; ++mi) {
      const int rowb = m0 + wr * 128 + mi * 16 + (lq << 2);
#pragma unroll
      for (int r = 0; r < 4; ++r)
        C[(size_t)(rowb + r) * N + col] = acc[mi][n][r] + bv;
    }
  }
}

extern "C" void kernel_launch(void* const* d_in, const int* in_sizes, int n_in,
                              void* d_out, int out_size, void* d_ws, size_t ws_size,
                              hipStream_t stream) {
  const float* W    = (const float*)d_in[0];   // [4096,4096]
  const float* bias = (const float*)d_in[1];   // [4096]
  const float* x    = (const float*)d_in[2];   // [4,2048,4096]
  const float* R    = (const float*)d_in[3];   // [8,512,512]
  float* out = (float*)d_out;

  char* ws = (char*)d_ws;
  u16* x_bf = (u16*)(ws);                      //  64 MiB
  u16* tw   = (u16*)(ws + 67108864);           //  32 MiB

  // scratch arena = d_out (128 MiB; fully overwritten by k_gemm256 at the end)
  char* arena = (char*)d_out;
  auto slot = [&](int i) -> u16* { return (u16*)(arena + (size_t)i * 4194304); };
  u16 *Mh = slot(0), *Ml = slot(1);
  u16 *G = slot(2), *G2 = slot(3), *G4 = slot(4);
  u16 *Xa = slot(5), *Xat = slot(6), *Xb = slot(7), *Xbt = slot(8);
  u16 *Xbl = slot(9), *Xbtl = slot(10);
  u16 *Tt = slot(2);                            // reuse G
  u16 *Tth = slot(3), *Ttl = slot(4);           // reuse G2, G4
  u16 *X6h = slot(5), *X6l = slot(6);           // reuse Xa/Xat (dead)
  u16 *X6th = slot(11), *X6tl = slot(12);
  float* Qf = (float*)(arena + (size_t)13 * 4194304);   // 8 MiB (slots 13-14)
  float* alpha = (float*)(arena + (size_t)15 * 4194304);

  const long long BS2 = 262144;
  const dim3 g8(8, 8, 8);
  const u16* NUL = nullptr;

  // 1) M pair
  k_build_M<<<dim3(16, 16, 8), 256, 0, stream>>>(R, Mh, Ml);
  // 2) G = M@M^T ; G2 = G@G^T ; G4 = G2@G2^T ; alpha from tr(G^8)
  k_bmm<0, 0, 1><<<g8, 256, 0, stream>>>(Mh, NUL, Mh, NUL, NUL, NUL,
                                         G, nullptr, nullptr, nullptr, nullptr, 0.f, 1.f);
  k_bmm<0, 0, 1><<<g8, 256, 0, stream>>>(G, NUL, G, NUL, NUL, NUL,
                                         G2, nullptr, nullptr, nullptr, nullptr, 0.f, 1.f);
  k_bmm<0, 0, 1><<<g8, 256, 0, stream>>>(G2, NUL, G2, NUL, NUL, NUL,
                                         G4, nullptr, nullptr, nullptr, nullptr, 0.f, 1.f);
  k_frob_alpha<<<8, 1024, 0, stream>>>(G4, alpha);
  // 3) X0 pair
  k_init_X0<<<8192, 256, 0, stream>>>(Mh, Ml, alpha, Xa, Xat);

  // 4) Newton iters 1-4 (bf16): T^T = (M@X)^T ; X' = 2X - X@T (+X'^T)
  u16 *cur = Xa, *curt = Xat, *nxt = Xb, *nxtt = Xbt;
  for (int it = 0; it < 4; ++it) {
    k_bmm<0, 0, 4><<<g8, 256, 0, stream>>>(Mh, NUL, curt, NUL, NUL, NUL,
                                           nullptr, nullptr, Tt, nullptr, nullptr, 0.f, 1.f);
    k_bmm<0, 1, 5><<<g8, 256, 0, stream>>>(cur, NUL, Tt, NUL, cur, NUL,
                                           nxt, nullptr, nxtt, nullptr, nullptr, 2.f, -1.f);
    u16* t;
    t = cur; cur = nxt; nxt = t;
    t = curt; curt = nxtt; nxtt = t;
  }
  // iter 5: write hi/lo pairs (normal + transposed)   [cur==Xa here]
  k_bmm<0, 0, 4><<<g8, 256, 0, stream>>>(Mh, NUL, curt, NUL, NUL, NUL,
                                         nullptr, nullptr, Tt, nullptr, nullptr, 0.f, 1.f);
  k_bmm<0, 1, 15><<<g8, 256, 0, stream>>>(cur, NUL, Tt, NUL, cur, NUL,
                                          Xb, Xbl, Xbt, Xbtl, nullptr, 2.f, -1.f);
  // 5) split-precision polish: T^T pair ; X6 = 2X5 - X5@T (pairs)
  k_bmm<1, 0, 12><<<g8, 256, 0, stream>>>(Mh, Ml, Xbt, Xbtl, NUL, NUL,
                                          nullptr, nullptr, Tth, Ttl, nullptr, 0.f, 1.f);
  k_bmm<1, 2, 15><<<g8, 256, 0, stream>>>(Xb, Xbl, Tth, Ttl, Xb, Xbl,
                                          X6h, X6l, X6th, X6tl, nullptr, 2.f, -1.f);
  // 6) Q = (2+1e-6)X6 - M@X6  (f32 out for tw)
  k_bmm<1, 2, 16><<<g8, 256, 0, stream>>>(Mh, Ml, X6th, X6tl, X6h, X6l,
                                          nullptr, nullptr, nullptr, nullptr, Qf, C1Q, -1.f);
  // 7) tw = W @ blockdiag(Q)
  k_smm<0, 1><<<dim3(4, 32, 8), 256, 0, stream>>>(W, 4096, 512, Qf, 512, BS2,
                                                  tw, 4096, 512, W, 4096, 512, 0.f, 1.f, 512);
  // 8) x -> bf16 ; main GEMM (overwrites the arena)
  k_f32_to_bf16<<<16384, 256, 0, stream>>>(x, x_bf);
  k_gemm256<<<dim3(16, 32), 512, 0, stream>>>(x_bf, tw, bias, out, 4096, 4096);
}

// Round 7
// 574.773 us; speedup vs baseline: 1.0146x; 1.0146x over previous
//
#include <hip/hip_runtime.h>
#include <hip/hip_bf16.h>

// EnhancedOFTLinearLayer: out = x @ (W @ blockdiag(cayley(R)))^T + bias
//   cayley(A): S = 0.5(A - A^T); Q = (I - S) @ inv((1+1e-6)I + S)
// Round 6: k_gemm256 -> BK=32, 18-slot LDS ring (144 KiB), 3-tile prefetch
// lead, one barrier + one counted vmcnt(8) per K-tile. Reads same-phase
// (round-4 style; compiler auto-lgkmcnt). Granule XOR uses (row>>1)&3 for
// 64-B rows -> 2-way bank aliasing (free). Rest identical to round 4.

typedef unsigned short u16;
typedef __attribute__((ext_vector_type(8))) __bf16 bf16x8;
typedef __attribute__((ext_vector_type(4))) float f32x4;
typedef __attribute__((ext_vector_type(8))) unsigned short u16x8;
typedef __attribute__((ext_vector_type(4))) unsigned short u16x4;

#define C0   1.000001f   /* 1 + 1e-6 */
#define C1Q  2.000001f   /* 1 + C0   */
#define AS1 __attribute__((address_space(1)))
#define AS3 __attribute__((address_space(3)))

__device__ __forceinline__ u16 f2bf(float x) {
  union { float f; unsigned u; } v; v.f = x;
  return (u16)((v.u + 0x7fffu + ((v.u >> 16) & 1u)) >> 16);
}
__device__ __forceinline__ float bf2f(u16 h) {
  union { float f; unsigned u; } v; v.u = ((unsigned)h) << 16; return v.f;
}

// ---------------- 1) M = (1+1e-6)I + 0.5(R - R^T) -> bf16 hi/lo pair --------
__global__ __launch_bounds__(256) void k_build_M(const float* __restrict__ R,
                                                 u16* __restrict__ Mh,
                                                 u16* __restrict__ Ml) {
  __shared__ float t1[32][33];
  const int n = blockIdx.z;
  const int tr = blockIdx.y * 32, tc = blockIdx.x * 32;
  const int ly = threadIdx.x >> 5, lx = threadIdx.x & 31;   // 8 x 32
  const float* Rb = R + (size_t)n * 262144;
  float a[4];
#pragma unroll
  for (int i = 0; i < 4; ++i) {
    a[i] = Rb[(size_t)(tr + ly + i * 8) * 512 + tc + lx];
    t1[ly + i * 8][lx] = Rb[(size_t)(tc + ly + i * 8) * 512 + tr + lx];
  }
  __syncthreads();
#pragma unroll
  for (int i = 0; i < 4; ++i) {
    const int r = tr + ly + i * 8, c = tc + lx;
    float m = 0.5f * (a[i] - t1[lx][ly + i * 8]) + (r == c ? C0 : 0.0f);
    u16 h = f2bf(m);
    const size_t idx = (size_t)n * 262144 + (size_t)r * 512 + c;
    Mh[idx] = h;
    Ml[idx] = f2bf(m - bf2f(h));
  }
}

// ---------------- 2b) alpha[n] = 2/(c0^2 + (||G4||_F^2)^(1/8)) --------------
__global__ __launch_bounds__(1024) void k_frob_alpha(const u16* __restrict__ G4,
                                                     float* __restrict__ alpha) {
  __shared__ float red[16];
  const int n = blockIdx.x, tid = threadIdx.x;
  const u16* src = G4 + (size_t)n * 262144;
  float s = 0.f;
  for (int i = tid; i < 32768; i += 1024) {
    u16x8 v = reinterpret_cast<const u16x8*>(src)[i];
#pragma unroll
    for (int e = 0; e < 8; ++e) { float f = bf2f(v[e]); s += f * f; }
  }
  for (int off = 32; off; off >>= 1) s += __shfl_down(s, off, 64);
  if ((tid & 63) == 0) red[tid >> 6] = s;
  __syncthreads();
  if (tid == 0) {
    float t = 0.f;
    for (int q = 0; q < 16; ++q) t += red[q];
    float lam = powf(t, 0.125f);            // >= lambda_max(M^T M)
    alpha[n] = 2.0f / (C0 * C0 + lam);
  }
}

// ---------------- 3a) X0 = alpha*(2c0 I - M) ; X0^T = alpha*M ---------------
__global__ __launch_bounds__(256) void k_init_X0(const u16* __restrict__ Mh,
                                                 const u16* __restrict__ Ml,
                                                 const float* __restrict__ alpha,
                                                 u16* __restrict__ X0,
                                                 u16* __restrict__ X0t) {
  int idx = blockIdx.x * 256 + threadIdx.x;
  int n = idx >> 18, r = (idx >> 9) & 511, c = idx & 511;
  float m = bf2f(Mh[idx]) + bf2f(Ml[idx]);
  float a = alpha[n];
  X0[idx]  = f2bf(a * ((r == c ? 2.0f * C0 : 0.0f) - m));
  X0t[idx] = f2bf(a * m);
}

// ---------------- batched bf16 mm: C = cd*D + cs*(A @ B^T) ------------------
// All matrices [8][512][512] bf16 row-major; B pre-transposed (k-contiguous).
// PROD3: A,B given as hi/lo pairs -> 3-MFMA split product (~fp21).
// DMODE: 0 none, 1 D=Dh, 2 D=Dh+Dl.  OMODE bits: 1 Cnh, 2 Cnl, 4 Cth, 8 Ctl,
// 16 Cf(f32).  Transposed outputs vectorize (4 rows -> one 8B store).
template <int PROD3, int DMODE, int OMODE>
__global__ __launch_bounds__(256)
void k_bmm(const u16* __restrict__ Ah, const u16* __restrict__ Al,
           const u16* __restrict__ Bh, const u16* __restrict__ Bl,
           const u16* __restrict__ Dh, const u16* __restrict__ Dl,
           u16* __restrict__ Cnh, u16* __restrict__ Cnl,
           u16* __restrict__ Cth, u16* __restrict__ Ctl,
           float* __restrict__ Cf, float cd, float cs) {
  __shared__ __align__(16) u16 sAh[2048], sBh[2048];
  __shared__ __align__(16) u16 sAl[PROD3 ? 2048 : 8], sBl[PROD3 ? 2048 : 8];
  const size_t zb = (size_t)blockIdx.z * 262144;
  const int tid = threadIdx.x, lane = tid & 63, wave = tid >> 6;
  const int m0 = blockIdx.y * 64, n0 = blockIdx.x * 64;
  const int wr = wave >> 1, wc = wave & 1;
  const int c15 = lane & 15, lk = lane >> 4;
  const int srow = tid >> 2;
  const int sg = (tid & 3) ^ (srow & 3);            // granule-XOR (involution)
  f32x4 acc[2][2] = {};
  const u16* pa = Ah + zb + (size_t)(m0 + srow) * 512 + sg * 8;
  const u16* pb = Bh + zb + (size_t)(n0 + srow) * 512 + sg * 8;

  for (int k0 = 0; k0 < 512; k0 += 32) {
    __builtin_amdgcn_global_load_lds((const AS1 void*)(pa + k0),
                                     (AS3 void*)(sAh + (size_t)tid * 8), 16, 0, 0);
    __builtin_amdgcn_global_load_lds((const AS1 void*)(pb + k0),
                                     (AS3 void*)(sBh + (size_t)tid * 8), 16, 0, 0);
    if constexpr (PROD3) {
      const u16* pal = Al + zb + (size_t)(m0 + srow) * 512 + sg * 8;
      const u16* pbl = Bl + zb + (size_t)(n0 + srow) * 512 + sg * 8;
      __builtin_amdgcn_global_load_lds((const AS1 void*)(pal + k0),
                                       (AS3 void*)(sAl + (size_t)tid * 8), 16, 0, 0);
      __builtin_amdgcn_global_load_lds((const AS1 void*)(pbl + k0),
                                       (AS3 void*)(sBl + (size_t)tid * 8), 16, 0, 0);
    }
    __syncthreads();
    bf16x8 a[2], b[2], al2[2], bl2[2];
#pragma unroll
    for (int i = 0; i < 2; ++i) {
      const int fr = wr * 32 + i * 16 + c15;
      const int ia = fr * 32 + ((lk ^ (fr & 3)) * 8);
      a[i] = *reinterpret_cast<const bf16x8*>(&sAh[ia]);
      if constexpr (PROD3) al2[i] = *reinterpret_cast<const bf16x8*>(&sAl[ia]);
    }
#pragma unroll
    for (int j = 0; j < 2; ++j) {
      const int fc = wc * 32 + j * 16 + c15;
      const int ib = fc * 32 + ((lk ^ (fc & 3)) * 8);
      b[j] = *reinterpret_cast<const bf16x8*>(&sBh[ib]);
      if constexpr (PROD3) bl2[j] = *reinterpret_cast<const bf16x8*>(&sBl[ib]);
    }
#pragma unroll
    for (int i = 0; i < 2; ++i)
#pragma unroll
      for (int j = 0; j < 2; ++j) {
        acc[i][j] = __builtin_amdgcn_mfma_f32_16x16x32_bf16(a[i], b[j], acc[i][j], 0, 0, 0);
        if constexpr (PROD3) {
          acc[i][j] = __builtin_amdgcn_mfma_f32_16x16x32_bf16(a[i],   bl2[j], acc[i][j], 0, 0, 0);
          acc[i][j] = __builtin_amdgcn_mfma_f32_16x16x32_bf16(al2[i], b[j],   acc[i][j], 0, 0, 0);
        }
      }
    __syncthreads();
  }
  // epilogue (C/D map: col=lane&15, row=(lane>>4)*4+r)
#pragma unroll
  for (int i = 0; i < 2; ++i)
#pragma unroll
    for (int j = 0; j < 2; ++j) {
      const int rowb = m0 + wr * 32 + i * 16 + lk * 4;
      const int col  = n0 + wc * 32 + j * 16 + c15;
      u16 hv[4], lv[4];
#pragma unroll
      for (int r = 0; r < 4; ++r) {
        float val = cs * acc[i][j][r];
        if constexpr (DMODE >= 1) {
          float d = bf2f(Dh[zb + (size_t)(rowb + r) * 512 + col]);
          if constexpr (DMODE == 2) d += bf2f(Dl[zb + (size_t)(rowb + r) * 512 + col]);
          val += cd * d;
        }
        if constexpr (OMODE & 16) Cf[zb + (size_t)(rowb + r) * 512 + col] = val;
        u16 h = f2bf(val);
        if constexpr (OMODE & 1) Cnh[zb + (size_t)(rowb + r) * 512 + col] = h;
        u16 l = 0;
        if constexpr (OMODE & 10) l = f2bf(val - bf2f(h));
        if constexpr (OMODE & 2) Cnl[zb + (size_t)(rowb + r) * 512 + col] = l;
        hv[r] = h; lv[r] = l;
      }
      if constexpr (OMODE & 4) {
        u16x4 v; v[0] = hv[0]; v[1] = hv[1]; v[2] = hv[2]; v[3] = hv[3];
        *reinterpret_cast<u16x4*>(&Cth[zb + (size_t)col * 512 + rowb]) = v;
      }
      if constexpr (OMODE & 8) {
        u16x4 v; v[0] = lv[0]; v[1] = lv[1]; v[2] = lv[2]; v[3] = lv[3];
        *reinterpret_cast<u16x4*>(&Ctl[zb + (size_t)col * 512 + rowb]) = v;
      }
    }
}

// ---------------- tw = W @ blockdiag(Q): f32-in batched mm (proven) ---------
template <int SPLIT, int BF16OUT>
__global__ __launch_bounds__(256)
void k_smm(const float* __restrict__ A, int lda, long long astride,
           const float* __restrict__ B, int ldb, long long bstride,
           void* __restrict__ Cv, int ldc, long long cstride,
           const float* __restrict__ D, int ldd, long long dstride,
           float c1, float sgn, int K) {
  __shared__ __align__(16) u16 lA  [128 * 40];
  __shared__ __align__(16) u16 lBT [128 * 40];
  const int nz = blockIdx.z;
  const float* Ab = A + (size_t)nz * astride;
  const float* Bb = B + (size_t)nz * bstride;
  const float* Db = D + (size_t)nz * dstride;
  const int tid = threadIdx.x, lane = tid & 63, wave = tid >> 6;
  const int m0 = blockIdx.y * 128, n0 = blockIdx.x * 128;
  const int wr = wave >> 1, wc = wave & 1;
  f32x4 acc[4][4] = {};

  for (int k0 = 0; k0 < K; k0 += 32) {
    if (k0) __syncthreads();
    {  // stage A tile [128 x 32]
      const int row = tid >> 1, ks = (tid & 1) * 16;
      const float* src = Ab + (size_t)(m0 + row) * lda + k0 + ks;
      float fv[16];
#pragma unroll
      for (int q = 0; q < 4; ++q) {
        float4 f = *(reinterpret_cast<const float4*>(src) + q);
        fv[q * 4 + 0] = f.x; fv[q * 4 + 1] = f.y; fv[q * 4 + 2] = f.z; fv[q * 4 + 3] = f.w;
      }
      u16x8 w0, w1;
#pragma unroll
      for (int e = 0; e < 8; ++e) { w0[e] = f2bf(fv[e]); w1[e] = f2bf(fv[e + 8]); }
      *reinterpret_cast<u16x8*>(&lA[row * 40 + ks])     = w0;
      *reinterpret_cast<u16x8*>(&lA[row * 40 + ks + 8]) = w1;
    }
    {  // stage B tile transposed
      const int kk = tid >> 3, nb = (tid & 7) * 16;
      const float* src = Bb + (size_t)(k0 + kk) * ldb + n0 + nb;
      float fv[16];
#pragma unroll
      for (int q = 0; q < 4; ++q) {
        float4 f = *(reinterpret_cast<const float4*>(src) + q);
        fv[q * 4 + 0] = f.x; fv[q * 4 + 1] = f.y; fv[q * 4 + 2] = f.z; fv[q * 4 + 3] = f.w;
      }
#pragma unroll
      for (int e = 0; e < 16; ++e) lBT[(nb + e) * 40 + kk] = f2bf(fv[e]);
    }
    __syncthreads();
    const int ks = (lane >> 4) * 8;
    bf16x8 af[4], bfr[4];
#pragma unroll
    for (int f = 0; f < 4; ++f) {
      const int ar = wr * 64 + f * 16 + (lane & 15);
      const int bc = wc * 64 + f * 16 + (lane & 15);
      af[f]  = *reinterpret_cast<const bf16x8*>(&lA [ar * 40 + ks]);
      bfr[f] = *reinterpret_cast<const bf16x8*>(&lBT[bc * 40 + ks]);
    }
#pragma unroll
    for (int i = 0; i < 4; ++i)
#pragma unroll
      for (int j = 0; j < 4; ++j)
        acc[i][j] = __builtin_amdgcn_mfma_f32_16x16x32_bf16(af[i], bfr[j], acc[i][j], 0, 0, 0);
  }
#pragma unroll
  for (int i = 0; i < 4; ++i) {
    const int rowb = m0 + wr * 64 + i * 16 + ((lane >> 4) << 2);
#pragma unroll
    for (int j = 0; j < 4; ++j) {
      const int col = n0 + wc * 64 + j * 16 + (lane & 15);
#pragma unroll
      for (int r = 0; r < 4; ++r) {
        float val = sgn * acc[i][j][r];
        if (c1 != 0.0f) val += c1 * Db[(size_t)(rowb + r) * ldd + col];
        if constexpr (BF16OUT)
          reinterpret_cast<u16*>(Cv)[(size_t)nz * cstride + (size_t)(rowb + r) * ldc + col] = f2bf(val);
        else
          reinterpret_cast<float*>(Cv)[(size_t)nz * cstride + (size_t)(rowb + r) * ldc + col] = val;
      }
    }
  }
}

// ---------------- 5a) x (f32) -> bf16 ----------------
__global__ __launch_bounds__(256) void k_f32_to_bf16(const float* __restrict__ in,
                                                     u16* __restrict__ out) {
  int idx = blockIdx.x * 256 + threadIdx.x;
  const float* src = in + (size_t)idx * 8;
  float4 f0 = *reinterpret_cast<const float4*>(src);
  float4 f1 = *reinterpret_cast<const float4*>(src + 4);
  u16x8 w;
  w[0] = f2bf(f0.x); w[1] = f2bf(f0.y); w[2] = f2bf(f0.z); w[3] = f2bf(f0.w);
  w[4] = f2bf(f1.x); w[5] = f2bf(f1.y); w[6] = f2bf(f1.z); w[7] = f2bf(f1.w);
  *reinterpret_cast<u16x8*>(out + (size_t)idx * 8) = w;
}

// ---------------- 5b) out = x_bf @ tw^T + bias ------------------------------
// 256x256 tile, BK=32, 8 waves (2Mx4N), 18-slot ring of 8 KiB half-tiles,
// 3-tile prefetch lead, 1 barrier + 1 counted vmcnt per K-tile.
#define NSL 18

#define RD_A3(dst, MH)                                                         \
  _Pragma("unroll")                                                            \
  for (int m = 0; m < 4; ++m)                                                  \
    dst[m] = *reinterpret_cast<const bf16x8*>(                                 \
        &lds[aslot * 4096 + ((MH) * 64 + m * 16 + c15) * 32 + gsw * 8]);

#define RD_B3(dst)                                                             \
  _Pragma("unroll")                                                            \
  for (int n = 0; n < 4; ++n)                                                  \
    dst[n] = *reinterpret_cast<const bf16x8*>(                                 \
        &lds[bslot * 4096 + (bq64 + n * 16 + c15) * 32 + gsw * 8]);

#define MFMA16(afX, bfX, MH)                                                   \
  __builtin_amdgcn_s_setprio(1);                                               \
  _Pragma("unroll")                                                            \
  for (int m = 0; m < 4; ++m)                                                  \
    _Pragma("unroll")                                                          \
    for (int n = 0; n < 4; ++n)                                                \
      acc[(MH) * 4 + m][n] = __builtin_amdgcn_mfma_f32_16x16x32_bf16(          \
          afX[m], bfX[n], acc[(MH) * 4 + m][n], 0, 0, 0);                      \
  __builtin_amdgcn_s_setprio(0);

// WM: 1 steady vmcnt(8) | 2 vmcnt(4) | 3 vmcnt(0) | 0 none (last tile)
#define TILE32(WM)                                                             \
  {                                                                            \
    int aslot = s0 + wr;            if (aslot >= NSL) aslot -= NSL;            \
    int bslot = s0 + 2 + (wc >> 1); if (bslot >= NSL) bslot -= NSL;            \
    STAGE(); STAGE();                                                          \
    RD_B3(bfr)                                                                 \
    RD_A3(afA, 0)                                                              \
    MFMA16(afA, bfr, 0)                                                        \
    STAGE(); STAGE();                                                          \
    RD_A3(afB, 1)                                                              \
    MFMA16(afB, bfr, 1)                                                        \
    if ((WM) == 1) asm volatile("s_waitcnt vmcnt(8)" ::: "memory");            \
    if ((WM) == 2) asm volatile("s_waitcnt vmcnt(4)" ::: "memory");            \
    if ((WM) == 3) asm volatile("s_waitcnt vmcnt(0)" ::: "memory");            \
    if ((WM) != 0) {                                                           \
      __builtin_amdgcn_s_barrier();                                            \
      __builtin_amdgcn_sched_barrier(0);                                       \
    }                                                                          \
    s0 += 4; if (s0 >= NSL) s0 -= NSL;                                         \
  }

__global__ __launch_bounds__(512, 2)
void k_gemm256(const u16* __restrict__ A, const u16* __restrict__ B,
               const float* __restrict__ bias,
               float* __restrict__ C, int N, int K) {
  __shared__ __align__(16) u16 lds[NSL * 4096];   // 144 KiB
  const int tid = threadIdx.x, lane = tid & 63, wave = tid >> 6;
  // T1: XCD-aware bijective swizzle (nwg = 512, divisible by 8)
  int bid = blockIdx.y * gridDim.x + blockIdx.x;
  const int cpx = (gridDim.x * gridDim.y) >> 3;
  bid = (bid & 7) * cpx + (bid >> 3);
  const int nbx = N >> 8;
  const int bx = bid % nbx, by = bid / nbx;
  const int m0 = by << 8, n0 = bx << 8;
  const int wr = wave >> 2, wc = wave & 3;          // 2 x 4 wave grid
  // staging: srow in [0,128), source granule XOR (involution)
  const int srow = tid >> 2;
  const int sgc  = (tid & 3) ^ ((srow >> 1) & 3);
  // reads: per-lane constant swizzled granule
  const int c15 = lane & 15, lq = lane >> 4;
  const int gsw = lq ^ ((c15 >> 1) & 3);
  const int bq64 = (wc & 1) * 64;
  const int NT = K >> 5;                            // 128

  f32x4 acc[8][4] = {};
  bf16x8 afA[4], afB[4], bfr[4];

  int jn = 0, js = 0;
  auto STAGE = [&]() {
    if (jn < 4 * NT) {
      const int t = jn >> 2, q = jn & 3;
      const u16* srcb = (q < 2)
          ? A + (size_t)(m0 + q * 128 + srow) * (size_t)K
          : B + (size_t)(n0 + (q - 2) * 128 + srow) * (size_t)K;
      const u16* src = srcb + (t << 5) + sgc * 8;
      u16* dst = (u16*)lds + js * 4096 + tid * 8;
      __builtin_amdgcn_global_load_lds(
          (const AS1 void*)src, (AS3 void*)dst, 16, 0, 0);
    }
    ++jn; js = (js == NSL - 1) ? 0 : js + 1;
  };

  // prologue: stage tiles 0,1,2 (12 stages); wait tile 0 (allow 8 out)
#pragma unroll
  for (int i = 0; i < 12; ++i) STAGE();
  asm volatile("s_waitcnt vmcnt(8)" ::: "memory");
  __builtin_amdgcn_s_barrier();
  __builtin_amdgcn_sched_barrier(0);

  int s0 = 0;
  for (int tau = 0; tau < NT - 3; ++tau) {
    TILE32(1)
  }
  TILE32(2)   // tau = NT-3: drain to 4 outstanding
  TILE32(3)   // tau = NT-2: full drain
  TILE32(0)   // tau = NT-1: no wait, no barrier

  // epilogue: C = acc + bias
#pragma unroll
  for (int n = 0; n < 4; ++n) {
    const int col = n0 + wc * 64 + n * 16 + c15;
    const float bv = bias[col];
#pragma unroll
    for (int mi = 0; mi < 8; ++mi) {
      const int rowb = m0 + wr * 128 + mi * 16 + (lq << 2);
#pragma unroll
      for (int r = 0; r < 4; ++r)
        C[(size_t)(rowb + r) * N + col] = acc[mi][n][r] + bv;
    }
  }
}

extern "C" void kernel_launch(void* const* d_in, const int* in_sizes, int n_in,
                              void* d_out, int out_size, void* d_ws, size_t ws_size,
                              hipStream_t stream) {
  const float* W    = (const float*)d_in[0];   // [4096,4096]
  const float* bias = (const float*)d_in[1];   // [4096]
  const float* x    = (const float*)d_in[2];   // [4,2048,4096]
  const float* R    = (const float*)d_in[3];   // [8,512,512]
  float* out = (float*)d_out;

  char* ws = (char*)d_ws;
  u16* x_bf = (u16*)(ws);                      //  64 MiB
  u16* tw   = (u16*)(ws + 67108864);           //  32 MiB

  // scratch arena = d_out (128 MiB; fully overwritten by k_gemm256 at the end)
  char* arena = (char*)d_out;
  auto slot = [&](int i) -> u16* { return (u16*)(arena + (size_t)i * 4194304); };
  u16 *Mh = slot(0), *Ml = slot(1);
  u16 *G = slot(2), *G2 = slot(3), *G4 = slot(4);
  u16 *Xa = slot(5), *Xat = slot(6), *Xb = slot(7), *Xbt = slot(8);
  u16 *Xbl = slot(9), *Xbtl = slot(10);
  u16 *Tt = slot(2);                            // reuse G
  u16 *Tth = slot(3), *Ttl = slot(4);           // reuse G2, G4
  u16 *X6h = slot(5), *X6l = slot(6);           // reuse Xa/Xat (dead)
  u16 *X6th = slot(11), *X6tl = slot(12);
  float* Qf = (float*)(arena + (size_t)13 * 4194304);   // 8 MiB (slots 13-14)
  float* alpha = (float*)(arena + (size_t)15 * 4194304);

  const long long BS2 = 262144;
  const dim3 g8(8, 8, 8);
  const u16* NUL = nullptr;

  // 1) M pair
  k_build_M<<<dim3(16, 16, 8), 256, 0, stream>>>(R, Mh, Ml);
  // 2) G = M@M^T ; G2 = G@G^T ; G4 = G2@G2^T ; alpha from tr(G^8)
  k_bmm<0, 0, 1><<<g8, 256, 0, stream>>>(Mh, NUL, Mh, NUL, NUL, NUL,
                                         G, nullptr, nullptr, nullptr, nullptr, 0.f, 1.f);
  k_bmm<0, 0, 1><<<g8, 256, 0, stream>>>(G, NUL, G, NUL, NUL, NUL,
                                         G2, nullptr, nullptr, nullptr, nullptr, 0.f, 1.f);
  k_bmm<0, 0, 1><<<g8, 256, 0, stream>>>(G2, NUL, G2, NUL, NUL, NUL,
                                         G4, nullptr, nullptr, nullptr, nullptr, 0.f, 1.f);
  k_frob_alpha<<<8, 1024, 0, stream>>>(G4, alpha);
  // 3) X0 pair
  k_init_X0<<<8192, 256, 0, stream>>>(Mh, Ml, alpha, Xa, Xat);

  // 4) Newton iters 1-4 (bf16): T^T = (M@X)^T ; X' = 2X - X@T (+X'^T)
  u16 *cur = Xa, *curt = Xat, *nxt = Xb, *nxtt = Xbt;
  for (int it = 0; it < 4; ++it) {
    k_bmm<0, 0, 4><<<g8, 256, 0, stream>>>(Mh, NUL, curt, NUL, NUL, NUL,
                                           nullptr, nullptr, Tt, nullptr, nullptr, 0.f, 1.f);
    k_bmm<0, 1, 5><<<g8, 256, 0, stream>>>(cur, NUL, Tt, NUL, cur, NUL,
                                           nxt, nullptr, nxtt, nullptr, nullptr, 2.f, -1.f);
    u16* t;
    t = cur; cur = nxt; nxt = t;
    t = curt; curt = nxtt; nxtt = t;
  }
  // iter 5: write hi/lo pairs (normal + transposed)   [cur==Xa here]
  k_bmm<0, 0, 4><<<g8, 256, 0, stream>>>(Mh, NUL, curt, NUL, NUL, NUL,
                                         nullptr, nullptr, Tt, nullptr, nullptr, 0.f, 1.f);
  k_bmm<0, 1, 15><<<g8, 256, 0, stream>>>(cur, NUL, Tt, NUL, cur, NUL,
                                          Xb, Xbl, Xbt, Xbtl, nullptr, 2.f, -1.f);
  // 5) split-precision polish: T^T pair ; X6 = 2X5 - X5@T (pairs)
  k_bmm<1, 0, 12><<<g8, 256, 0, stream>>>(Mh, Ml, Xbt, Xbtl, NUL, NUL,
                                          nullptr, nullptr, Tth, Ttl, nullptr, 0.f, 1.f);
  k_bmm<1, 2, 15><<<g8, 256, 0, stream>>>(Xb, Xbl, Tth, Ttl, Xb, Xbl,
                                          X6h, X6l, X6th, X6tl, nullptr, 2.f, -1.f);
  // 6) Q = (2+1e-6)X6 - M@X6  (f32 out for tw)
  k_bmm<1, 2, 16><<<g8, 256, 0, stream>>>(Mh, Ml, X6th, X6tl, X6h, X6l,
                                          nullptr, nullptr, nullptr, nullptr, Qf, C1Q, -1.f);
  // 7) tw = W @ blockdiag(Q)
  k_smm<0, 1><<<dim3(4, 32, 8), 256, 0, stream>>>(W, 4096, 512, Qf, 512, BS2,
                                                  tw, 4096, 512, W, 4096, 512, 0.f, 1.f, 512);
  // 8) x -> bf16 ; main GEMM (overwrites the arena)
  k_f32_to_bf16<<<16384, 256, 0, stream>>>(x, x_bf);
  k_gemm256<<<dim3(16, 32), 512, 0, stream>>>(x_bf, tw, bias, out, 4096, 4096);
}

// Round 8
// 550.592 us; speedup vs baseline: 1.0591x; 1.0439x over previous
//
#include <hip/hip_runtime.h>
#include <hip/hip_bf16.h>

// EnhancedOFTLinearLayer: out = x @ (W @ blockdiag(cayley(R)))^T + bias
//   cayley(A): S = 0.5(A - A^T); Q = (I - S) @ inv((1+1e-6)I + S)
// Round 7: k_bmm -> 4-slot LDS ring, 2-step prefetch lead, counted vmcnt,
// one barrier per K-step. tw path rewritten bf16-native: Q-formation emits
// Qt (bf16 transposed); W converted once; k_twmm (ring) computes tw.
// k_gemm256 kept verbatim from round 6.

typedef unsigned short u16;
typedef __attribute__((ext_vector_type(8))) __bf16 bf16x8;
typedef __attribute__((ext_vector_type(4))) float f32x4;
typedef __attribute__((ext_vector_type(8))) unsigned short u16x8;
typedef __attribute__((ext_vector_type(4))) unsigned short u16x4;

#define C0   1.000001f   /* 1 + 1e-6 */
#define C1Q  2.000001f   /* 1 + C0   */
#define AS1 __attribute__((address_space(1)))
#define AS3 __attribute__((address_space(3)))

__device__ __forceinline__ u16 f2bf(float x) {
  union { float f; unsigned u; } v; v.f = x;
  return (u16)((v.u + 0x7fffu + ((v.u >> 16) & 1u)) >> 16);
}
__device__ __forceinline__ float bf2f(u16 h) {
  union { float f; unsigned u; } v; v.u = ((unsigned)h) << 16; return v.f;
}

// ---------------- 1) M = (1+1e-6)I + 0.5(R - R^T) -> bf16 hi/lo pair --------
__global__ __launch_bounds__(256) void k_build_M(const float* __restrict__ R,
                                                 u16* __restrict__ Mh,
                                                 u16* __restrict__ Ml) {
  __shared__ float t1[32][33];
  const int n = blockIdx.z;
  const int tr = blockIdx.y * 32, tc = blockIdx.x * 32;
  const int ly = threadIdx.x >> 5, lx = threadIdx.x & 31;   // 8 x 32
  const float* Rb = R + (size_t)n * 262144;
  float a[4];
#pragma unroll
  for (int i = 0; i < 4; ++i) {
    a[i] = Rb[(size_t)(tr + ly + i * 8) * 512 + tc + lx];
    t1[ly + i * 8][lx] = Rb[(size_t)(tc + ly + i * 8) * 512 + tr + lx];
  }
  __syncthreads();
#pragma unroll
  for (int i = 0; i < 4; ++i) {
    const int r = tr + ly + i * 8, c = tc + lx;
    float m = 0.5f * (a[i] - t1[lx][ly + i * 8]) + (r == c ? C0 : 0.0f);
    u16 h = f2bf(m);
    const size_t idx = (size_t)n * 262144 + (size_t)r * 512 + c;
    Mh[idx] = h;
    Ml[idx] = f2bf(m - bf2f(h));
  }
}

// ---------------- 2b) alpha[n] = 2/(c0^2 + (||G4||_F^2)^(1/8)) --------------
__global__ __launch_bounds__(1024) void k_frob_alpha(const u16* __restrict__ G4,
                                                     float* __restrict__ alpha) {
  __shared__ float red[16];
  const int n = blockIdx.x, tid = threadIdx.x;
  const u16* src = G4 + (size_t)n * 262144;
  float s = 0.f;
  for (int i = tid; i < 32768; i += 1024) {
    u16x8 v = reinterpret_cast<const u16x8*>(src)[i];
#pragma unroll
    for (int e = 0; e < 8; ++e) { float f = bf2f(v[e]); s += f * f; }
  }
  for (int off = 32; off; off >>= 1) s += __shfl_down(s, off, 64);
  if ((tid & 63) == 0) red[tid >> 6] = s;
  __syncthreads();
  if (tid == 0) {
    float t = 0.f;
    for (int q = 0; q < 16; ++q) t += red[q];
    float lam = powf(t, 0.125f);            // >= lambda_max(M^T M)
    alpha[n] = 2.0f / (C0 * C0 + lam);
  }
}

// ---------------- 3a) X0 = alpha*(2c0 I - M) ; X0^T = alpha*M ---------------
__global__ __launch_bounds__(256) void k_init_X0(const u16* __restrict__ Mh,
                                                 const u16* __restrict__ Ml,
                                                 const float* __restrict__ alpha,
                                                 u16* __restrict__ X0,
                                                 u16* __restrict__ X0t) {
  int idx = blockIdx.x * 256 + threadIdx.x;
  int n = idx >> 18, r = (idx >> 9) & 511, c = idx & 511;
  float m = bf2f(Mh[idx]) + bf2f(Ml[idx]);
  float a = alpha[n];
  X0[idx]  = f2bf(a * ((r == c ? 2.0f * C0 : 0.0f) - m));
  X0t[idx] = f2bf(a * m);
}

// ---------------- batched bf16 mm: C = cd*D + cs*(A @ B^T) ------------------
// All matrices [8][512][512] bf16 row-major; B pre-transposed (k-contiguous).
// 4-slot LDS ring, 2-step prefetch lead, counted vmcnt, 1 barrier/step.
// PROD3: A,B given as hi/lo pairs -> 3-MFMA split product (~fp21).
// DMODE: 0 none, 1 D=Dh, 2 D=Dh+Dl.  OMODE bits: 1 Cnh, 2 Cnl, 4 Cth, 8 Ctl.
#define BMM_FRAGS(rs)                                                          \
  bf16x8 a[2], b[2], al2[2], bl2[2];                                           \
  _Pragma("unroll")                                                            \
  for (int i = 0; i < 2; ++i) {                                                \
    const int fr = wr * 32 + i * 16 + c15;                                     \
    const int ia = (rs) * 2048 + fr * 32 + ((lk ^ (fr & 3)) * 8);              \
    a[i] = *reinterpret_cast<const bf16x8*>(&sA[ia]);                          \
    if constexpr (PROD3) al2[i] = *reinterpret_cast<const bf16x8*>(&sAl[ia]);  \
  }                                                                            \
  _Pragma("unroll")                                                            \
  for (int j = 0; j < 2; ++j) {                                                \
    const int fc = wc * 32 + j * 16 + c15;                                     \
    const int ib = (rs) * 2048 + fc * 32 + ((lk ^ (fc & 3)) * 8);              \
    b[j] = *reinterpret_cast<const bf16x8*>(&sB[ib]);                          \
    if constexpr (PROD3) bl2[j] = *reinterpret_cast<const bf16x8*>(&sBl[ib]);  \
  }                                                                            \
  _Pragma("unroll")                                                            \
  for (int i = 0; i < 2; ++i)                                                  \
    _Pragma("unroll")                                                          \
    for (int j = 0; j < 2; ++j) {                                              \
      acc[i][j] = __builtin_amdgcn_mfma_f32_16x16x32_bf16(a[i], b[j], acc[i][j], 0, 0, 0); \
      if constexpr (PROD3) {                                                   \
        acc[i][j] = __builtin_amdgcn_mfma_f32_16x16x32_bf16(a[i],   bl2[j], acc[i][j], 0, 0, 0); \
        acc[i][j] = __builtin_amdgcn_mfma_f32_16x16x32_bf16(al2[i], b[j],   acc[i][j], 0, 0, 0); \
      }                                                                        \
    }

#define BMM_WAIT(SEL)                                                          \
  if ((SEL) == 0) {                                                            \
    if constexpr (PROD3) asm volatile("s_waitcnt vmcnt(8)" ::: "memory");      \
    else                 asm volatile("s_waitcnt vmcnt(4)" ::: "memory");      \
  } else if ((SEL) == 1) {                                                     \
    if constexpr (PROD3) asm volatile("s_waitcnt vmcnt(4)" ::: "memory");      \
    else                 asm volatile("s_waitcnt vmcnt(2)" ::: "memory");      \
  } else {                                                                     \
    asm volatile("s_waitcnt vmcnt(0)" ::: "memory");                           \
  }

template <int PROD3, int DMODE, int OMODE>
__global__ __launch_bounds__(256)
void k_bmm(const u16* __restrict__ Ah, const u16* __restrict__ Al,
           const u16* __restrict__ Bh, const u16* __restrict__ Bl,
           const u16* __restrict__ Dh, const u16* __restrict__ Dl,
           u16* __restrict__ Cnh, u16* __restrict__ Cnl,
           u16* __restrict__ Cth, u16* __restrict__ Ctl,
           float cd, float cs) {
  __shared__ __align__(16) u16 sA[4 * 2048], sB[4 * 2048];
  __shared__ __align__(16) u16 sAl[PROD3 ? 4 * 2048 : 8];
  __shared__ __align__(16) u16 sBl[PROD3 ? 4 * 2048 : 8];
  const size_t zb = (size_t)blockIdx.z * 262144;
  const int tid = threadIdx.x, lane = tid & 63, wave = tid >> 6;
  const int m0 = blockIdx.y * 64, n0 = blockIdx.x * 64;
  const int wr = wave >> 1, wc = wave & 1;
  const int c15 = lane & 15, lk = lane >> 4;
  const int srow = tid >> 2;
  const int sg = (tid & 3) ^ (srow & 3);            // granule-XOR (involution)
  f32x4 acc[2][2] = {};
  const u16* pa = Ah + zb + (size_t)(m0 + srow) * 512 + sg * 8;
  const u16* pb = Bh + zb + (size_t)(n0 + srow) * 512 + sg * 8;
  const u16* pal = PROD3 ? Al + zb + (size_t)(m0 + srow) * 512 + sg * 8 : pa;
  const u16* pbl = PROD3 ? Bl + zb + (size_t)(n0 + srow) * 512 + sg * 8 : pb;

  int jn = 0, js = 0;
  auto STG = [&]() {
    if (jn < 16) {
      const int off = jn << 5;
      u16* da = sA + js * 2048 + tid * 8;
      u16* db = sB + js * 2048 + tid * 8;
      __builtin_amdgcn_global_load_lds((const AS1 void*)(pa + off), (AS3 void*)da, 16, 0, 0);
      __builtin_amdgcn_global_load_lds((const AS1 void*)(pb + off), (AS3 void*)db, 16, 0, 0);
      if constexpr (PROD3) {
        __builtin_amdgcn_global_load_lds((const AS1 void*)(pal + off),
                                         (AS3 void*)(sAl + js * 2048 + tid * 8), 16, 0, 0);
        __builtin_amdgcn_global_load_lds((const AS1 void*)(pbl + off),
                                         (AS3 void*)(sBl + js * 2048 + tid * 8), 16, 0, 0);
      }
    }
    ++jn; js = (js + 1) & 3;
  };

  STG(); STG();                 // prefetch steps 0,1
  int rs = 0;
  for (int t = 0; t < 14; ++t) {
    STG();                      // stage step t+2
    BMM_WAIT(0)                 // ensure step t landed (2 steps in flight)
    __builtin_amdgcn_s_barrier();
    BMM_FRAGS(rs)
    rs = (rs + 1) & 3;
  }
  STG();                        // no-op (jn=16)
  BMM_WAIT(1)                   // step 14 landed (1 step in flight)
  __builtin_amdgcn_s_barrier();
  { BMM_FRAGS(rs) }
  rs = (rs + 1) & 3;
  STG();                        // no-op
  BMM_WAIT(2)                   // full drain for step 15
  __builtin_amdgcn_s_barrier();
  { BMM_FRAGS(rs) }

  // epilogue (C/D map: col=lane&15, row=(lane>>4)*4+r)
#pragma unroll
  for (int i = 0; i < 2; ++i)
#pragma unroll
    for (int j = 0; j < 2; ++j) {
      const int rowb = m0 + wr * 32 + i * 16 + lk * 4;
      const int col  = n0 + wc * 32 + j * 16 + c15;
      u16 hv[4], lv[4];
#pragma unroll
      for (int r = 0; r < 4; ++r) {
        float val = cs * acc[i][j][r];
        if constexpr (DMODE >= 1) {
          float d = bf2f(Dh[zb + (size_t)(rowb + r) * 512 + col]);
          if constexpr (DMODE == 2) d += bf2f(Dl[zb + (size_t)(rowb + r) * 512 + col]);
          val += cd * d;
        }
        u16 h = f2bf(val);
        if constexpr (OMODE & 1) Cnh[zb + (size_t)(rowb + r) * 512 + col] = h;
        u16 l = 0;
        if constexpr (OMODE & 10) l = f2bf(val - bf2f(h));
        if constexpr (OMODE & 2) Cnl[zb + (size_t)(rowb + r) * 512 + col] = l;
        hv[r] = h; lv[r] = l;
      }
      if constexpr (OMODE & 4) {
        u16x4 v; v[0] = hv[0]; v[1] = hv[1]; v[2] = hv[2]; v[3] = hv[3];
        *reinterpret_cast<u16x4*>(&Cth[zb + (size_t)col * 512 + rowb]) = v;
      }
      if constexpr (OMODE & 8) {
        u16x4 v; v[0] = lv[0]; v[1] = lv[1]; v[2] = lv[2]; v[3] = lv[3];
        *reinterpret_cast<u16x4*>(&Ctl[zb + (size_t)col * 512 + rowb]) = v;
      }
    }
}

// ---------------- tw = W_bf @ blockdiag(Q)  (via B = Qt, same ring) ---------
__global__ __launch_bounds__(256)
void k_twmm(const u16* __restrict__ W, const u16* __restrict__ Qt,
            u16* __restrict__ tw) {
  __shared__ __align__(16) u16 sA[4 * 2048], sB[4 * 2048];
  const int z = blockIdx.z;
  const size_t zb = (size_t)z * 262144;
  const int tid = threadIdx.x, lane = tid & 63, wave = tid >> 6;
  const int m0 = blockIdx.y * 64, n0 = blockIdx.x * 64;
  const int wr = wave >> 1, wc = wave & 1;
  const int c15 = lane & 15, lk = lane >> 4;
  const int srow = tid >> 2;
  const int sg = (tid & 3) ^ (srow & 3);
  f32x4 acc[2][2] = {};
  const u16* pa = W + (size_t)(m0 + srow) * 4096 + z * 512 + sg * 8;
  const u16* pb = Qt + zb + (size_t)(n0 + srow) * 512 + sg * 8;

  int jn = 0, js = 0;
  auto STG = [&]() {
    if (jn < 16) {
      const int off = jn << 5;
      __builtin_amdgcn_global_load_lds((const AS1 void*)(pa + off),
                                       (AS3 void*)(sA + js * 2048 + tid * 8), 16, 0, 0);
      __builtin_amdgcn_global_load_lds((const AS1 void*)(pb + off),
                                       (AS3 void*)(sB + js * 2048 + tid * 8), 16, 0, 0);
    }
    ++jn; js = (js + 1) & 3;
  };

#define TW_FRAGS(rs)                                                           \
  {                                                                            \
    bf16x8 a[2], b[2];                                                         \
    _Pragma("unroll")                                                          \
    for (int i = 0; i < 2; ++i) {                                              \
      const int fr = wr * 32 + i * 16 + c15;                                   \
      a[i] = *reinterpret_cast<const bf16x8*>(                                 \
          &sA[(rs) * 2048 + fr * 32 + ((lk ^ (fr & 3)) * 8)]);                 \
    }                                                                          \
    _Pragma("unroll")                                                          \
    for (int j = 0; j < 2; ++j) {                                              \
      const int fc = wc * 32 + j * 16 + c15;                                   \
      b[j] = *reinterpret_cast<const bf16x8*>(                                 \
          &sB[(rs) * 2048 + fc * 32 + ((lk ^ (fc & 3)) * 8)]);                 \
    }                                                                          \
    _Pragma("unroll")                                                          \
    for (int i = 0; i < 2; ++i)                                                \
      _Pragma("unroll")                                                        \
      for (int j = 0; j < 2; ++j)                                              \
        acc[i][j] = __builtin_amdgcn_mfma_f32_16x16x32_bf16(a[i], b[j], acc[i][j], 0, 0, 0); \
  }

  STG(); STG();
  int rs = 0;
  for (int t = 0; t < 14; ++t) {
    STG();
    asm volatile("s_waitcnt vmcnt(4)" ::: "memory");
    __builtin_amdgcn_s_barrier();
    TW_FRAGS(rs)
    rs = (rs + 1) & 3;
  }
  STG();
  asm volatile("s_waitcnt vmcnt(2)" ::: "memory");
  __builtin_amdgcn_s_barrier();
  TW_FRAGS(rs)
  rs = (rs + 1) & 3;
  STG();
  asm volatile("s_waitcnt vmcnt(0)" ::: "memory");
  __builtin_amdgcn_s_barrier();
  TW_FRAGS(rs)

#pragma unroll
  for (int i = 0; i < 2; ++i)
#pragma unroll
    for (int j = 0; j < 2; ++j) {
      const int rowb = m0 + wr * 32 + i * 16 + lk * 4;
      const int col  = z * 512 + n0 + wc * 32 + j * 16 + c15;
#pragma unroll
      for (int r = 0; r < 4; ++r)
        tw[(size_t)(rowb + r) * 4096 + col] = f2bf(acc[i][j][r]);
    }
}

// ---------------- 5a) f32 -> bf16 (x and W) ----------------
__global__ __launch_bounds__(256) void k_f32_to_bf16(const float* __restrict__ in,
                                                     u16* __restrict__ out) {
  int idx = blockIdx.x * 256 + threadIdx.x;
  const float* src = in + (size_t)idx * 8;
  float4 f0 = *reinterpret_cast<const float4*>(src);
  float4 f1 = *reinterpret_cast<const float4*>(src + 4);
  u16x8 w;
  w[0] = f2bf(f0.x); w[1] = f2bf(f0.y); w[2] = f2bf(f0.z); w[3] = f2bf(f0.w);
  w[4] = f2bf(f1.x); w[5] = f2bf(f1.y); w[6] = f2bf(f1.z); w[7] = f2bf(f1.w);
  *reinterpret_cast<u16x8*>(out + (size_t)idx * 8) = w;
}

// ---------------- 5b) out = x_bf @ tw^T + bias (round-6, verbatim) ----------
#define NSL 18

#define RD_A3(dst, MH)                                                         \
  _Pragma("unroll")                                                            \
  for (int m = 0; m < 4; ++m)                                                  \
    dst[m] = *reinterpret_cast<const bf16x8*>(                                 \
        &lds[aslot * 4096 + ((MH) * 64 + m * 16 + c15) * 32 + gsw * 8]);

#define RD_B3(dst)                                                             \
  _Pragma("unroll")                                                            \
  for (int n = 0; n < 4; ++n)                                                  \
    dst[n] = *reinterpret_cast<const bf16x8*>(                                 \
        &lds[bslot * 4096 + (bq64 + n * 16 + c15) * 32 + gsw * 8]);

#define MFMA16(afX, bfX, MH)                                                   \
  __builtin_amdgcn_s_setprio(1);                                               \
  _Pragma("unroll")                                                            \
  for (int m = 0; m < 4; ++m)                                                  \
    _Pragma("unroll")                                                          \
    for (int n = 0; n < 4; ++n)                                                \
      acc[(MH) * 4 + m][n] = __builtin_amdgcn_mfma_f32_16x16x32_bf16(          \
          afX[m], bfX[n], acc[(MH) * 4 + m][n], 0, 0, 0);                      \
  __builtin_amdgcn_s_setprio(0);

// WM: 1 steady vmcnt(8) | 2 vmcnt(4) | 3 vmcnt(0) | 0 none (last tile)
#define TILE32(WM)                                                             \
  {                                                                            \
    int aslot = s0 + wr;            if (aslot >= NSL) aslot -= NSL;            \
    int bslot = s0 + 2 + (wc >> 1); if (bslot >= NSL) bslot -= NSL;            \
    STAGE(); STAGE();                                                          \
    RD_B3(bfr)                                                                 \
    RD_A3(afA, 0)                                                              \
    MFMA16(afA, bfr, 0)                                                        \
    STAGE(); STAGE();                                                          \
    RD_A3(afB, 1)                                                              \
    MFMA16(afB, bfr, 1)                                                        \
    if ((WM) == 1) asm volatile("s_waitcnt vmcnt(8)" ::: "memory");            \
    if ((WM) == 2) asm volatile("s_waitcnt vmcnt(4)" ::: "memory");            \
    if ((WM) == 3) asm volatile("s_waitcnt vmcnt(0)" ::: "memory");            \
    if ((WM) != 0) {                                                           \
      __builtin_amdgcn_s_barrier();                                            \
      __builtin_amdgcn_sched_barrier(0);                                       \
    }                                                                          \
    s0 += 4; if (s0 >= NSL) s0 -= NSL;                                         \
  }

__global__ __launch_bounds__(512, 2)
void k_gemm256(const u16* __restrict__ A, const u16* __restrict__ B,
               const float* __restrict__ bias,
               float* __restrict__ C, int N, int K) {
  __shared__ __align__(16) u16 lds[NSL * 4096];   // 144 KiB
  const int tid = threadIdx.x, lane = tid & 63, wave = tid >> 6;
  int bid = blockIdx.y * gridDim.x + blockIdx.x;
  const int cpx = (gridDim.x * gridDim.y) >> 3;
  bid = (bid & 7) * cpx + (bid >> 3);
  const int nbx = N >> 8;
  const int bx = bid % nbx, by = bid / nbx;
  const int m0 = by << 8, n0 = bx << 8;
  const int wr = wave >> 2, wc = wave & 3;          // 2 x 4 wave grid
  const int srow = tid >> 2;
  const int sgc  = (tid & 3) ^ ((srow >> 1) & 3);
  const int c15 = lane & 15, lq = lane >> 4;
  const int gsw = lq ^ ((c15 >> 1) & 3);
  const int bq64 = (wc & 1) * 64;
  const int NT = K >> 5;                            // 128

  f32x4 acc[8][4] = {};
  bf16x8 afA[4], afB[4], bfr[4];

  int jn = 0, js = 0;
  auto STAGE = [&]() {
    if (jn < 4 * NT) {
      const int t = jn >> 2, q = jn & 3;
      const u16* srcb = (q < 2)
          ? A + (size_t)(m0 + q * 128 + srow) * (size_t)K
          : B + (size_t)(n0 + (q - 2) * 128 + srow) * (size_t)K;
      const u16* src = srcb + (t << 5) + sgc * 8;
      u16* dst = (u16*)lds + js * 4096 + tid * 8;
      __builtin_amdgcn_global_load_lds(
          (const AS1 void*)src, (AS3 void*)dst, 16, 0, 0);
    }
    ++jn; js = (js == NSL - 1) ? 0 : js + 1;
  };

#pragma unroll
  for (int i = 0; i < 12; ++i) STAGE();
  asm volatile("s_waitcnt vmcnt(8)" ::: "memory");
  __builtin_amdgcn_s_barrier();
  __builtin_amdgcn_sched_barrier(0);

  int s0 = 0;
  for (int tau = 0; tau < NT - 3; ++tau) {
    TILE32(1)
  }
  TILE32(2)
  TILE32(3)
  TILE32(0)

#pragma unroll
  for (int n = 0; n < 4; ++n) {
    const int col = n0 + wc * 64 + n * 16 + c15;
    const float bv = bias[col];
#pragma unroll
    for (int mi = 0; mi < 8; ++mi) {
      const int rowb = m0 + wr * 128 + mi * 16 + (lq << 2);
#pragma unroll
      for (int r = 0; r < 4; ++r)
        C[(size_t)(rowb + r) * N + col] = acc[mi][n][r] + bv;
    }
  }
}

extern "C" void kernel_launch(void* const* d_in, const int* in_sizes, int n_in,
                              void* d_out, int out_size, void* d_ws, size_t ws_size,
                              hipStream_t stream) {
  const float* W    = (const float*)d_in[0];   // [4096,4096]
  const float* bias = (const float*)d_in[1];   // [4096]
  const float* x    = (const float*)d_in[2];   // [4,2048,4096]
  const float* R    = (const float*)d_in[3];   // [8,512,512]
  float* out = (float*)d_out;

  char* ws = (char*)d_ws;
  u16* x_bf = (u16*)(ws);                      //  64 MiB
  u16* tw   = (u16*)(ws + 67108864);           //  32 MiB
  u16* W_bf = (u16*)(ws + 100663296);          //  32 MiB

  // scratch arena = d_out (128 MiB; fully overwritten by k_gemm256 at the end)
  char* arena = (char*)d_out;
  auto slot = [&](int i) -> u16* { return (u16*)(arena + (size_t)i * 4194304); };
  u16 *Mh = slot(0), *Ml = slot(1);
  u16 *G = slot(2), *G2 = slot(3), *G4 = slot(4);
  u16 *Xa = slot(5), *Xat = slot(6), *Xb = slot(7), *Xbt = slot(8);
  u16 *Xbl = slot(9), *Xbtl = slot(10);
  u16 *Tt = slot(2);                            // reuse G
  u16 *Tth = slot(3), *Ttl = slot(4);           // reuse G2, G4
  u16 *X6h = slot(5), *X6l = slot(6);           // reuse Xa/Xat (dead)
  u16 *X6th = slot(11), *X6tl = slot(12);
  u16 *Qt = slot(13);                           // Q transposed, bf16
  float* alpha = (float*)(arena + (size_t)15 * 4194304);

  const dim3 g8(8, 8, 8);
  const u16* NUL = nullptr;

  // 1) M pair
  k_build_M<<<dim3(16, 16, 8), 256, 0, stream>>>(R, Mh, Ml);
  // 2) G = M@M^T ; G2 = G@G^T ; G4 = G2@G2^T ; alpha from tr(G^8)
  k_bmm<0, 0, 1><<<g8, 256, 0, stream>>>(Mh, NUL, Mh, NUL, NUL, NUL,
                                         G, nullptr, nullptr, nullptr, 0.f, 1.f);
  k_bmm<0, 0, 1><<<g8, 256, 0, stream>>>(G, NUL, G, NUL, NUL, NUL,
                                         G2, nullptr, nullptr, nullptr, 0.f, 1.f);
  k_bmm<0, 0, 1><<<g8, 256, 0, stream>>>(G2, NUL, G2, NUL, NUL, NUL,
                                         G4, nullptr, nullptr, nullptr, 0.f, 1.f);
  k_frob_alpha<<<8, 1024, 0, stream>>>(G4, alpha);
  // 3) X0 pair
  k_init_X0<<<8192, 256, 0, stream>>>(Mh, Ml, alpha, Xa, Xat);

  // 4) Newton iters 1-4 (bf16): T^T = (M@X)^T ; X' = 2X - X@T (+X'^T)
  u16 *cur = Xa, *curt = Xat, *nxt = Xb, *nxtt = Xbt;
  for (int it = 0; it < 4; ++it) {
    k_bmm<0, 0, 4><<<g8, 256, 0, stream>>>(Mh, NUL, curt, NUL, NUL, NUL,
                                           nullptr, nullptr, Tt, nullptr, 0.f, 1.f);
    k_bmm<0, 1, 5><<<g8, 256, 0, stream>>>(cur, NUL, Tt, NUL, cur, NUL,
                                           nxt, nullptr, nxtt, nullptr, 2.f, -1.f);
    u16* t;
    t = cur; cur = nxt; nxt = t;
    t = curt; curt = nxtt; nxtt = t;
  }
  // iter 5: write hi/lo pairs (normal + transposed)   [cur==Xa here]
  k_bmm<0, 0, 4><<<g8, 256, 0, stream>>>(Mh, NUL, curt, NUL, NUL, NUL,
                                         nullptr, nullptr, Tt, nullptr, 0.f, 1.f);
  k_bmm<0, 1, 15><<<g8, 256, 0, stream>>>(cur, NUL, Tt, NUL, cur, NUL,
                                          Xb, Xbl, Xbt, Xbtl, 2.f, -1.f);
  // 5) split-precision polish: T^T pair ; X6 = 2X5 - X5@T (pairs)
  k_bmm<1, 0, 12><<<g8, 256, 0, stream>>>(Mh, Ml, Xbt, Xbtl, NUL, NUL,
                                          nullptr, nullptr, Tth, Ttl, 0.f, 1.f);
  k_bmm<1, 2, 15><<<g8, 256, 0, stream>>>(Xb, Xbl, Tth, Ttl, Xb, Xbl,
                                          X6h, X6l, X6th, X6tl, 2.f, -1.f);
  // 6) Q^T (bf16) = transpose of (2+1e-6)X6 - M@X6
  k_bmm<1, 2, 4><<<g8, 256, 0, stream>>>(Mh, Ml, X6th, X6tl, X6h, X6l,
                                         nullptr, nullptr, Qt, nullptr, C1Q, -1.f);
  // 7) W -> bf16 ; tw = W_bf @ blockdiag(Q)
  k_f32_to_bf16<<<8192, 256, 0, stream>>>(W, W_bf);
  k_twmm<<<dim3(8, 64, 8), 256, 0, stream>>>(W_bf, Qt, tw);
  // 8) x -> bf16 ; main GEMM (overwrites the arena)
  k_f32_to_bf16<<<16384, 256, 0, stream>>>(x, x_bf);
  k_gemm256<<<dim3(16, 32), 512, 0, stream>>>(x_bf, tw, bias, out, 4096, 4096);
}

// Round 9
// 541.597 us; speedup vs baseline: 1.0767x; 1.0166x over previous
//
#include <hip/hip_runtime.h>
#include <hip/hip_bf16.h>

// EnhancedOFTLinearLayer: out = x @ (W @ blockdiag(cayley(R)))^T + bias
//   cayley(A): S = 0.5(A - A^T); Q = (I - S) @ inv((1+1e-6)I + S)
// Round 8: (1) W/x f32->bf16 conversion fused into k_bmm launches as extra
// grid-z planes (z=8,9; 12 chunks of 4M elems) -- runs on idle HBM/CUs
// alongside the latency-bound Newton chain; dedicated conversion launches
// removed. (2) Recentered Newton (X *= 2/(2-e^2) each iter, per-batch factors
// from k_frob_alpha) -> 3 bf16 iters instead of 5; chain 16 -> 12 k_bmm.
// k_gemm256 / k_twmm verbatim from round 7.

typedef unsigned short u16;
typedef __attribute__((ext_vector_type(8))) __bf16 bf16x8;
typedef __attribute__((ext_vector_type(4))) float f32x4;
typedef __attribute__((ext_vector_type(8))) unsigned short u16x8;
typedef __attribute__((ext_vector_type(4))) unsigned short u16x4;

#define C0   1.000001f   /* 1 + 1e-6 */
#define C1Q  2.000001f   /* 1 + C0   */
#define AS1 __attribute__((address_space(1)))
#define AS3 __attribute__((address_space(3)))

__device__ __forceinline__ u16 f2bf(float x) {
  union { float f; unsigned u; } v; v.f = x;
  return (u16)((v.u + 0x7fffu + ((v.u >> 16) & 1u)) >> 16);
}
__device__ __forceinline__ float bf2f(u16 h) {
  union { float f; unsigned u; } v; v.u = ((unsigned)h) << 16; return v.f;
}

// ---------------- 1) M = (1+1e-6)I + 0.5(R - R^T) -> bf16 hi/lo pair --------
__global__ __launch_bounds__(256) void k_build_M(const float* __restrict__ R,
                                                 u16* __restrict__ Mh,
                                                 u16* __restrict__ Ml) {
  __shared__ float t1[32][33];
  const int n = blockIdx.z;
  const int tr = blockIdx.y * 32, tc = blockIdx.x * 32;
  const int ly = threadIdx.x >> 5, lx = threadIdx.x & 31;   // 8 x 32
  const float* Rb = R + (size_t)n * 262144;
  float a[4];
#pragma unroll
  for (int i = 0; i < 4; ++i) {
    a[i] = Rb[(size_t)(tr + ly + i * 8) * 512 + tc + lx];
    t1[ly + i * 8][lx] = Rb[(size_t)(tc + ly + i * 8) * 512 + tr + lx];
  }
  __syncthreads();
#pragma unroll
  for (int i = 0; i < 4; ++i) {
    const int r = tr + ly + i * 8, c = tc + lx;
    float m = 0.5f * (a[i] - t1[lx][ly + i * 8]) + (r == c ? C0 : 0.0f);
    u16 h = f2bf(m);
    const size_t idx = (size_t)n * 262144 + (size_t)r * 512 + c;
    Mh[idx] = h;
    Ml[idx] = f2bf(m - bf2f(h));
  }
}

// ------- 2b) alpha + recentered-Newton scale schedule (per batch) -----------
// lam_hat = (||G4||_F^2)^(1/8) >= lambda_max(M^T M);  e0 = (lam-c0^2)/(lam+c0^2)
// per iter k: s=e^2; c=2/(2-s); (cd,cs)=(2c,-c); e=s/(2-s).
__global__ __launch_bounds__(1024) void k_frob_alpha(const u16* __restrict__ G4,
                                                     float* __restrict__ alpha,
                                                     float* __restrict__ cdv,
                                                     float* __restrict__ csv) {
  __shared__ float red[16];
  const int n = blockIdx.x, tid = threadIdx.x;
  const u16* src = G4 + (size_t)n * 262144;
  float s = 0.f;
  for (int i = tid; i < 32768; i += 1024) {
    u16x8 v = reinterpret_cast<const u16x8*>(src)[i];
#pragma unroll
    for (int e = 0; e < 8; ++e) { float f = bf2f(v[e]); s += f * f; }
  }
  for (int off = 32; off; off >>= 1) s += __shfl_down(s, off, 64);
  if ((tid & 63) == 0) red[tid >> 6] = s;
  __syncthreads();
  if (tid == 0) {
    float t = 0.f;
    for (int q = 0; q < 16; ++q) t += red[q];
    float lam = powf(t, 0.125f);
    alpha[n] = 2.0f / (C0 * C0 + lam);
    float e = (lam - C0 * C0) / (lam + C0 * C0);
#pragma unroll
    for (int k = 0; k < 3; ++k) {
      float sq = e * e;
      float c = 2.0f / (2.0f - sq);
      cdv[k * 8 + n] = 2.0f * c;
      csv[k * 8 + n] = -c;
      e = sq / (2.0f - sq);
    }
  }
}

// ---------------- 3a) X0 = alpha*(2c0 I - M) ; X0^T = alpha*M ---------------
__global__ __launch_bounds__(256) void k_init_X0(const u16* __restrict__ Mh,
                                                 const u16* __restrict__ Ml,
                                                 const float* __restrict__ alpha,
                                                 u16* __restrict__ X0,
                                                 u16* __restrict__ X0t) {
  int idx = blockIdx.x * 256 + threadIdx.x;
  int n = idx >> 18, r = (idx >> 9) & 511, c = idx & 511;
  float m = bf2f(Mh[idx]) + bf2f(Ml[idx]);
  float a = alpha[n];
  X0[idx]  = f2bf(a * ((r == c ? 2.0f * C0 : 0.0f) - m));
  X0t[idx] = f2bf(a * m);
}

// ---------------- batched bf16 mm: C = cd*D + cs*(A @ B^T) ------------------
// grid (8,8,10): z<8 = mm batches; z>=8 = f32->bf16 conversion side-channel
// (128 blocks x 32768 elems = one 4M-elem chunk per launch).
// 4-slot LDS ring, 2-step prefetch lead, counted vmcnt, 1 barrier/step.
// PROD3: split hi/lo 3-MFMA product. DMODE: 0/1/2. OMODE bits 1/2/4/8.
// cdp/csp non-null -> per-batch cd/cs from arrays (recentered Newton).
#define BMM_FRAGS(rs)                                                          \
  bf16x8 a[2], b[2], al2[2], bl2[2];                                           \
  _Pragma("unroll")                                                            \
  for (int i = 0; i < 2; ++i) {                                                \
    const int fr = wr * 32 + i * 16 + c15;                                     \
    const int ia = (rs) * 2048 + fr * 32 + ((lk ^ (fr & 3)) * 8);              \
    a[i] = *reinterpret_cast<const bf16x8*>(&sA[ia]);                          \
    if constexpr (PROD3) al2[i] = *reinterpret_cast<const bf16x8*>(&sAl[ia]);  \
  }                                                                            \
  _Pragma("unroll")                                                            \
  for (int j = 0; j < 2; ++j) {                                                \
    const int fc = wc * 32 + j * 16 + c15;                                     \
    const int ib = (rs) * 2048 + fc * 32 + ((lk ^ (fc & 3)) * 8);              \
    b[j] = *reinterpret_cast<const bf16x8*>(&sB[ib]);                          \
    if constexpr (PROD3) bl2[j] = *reinterpret_cast<const bf16x8*>(&sBl[ib]);  \
  }                                                                            \
  _Pragma("unroll")                                                            \
  for (int i = 0; i < 2; ++i)                                                  \
    _Pragma("unroll")                                                          \
    for (int j = 0; j < 2; ++j) {                                              \
      acc[i][j] = __builtin_amdgcn_mfma_f32_16x16x32_bf16(a[i], b[j], acc[i][j], 0, 0, 0); \
      if constexpr (PROD3) {                                                   \
        acc[i][j] = __builtin_amdgcn_mfma_f32_16x16x32_bf16(a[i],   bl2[j], acc[i][j], 0, 0, 0); \
        acc[i][j] = __builtin_amdgcn_mfma_f32_16x16x32_bf16(al2[i], b[j],   acc[i][j], 0, 0, 0); \
      }                                                                        \
    }

#define BMM_WAIT(SEL)                                                          \
  if ((SEL) == 0) {                                                            \
    if constexpr (PROD3) asm volatile("s_waitcnt vmcnt(8)" ::: "memory");      \
    else                 asm volatile("s_waitcnt vmcnt(4)" ::: "memory");      \
  } else if ((SEL) == 1) {                                                     \
    if constexpr (PROD3) asm volatile("s_waitcnt vmcnt(4)" ::: "memory");      \
    else                 asm volatile("s_waitcnt vmcnt(2)" ::: "memory");      \
  } else {                                                                     \
    asm volatile("s_waitcnt vmcnt(0)" ::: "memory");                           \
  }

template <int PROD3, int DMODE, int OMODE>
__global__ __launch_bounds__(256)
void k_bmm(const u16* __restrict__ Ah, const u16* __restrict__ Al,
           const u16* __restrict__ Bh, const u16* __restrict__ Bl,
           const u16* __restrict__ Dh, const u16* __restrict__ Dl,
           u16* __restrict__ Cnh, u16* __restrict__ Cnl,
           u16* __restrict__ Cth, u16* __restrict__ Ctl,
           float cd, float cs,
           const float* __restrict__ cdp, const float* __restrict__ csp,
           const float* __restrict__ cvsrc, u16* __restrict__ cvdst) {
  __shared__ __align__(16) u16 sA[4 * 2048], sB[4 * 2048];
  __shared__ __align__(16) u16 sAl[PROD3 ? 4 * 2048 : 8];
  __shared__ __align__(16) u16 sBl[PROD3 ? 4 * 2048 : 8];

  if (blockIdx.z >= 8) {        // conversion side-channel
    const int zi = (blockIdx.z - 8) * 64 + blockIdx.y * 8 + blockIdx.x;
    const int base = zi * 256 + (int)threadIdx.x;
#pragma unroll
    for (int e = 0; e < 16; ++e) {
      const size_t g = (size_t)(base + e * 32768) * 8;
      float4 f0 = *reinterpret_cast<const float4*>(cvsrc + g);
      float4 f1 = *reinterpret_cast<const float4*>(cvsrc + g + 4);
      u16x8 w;
      w[0] = f2bf(f0.x); w[1] = f2bf(f0.y); w[2] = f2bf(f0.z); w[3] = f2bf(f0.w);
      w[4] = f2bf(f1.x); w[5] = f2bf(f1.y); w[6] = f2bf(f1.z); w[7] = f2bf(f1.w);
      *reinterpret_cast<u16x8*>(cvdst + g) = w;
    }
    return;
  }

  const size_t zb = (size_t)blockIdx.z * 262144;
  const int tid = threadIdx.x, lane = tid & 63, wave = tid >> 6;
  const int m0 = blockIdx.y * 64, n0 = blockIdx.x * 64;
  const int wr = wave >> 1, wc = wave & 1;
  const int c15 = lane & 15, lk = lane >> 4;
  const int srow = tid >> 2;
  const int sg = (tid & 3) ^ (srow & 3);            // granule-XOR (involution)
  f32x4 acc[2][2] = {};
  const u16* pa = Ah + zb + (size_t)(m0 + srow) * 512 + sg * 8;
  const u16* pb = Bh + zb + (size_t)(n0 + srow) * 512 + sg * 8;
  const u16* pal = PROD3 ? Al + zb + (size_t)(m0 + srow) * 512 + sg * 8 : pa;
  const u16* pbl = PROD3 ? Bl + zb + (size_t)(n0 + srow) * 512 + sg * 8 : pb;

  int jn = 0, js = 0;
  auto STG = [&]() {
    if (jn < 16) {
      const int off = jn << 5;
      u16* da = sA + js * 2048 + tid * 8;
      u16* db = sB + js * 2048 + tid * 8;
      __builtin_amdgcn_global_load_lds((const AS1 void*)(pa + off), (AS3 void*)da, 16, 0, 0);
      __builtin_amdgcn_global_load_lds((const AS1 void*)(pb + off), (AS3 void*)db, 16, 0, 0);
      if constexpr (PROD3) {
        __builtin_amdgcn_global_load_lds((const AS1 void*)(pal + off),
                                         (AS3 void*)(sAl + js * 2048 + tid * 8), 16, 0, 0);
        __builtin_amdgcn_global_load_lds((const AS1 void*)(pbl + off),
                                         (AS3 void*)(sBl + js * 2048 + tid * 8), 16, 0, 0);
      }
    }
    ++jn; js = (js + 1) & 3;
  };

  STG(); STG();                 // prefetch steps 0,1
  int rs = 0;
  for (int t = 0; t < 14; ++t) {
    STG();                      // stage step t+2
    BMM_WAIT(0)                 // step t landed (2 steps in flight)
    __builtin_amdgcn_s_barrier();
    BMM_FRAGS(rs)
    rs = (rs + 1) & 3;
  }
  STG();                        // no-op (jn=16)
  BMM_WAIT(1)
  __builtin_amdgcn_s_barrier();
  { BMM_FRAGS(rs) }
  rs = (rs + 1) & 3;
  STG();                        // no-op
  BMM_WAIT(2)
  __builtin_amdgcn_s_barrier();
  { BMM_FRAGS(rs) }

  const float cdL = cdp ? cdp[blockIdx.z] : cd;
  const float csL = csp ? csp[blockIdx.z] : cs;
  // epilogue (C/D map: col=lane&15, row=(lane>>4)*4+r)
#pragma unroll
  for (int i = 0; i < 2; ++i)
#pragma unroll
    for (int j = 0; j < 2; ++j) {
      const int rowb = m0 + wr * 32 + i * 16 + lk * 4;
      const int col  = n0 + wc * 32 + j * 16 + c15;
      u16 hv[4], lv[4];
#pragma unroll
      for (int r = 0; r < 4; ++r) {
        float val = csL * acc[i][j][r];
        if constexpr (DMODE >= 1) {
          float d = bf2f(Dh[zb + (size_t)(rowb + r) * 512 + col]);
          if constexpr (DMODE == 2) d += bf2f(Dl[zb + (size_t)(rowb + r) * 512 + col]);
          val += cdL * d;
        }
        u16 h = f2bf(val);
        if constexpr (OMODE & 1) Cnh[zb + (size_t)(rowb + r) * 512 + col] = h;
        u16 l = 0;
        if constexpr (OMODE & 10) l = f2bf(val - bf2f(h));
        if constexpr (OMODE & 2) Cnl[zb + (size_t)(rowb + r) * 512 + col] = l;
        hv[r] = h; lv[r] = l;
      }
      if constexpr (OMODE & 4) {
        u16x4 v; v[0] = hv[0]; v[1] = hv[1]; v[2] = hv[2]; v[3] = hv[3];
        *reinterpret_cast<u16x4*>(&Cth[zb + (size_t)col * 512 + rowb]) = v;
      }
      if constexpr (OMODE & 8) {
        u16x4 v; v[0] = lv[0]; v[1] = lv[1]; v[2] = lv[2]; v[3] = lv[3];
        *reinterpret_cast<u16x4*>(&Ctl[zb + (size_t)col * 512 + rowb]) = v;
      }
    }
}

// ---------------- tw = W_bf @ blockdiag(Q)  (via B = Qt, same ring) ---------
__global__ __launch_bounds__(256)
void k_twmm(const u16* __restrict__ W, const u16* __restrict__ Qt,
            u16* __restrict__ tw) {
  __shared__ __align__(16) u16 sA[4 * 2048], sB[4 * 2048];
  const int z = blockIdx.z;
  const size_t zb = (size_t)z * 262144;
  const int tid = threadIdx.x, lane = tid & 63, wave = tid >> 6;
  const int m0 = blockIdx.y * 64, n0 = blockIdx.x * 64;
  const int wr = wave >> 1, wc = wave & 1;
  const int c15 = lane & 15, lk = lane >> 4;
  const int srow = tid >> 2;
  const int sg = (tid & 3) ^ (srow & 3);
  f32x4 acc[2][2] = {};
  const u16* pa = W + (size_t)(m0 + srow) * 4096 + z * 512 + sg * 8;
  const u16* pb = Qt + zb + (size_t)(n0 + srow) * 512 + sg * 8;

  int jn = 0, js = 0;
  auto STG = [&]() {
    if (jn < 16) {
      const int off = jn << 5;
      __builtin_amdgcn_global_load_lds((const AS1 void*)(pa + off),
                                       (AS3 void*)(sA + js * 2048 + tid * 8), 16, 0, 0);
      __builtin_amdgcn_global_load_lds((const AS1 void*)(pb + off),
                                       (AS3 void*)(sB + js * 2048 + tid * 8), 16, 0, 0);
    }
    ++jn; js = (js + 1) & 3;
  };

#define TW_FRAGS(rs)                                                           \
  {                                                                            \
    bf16x8 a[2], b[2];                                                         \
    _Pragma("unroll")                                                          \
    for (int i = 0; i < 2; ++i) {                                              \
      const int fr = wr * 32 + i * 16 + c15;                                   \
      a[i] = *reinterpret_cast<const bf16x8*>(                                 \
          &sA[(rs) * 2048 + fr * 32 + ((lk ^ (fr & 3)) * 8)]);                 \
    }                                                                          \
    _Pragma("unroll")                                                          \
    for (int j = 0; j < 2; ++j) {                                              \
      const int fc = wc * 32 + j * 16 + c15;                                   \
      b[j] = *reinterpret_cast<const bf16x8*>(                                 \
          &sB[(rs) * 2048 + fc * 32 + ((lk ^ (fc & 3)) * 8)]);                 \
    }                                                                          \
    _Pragma("unroll")                                                          \
    for (int i = 0; i < 2; ++i)                                                \
      _Pragma("unroll")                                                        \
      for (int j = 0; j < 2; ++j)                                              \
        acc[i][j] = __builtin_amdgcn_mfma_f32_16x16x32_bf16(a[i], b[j], acc[i][j], 0, 0, 0); \
  }

  STG(); STG();
  int rs = 0;
  for (int t = 0; t < 14; ++t) {
    STG();
    asm volatile("s_waitcnt vmcnt(4)" ::: "memory");
    __builtin_amdgcn_s_barrier();
    TW_FRAGS(rs)
    rs = (rs + 1) & 3;
  }
  STG();
  asm volatile("s_waitcnt vmcnt(2)" ::: "memory");
  __builtin_amdgcn_s_barrier();
  TW_FRAGS(rs)
  rs = (rs + 1) & 3;
  STG();
  asm volatile("s_waitcnt vmcnt(0)" ::: "memory");
  __builtin_amdgcn_s_barrier();
  TW_FRAGS(rs)

#pragma unroll
  for (int i = 0; i < 2; ++i)
#pragma unroll
    for (int j = 0; j < 2; ++j) {
      const int rowb = m0 + wr * 32 + i * 16 + lk * 4;
      const int col  = z * 512 + n0 + wc * 32 + j * 16 + c15;
#pragma unroll
      for (int r = 0; r < 4; ++r)
        tw[(size_t)(rowb + r) * 4096 + col] = f2bf(acc[i][j][r]);
    }
}

// ---------------- out = x_bf @ tw^T + bias (round-6, verbatim) --------------
#define NSL 18

#define RD_A3(dst, MH)                                                         \
  _Pragma("unroll")                                                            \
  for (int m = 0; m < 4; ++m)                                                  \
    dst[m] = *reinterpret_cast<const bf16x8*>(                                 \
        &lds[aslot * 4096 + ((MH) * 64 + m * 16 + c15) * 32 + gsw * 8]);

#define RD_B3(dst)                                                             \
  _Pragma("unroll")                                                            \
  for (int n = 0; n < 4; ++n)                                                  \
    dst[n] = *reinterpret_cast<const bf16x8*>(                                 \
        &lds[bslot * 4096 + (bq64 + n * 16 + c15) * 32 + gsw * 8]);

#define MFMA16(afX, bfX, MH)                                                   \
  __builtin_amdgcn_s_setprio(1);                                               \
  _Pragma("unroll")                                                            \
  for (int m = 0; m < 4; ++m)                                                  \
    _Pragma("unroll")                                                          \
    for (int n = 0; n < 4; ++n)                                                \
      acc[(MH) * 4 + m][n] = __builtin_amdgcn_mfma_f32_16x16x32_bf16(          \
          afX[m], bfX[n], acc[(MH) * 4 + m][n], 0, 0, 0);                      \
  __builtin_amdgcn_s_setprio(0);

// WM: 1 steady vmcnt(8) | 2 vmcnt(4) | 3 vmcnt(0) | 0 none (last tile)
#define TILE32(WM)                                                             \
  {                                                                            \
    int aslot = s0 + wr;            if (aslot >= NSL) aslot -= NSL;            \
    int bslot = s0 + 2 + (wc >> 1); if (bslot >= NSL) bslot -= NSL;            \
    STAGE(); STAGE();                                                          \
    RD_B3(bfr)                                                                 \
    RD_A3(afA, 0)                                                              \
    MFMA16(afA, bfr, 0)                                                        \
    STAGE(); STAGE();                                                          \
    RD_A3(afB, 1)                                                              \
    MFMA16(afB, bfr, 1)                                                        \
    if ((WM) == 1) asm volatile("s_waitcnt vmcnt(8)" ::: "memory");            \
    if ((WM) == 2) asm volatile("s_waitcnt vmcnt(4)" ::: "memory");            \
    if ((WM) == 3) asm volatile("s_waitcnt vmcnt(0)" ::: "memory");            \
    if ((WM) != 0) {                                                           \
      __builtin_amdgcn_s_barrier();                                            \
      __builtin_amdgcn_sched_barrier(0);                                       \
    }                                                                          \
    s0 += 4; if (s0 >= NSL) s0 -= NSL;                                         \
  }

__global__ __launch_bounds__(512, 2)
void k_gemm256(const u16* __restrict__ A, const u16* __restrict__ B,
               const float* __restrict__ bias,
               float* __restrict__ C, int N, int K) {
  __shared__ __align__(16) u16 lds[NSL * 4096];   // 144 KiB
  const int tid = threadIdx.x, lane = tid & 63, wave = tid >> 6;
  int bid = blockIdx.y * gridDim.x + blockIdx.x;
  const int cpx = (gridDim.x * gridDim.y) >> 3;
  bid = (bid & 7) * cpx + (bid >> 3);
  const int nbx = N >> 8;
  const int bx = bid % nbx, by = bid / nbx;
  const int m0 = by << 8, n0 = bx << 8;
  const int wr = wave >> 2, wc = wave & 3;          // 2 x 4 wave grid
  const int srow = tid >> 2;
  const int sgc  = (tid & 3) ^ ((srow >> 1) & 3);
  const int c15 = lane & 15, lq = lane >> 4;
  const int gsw = lq ^ ((c15 >> 1) & 3);
  const int bq64 = (wc & 1) * 64;
  const int NT = K >> 5;                            // 128

  f32x4 acc[8][4] = {};
  bf16x8 afA[4], afB[4], bfr[4];

  int jn = 0, js = 0;
  auto STAGE = [&]() {
    if (jn < 4 * NT) {
      const int t = jn >> 2, q = jn & 3;
      const u16* srcb = (q < 2)
          ? A + (size_t)(m0 + q * 128 + srow) * (size_t)K
          : B + (size_t)(n0 + (q - 2) * 128 + srow) * (size_t)K;
      const u16* src = srcb + (t << 5) + sgc * 8;
      u16* dst = (u16*)lds + js * 4096 + tid * 8;
      __builtin_amdgcn_global_load_lds(
          (const AS1 void*)src, (AS3 void*)dst, 16, 0, 0);
    }
    ++jn; js = (js == NSL - 1) ? 0 : js + 1;
  };

#pragma unroll
  for (int i = 0; i < 12; ++i) STAGE();
  asm volatile("s_waitcnt vmcnt(8)" ::: "memory");
  __builtin_amdgcn_s_barrier();
  __builtin_amdgcn_sched_barrier(0);

  int s0 = 0;
  for (int tau = 0; tau < NT - 3; ++tau) {
    TILE32(1)
  }
  TILE32(2)
  TILE32(3)
  TILE32(0)

#pragma unroll
  for (int n = 0; n < 4; ++n) {
    const int col = n0 + wc * 64 + n * 16 + c15;
    const float bv = bias[col];
#pragma unroll
    for (int mi = 0; mi < 8; ++mi) {
      const int rowb = m0 + wr * 128 + mi * 16 + (lq << 2);
#pragma unroll
      for (int r = 0; r < 4; ++r)
        C[(size_t)(rowb + r) * N + col] = acc[mi][n][r] + bv;
    }
  }
}

extern "C" void kernel_launch(void* const* d_in, const int* in_sizes, int n_in,
                              void* d_out, int out_size, void* d_ws, size_t ws_size,
                              hipStream_t stream) {
  const float* W    = (const float*)d_in[0];   // [4096,4096]
  const float* bias = (const float*)d_in[1];   // [4096]
  const float* x    = (const float*)d_in[2];   // [4,2048,4096]
  const float* R    = (const float*)d_in[3];   // [8,512,512]
  float* out = (float*)d_out;

  char* ws = (char*)d_ws;
  u16* x_bf = (u16*)(ws);                      //  64 MiB
  u16* tw   = (u16*)(ws + 67108864);           //  32 MiB
  u16* W_bf = (u16*)(ws + 100663296);          //  32 MiB

  // scratch arena = d_out (128 MiB; fully overwritten by k_gemm256 at the end)
  char* arena = (char*)d_out;
  auto slot = [&](int i) -> u16* { return (u16*)(arena + (size_t)i * 4194304); };
  u16 *Mh = slot(0), *Ml = slot(1);
  u16 *G = slot(2), *G2 = slot(3), *G4 = slot(4);
  u16 *Xa = slot(5), *Xat = slot(6), *Xb = slot(7), *Xbt = slot(8);
  u16 *Xbl = slot(9), *Xbtl = slot(10);
  u16 *Tt = slot(2);                            // reuse G
  u16 *Tth = slot(3), *Ttl = slot(4);           // reuse G2, G4
  u16 *X6h = slot(5), *X6l = slot(6);           // reuse Xa/Xat (dead)
  u16 *X6th = slot(11), *X6tl = slot(12);
  u16 *Qt = slot(13);                           // Q transposed, bf16
  float* alpha = (float*)(arena + (size_t)15 * 4194304);
  float* cdv = alpha + 8;                       // 24 floats (3 iters x 8)
  float* csv = alpha + 40;                      // 24 floats

  const dim3 g8c(8, 8, 10);                     // z 8-9 = conversion planes
  const u16* NUL = nullptr;
  const float* NULF = nullptr;
  // conversion chunks: [0-3] = W (4 x 4194304), [4-11] = x (8 x 4194304)
  auto cvs = [&](int i) -> const float* {
    return i < 4 ? W + (size_t)i * 4194304 : x + (size_t)(i - 4) * 4194304;
  };
  auto cvd = [&](int i) -> u16* {
    return i < 4 ? W_bf + (size_t)i * 4194304 : x_bf + (size_t)(i - 4) * 4194304;
  };

  // 1) M pair
  k_build_M<<<dim3(16, 16, 8), 256, 0, stream>>>(R, Mh, Ml);
  // 2) G = M@M^T ; G2 = G@G^T ; G4 = G2@G2^T ; alpha + recenter schedule
  k_bmm<0, 0, 1><<<g8c, 256, 0, stream>>>(Mh, NUL, Mh, NUL, NUL, NUL,
                                          G, nullptr, nullptr, nullptr,
                                          0.f, 1.f, NULF, NULF, cvs(0), cvd(0));
  k_bmm<0, 0, 1><<<g8c, 256, 0, stream>>>(G, NUL, G, NUL, NUL, NUL,
                                          G2, nullptr, nullptr, nullptr,
                                          0.f, 1.f, NULF, NULF, cvs(1), cvd(1));
  k_bmm<0, 0, 1><<<g8c, 256, 0, stream>>>(G2, NUL, G2, NUL, NUL, NUL,
                                          G4, nullptr, nullptr, nullptr,
                                          0.f, 1.f, NULF, NULF, cvs(2), cvd(2));
  k_frob_alpha<<<8, 1024, 0, stream>>>(G4, alpha, cdv, csv);
  // 3) X0 pair
  k_init_X0<<<8192, 256, 0, stream>>>(Mh, Ml, alpha, Xa, Xat);

  // 4) Recentered Newton iters 1-2: T^T=(M@X)^T ; X' = c(2X - X@T) (+X'^T)
  u16 *cur = Xa, *curt = Xat, *nxt = Xb, *nxtt = Xbt;
  for (int it = 0; it < 2; ++it) {
    k_bmm<0, 0, 4><<<g8c, 256, 0, stream>>>(Mh, NUL, curt, NUL, NUL, NUL,
                                            nullptr, nullptr, Tt, nullptr,
                                            0.f, 1.f, NULF, NULF,
                                            cvs(3 + 2 * it), cvd(3 + 2 * it));
    k_bmm<0, 1, 5><<<g8c, 256, 0, stream>>>(cur, NUL, Tt, NUL, cur, NUL,
                                            nxt, nullptr, nxtt, nullptr,
                                            0.f, 0.f, cdv + it * 8, csv + it * 8,
                                            cvs(4 + 2 * it), cvd(4 + 2 * it));
    u16* t;
    t = cur; cur = nxt; nxt = t;
    t = curt; curt = nxtt; nxtt = t;
  }
  // iter 3 (recentered): write hi/lo pairs (normal + transposed) [cur==Xa]
  k_bmm<0, 0, 4><<<g8c, 256, 0, stream>>>(Mh, NUL, curt, NUL, NUL, NUL,
                                          nullptr, nullptr, Tt, nullptr,
                                          0.f, 1.f, NULF, NULF, cvs(7), cvd(7));
  k_bmm<0, 1, 15><<<g8c, 256, 0, stream>>>(cur, NUL, Tt, NUL, cur, NUL,
                                           Xb, Xbl, Xbt, Xbtl,
                                           0.f, 0.f, cdv + 16, csv + 16,
                                           cvs(8), cvd(8));
  // 5) split-precision polish: T^T pair ; X6 = 2X5 - X5@T (pairs)
  k_bmm<1, 0, 12><<<g8c, 256, 0, stream>>>(Mh, Ml, Xbt, Xbtl, NUL, NUL,
                                           nullptr, nullptr, Tth, Ttl,
                                           0.f, 1.f, NULF, NULF, cvs(9), cvd(9));
  k_bmm<1, 2, 15><<<g8c, 256, 0, stream>>>(Xb, Xbl, Tth, Ttl, Xb, Xbl,
                                           X6h, X6l, X6th, X6tl,
                                           2.f, -1.f, NULF, NULF, cvs(10), cvd(10));
  // 6) Q^T (bf16) = transpose of (2+1e-6)X6 - M@X6
  k_bmm<1, 2, 4><<<g8c, 256, 0, stream>>>(Mh, Ml, X6th, X6tl, X6h, X6l,
                                          nullptr, nullptr, Qt, nullptr,
                                          C1Q, -1.f, NULF, NULF, cvs(11), cvd(11));
  // 7) tw = W_bf @ blockdiag(Q)
  k_twmm<<<dim3(8, 64, 8), 256, 0, stream>>>(W_bf, Qt, tw);
  // 8) main GEMM (overwrites the arena)
  k_gemm256<<<dim3(16, 32), 512, 0, stream>>>(x_bf, tw, bias, out, 4096, 4096);
}

// Round 11
// 520.836 us; speedup vs baseline: 1.1197x; 1.0399x over previous
//
#include <hip/hip_runtime.h>
#include <hip/hip_bf16.h>

// EnhancedOFTLinearLayer: out = x @ (W @ blockdiag(cayley(R)))^T + bias
//   cayley(A): S = 0.5(A - A^T); Q = (I - S) @ inv((1+1e-6)I + S)
// Round 10: fix conversion side-channel indexing for 256-block (2-chunk)
// launches: chunk = zi>>7, base = (zi&127)*256+tid (round-9 version aliased
// chunk 0 and left chunk 1 unconverted -> 35% of x_bf was poison).
// Everything else identical to round 9 (algebraic Newton collapse).

typedef unsigned short u16;
typedef __attribute__((ext_vector_type(8))) __bf16 bf16x8;
typedef __attribute__((ext_vector_type(4))) float f32x4;
typedef __attribute__((ext_vector_type(8))) unsigned short u16x8;
typedef __attribute__((ext_vector_type(4))) unsigned short u16x4;

#define C0   1.000001f   /* 1 + 1e-6 */
#define C1Q  2.000001f   /* 1 + C0   */
#define AS1 __attribute__((address_space(1)))
#define AS3 __attribute__((address_space(3)))

__device__ __forceinline__ u16 f2bf(float x) {
  union { float f; unsigned u; } v; v.f = x;
  return (u16)((v.u + 0x7fffu + ((v.u >> 16) & 1u)) >> 16);
}
__device__ __forceinline__ float bf2f(u16 h) {
  union { float f; unsigned u; } v; v.u = ((unsigned)h) << 16; return v.f;
}

// ---------------- 1) M = (1+1e-6)I + 0.5(R - R^T) -> bf16 hi/lo pair --------
__global__ __launch_bounds__(256) void k_build_M(const float* __restrict__ R,
                                                 u16* __restrict__ Mh,
                                                 u16* __restrict__ Ml) {
  __shared__ float t1[32][33];
  const int n = blockIdx.z;
  const int tr = blockIdx.y * 32, tc = blockIdx.x * 32;
  const int ly = threadIdx.x >> 5, lx = threadIdx.x & 31;   // 8 x 32
  const float* Rb = R + (size_t)n * 262144;
  float a[4];
#pragma unroll
  for (int i = 0; i < 4; ++i) {
    a[i] = Rb[(size_t)(tr + ly + i * 8) * 512 + tc + lx];
    t1[ly + i * 8][lx] = Rb[(size_t)(tc + ly + i * 8) * 512 + tr + lx];
  }
  __syncthreads();
#pragma unroll
  for (int i = 0; i < 4; ++i) {
    const int r = tr + ly + i * 8, c = tc + lx;
    float m = 0.5f * (a[i] - t1[lx][ly + i * 8]) + (r == c ? C0 : 0.0f);
    u16 h = f2bf(m);
    const size_t idx = (size_t)n * 262144 + (size_t)r * 512 + c;
    Mh[idx] = h;
    Ml[idx] = f2bf(m - bf2f(h));
  }
}

// ------- 2b) alpha + recentered-Newton coefficient schedule (per batch) -----
// coef layout (floats): [0]=alpha [8]=2c1 [16]=-c1*a [24]=2c1a [32]=-c1*a^2
//                       [40]=2c2 [48]=-c2 [56]=2c3 [64]=-c3   (each x8)
__global__ __launch_bounds__(1024) void k_frob_alpha(const u16* __restrict__ G4,
                                                     float* __restrict__ coef) {
  __shared__ float red[16];
  const int n = blockIdx.x, tid = threadIdx.x;
  const u16* src = G4 + (size_t)n * 262144;
  float s = 0.f;
  for (int i = tid; i < 32768; i += 1024) {
    u16x8 v = reinterpret_cast<const u16x8*>(src)[i];
#pragma unroll
    for (int e = 0; e < 8; ++e) { float f = bf2f(v[e]); s += f * f; }
  }
  for (int off = 32; off; off >>= 1) s += __shfl_down(s, off, 64);
  if ((tid & 63) == 0) red[tid >> 6] = s;
  __syncthreads();
  if (tid == 0) {
    float t = 0.f;
    for (int q = 0; q < 16; ++q) t += red[q];
    float lam = powf(t, 0.125f);            // >= lambda_max(M^T M)
    float a = 2.0f / (C0 * C0 + lam);
    coef[n] = a;
    float e = (lam - C0 * C0) / (lam + C0 * C0);
    float sq = e * e;
    float c1 = 2.0f / (2.0f - sq);
    coef[8 + n]  = 2.0f * c1;
    coef[16 + n] = -c1 * a;
    coef[24 + n] = 2.0f * c1 * a;
    coef[32 + n] = -c1 * a * a;
    e = sq / (2.0f - sq);
    sq = e * e;
    float c2 = 2.0f / (2.0f - sq);
    coef[40 + n] = 2.0f * c2;
    coef[48 + n] = -c2;
    e = sq / (2.0f - sq);
    sq = e * e;
    float c3 = 2.0f / (2.0f - sq);
    coef[56 + n] = 2.0f * c3;
    coef[64 + n] = -c3;
  }
}

// ---- 3a) X0 = alpha*(2c0 I - M) ; T2 = (2c1a)*G + (-c1a^2)*G2 (elemwise) ---
__global__ __launch_bounds__(256) void k_init(const u16* __restrict__ Mh,
                                              const u16* __restrict__ Ml,
                                              const u16* __restrict__ G,
                                              const u16* __restrict__ G2,
                                              const float* __restrict__ coef,
                                              u16* __restrict__ X0,
                                              u16* __restrict__ T2) {
  int idx = blockIdx.x * 256 + threadIdx.x;
  int n = idx >> 18, r = (idx >> 9) & 511, c = idx & 511;
  float m = bf2f(Mh[idx]) + bf2f(Ml[idx]);
  X0[idx] = f2bf(coef[n] * ((r == c ? 2.0f * C0 : 0.0f) - m));
  T2[idx] = f2bf(coef[24 + n] * bf2f(G[idx]) + coef[32 + n] * bf2f(G2[idx]));
}

// ---------------- batched bf16 mm: C = cd*D + cs*(A @ B^T) ------------------
// grid (8,8,Z): z < zmm = mm batches (DUAL: z in [8,16) = second job);
// z >= zmm = f32->bf16 conversion side-channel. Each 2 planes (128 blocks)
// convert one 4M-elem chunk: chunk = zi>>7, base = (zi&127)*256+tid.
// 4-slot LDS ring, 2-step prefetch lead, counted vmcnt, 1 barrier/step.
// PROD3: split hi/lo 3-MFMA product. DMODE 0/1/2. OMODE bits 1/2/4/8.
#define BMM_FRAGS(rs)                                                          \
  bf16x8 a[2], b[2], al2[2], bl2[2];                                           \
  _Pragma("unroll")                                                            \
  for (int i = 0; i < 2; ++i) {                                                \
    const int fr = wr * 32 + i * 16 + c15;                                     \
    const int ia = (rs) * 2048 + fr * 32 + ((lk ^ (fr & 3)) * 8);              \
    a[i] = *reinterpret_cast<const bf16x8*>(&sA[ia]);                          \
    if constexpr (PROD3) al2[i] = *reinterpret_cast<const bf16x8*>(&sAl[ia]);  \
  }                                                                            \
  _Pragma("unroll")                                                            \
  for (int j = 0; j < 2; ++j) {                                                \
    const int fc = wc * 32 + j * 16 + c15;                                     \
    const int ib = (rs) * 2048 + fc * 32 + ((lk ^ (fc & 3)) * 8);              \
    b[j] = *reinterpret_cast<const bf16x8*>(&sB[ib]);                          \
    if constexpr (PROD3) bl2[j] = *reinterpret_cast<const bf16x8*>(&sBl[ib]);  \
  }                                                                            \
  _Pragma("unroll")                                                            \
  for (int i = 0; i < 2; ++i)                                                  \
    _Pragma("unroll")                                                          \
    for (int j = 0; j < 2; ++j) {                                              \
      acc[i][j] = __builtin_amdgcn_mfma_f32_16x16x32_bf16(a[i], b[j], acc[i][j], 0, 0, 0); \
      if constexpr (PROD3) {                                                   \
        acc[i][j] = __builtin_amdgcn_mfma_f32_16x16x32_bf16(a[i],   bl2[j], acc[i][j], 0, 0, 0); \
        acc[i][j] = __builtin_amdgcn_mfma_f32_16x16x32_bf16(al2[i], b[j],   acc[i][j], 0, 0, 0); \
      }                                                                        \
    }

#define BMM_WAIT(SEL)                                                          \
  if ((SEL) == 0) {                                                            \
    if constexpr (PROD3) asm volatile("s_waitcnt vmcnt(8)" ::: "memory");      \
    else                 asm volatile("s_waitcnt vmcnt(4)" ::: "memory");      \
  } else if ((SEL) == 1) {                                                     \
    if constexpr (PROD3) asm volatile("s_waitcnt vmcnt(4)" ::: "memory");      \
    else                 asm volatile("s_waitcnt vmcnt(2)" ::: "memory");      \
  } else {                                                                     \
    asm volatile("s_waitcnt vmcnt(0)" ::: "memory");                           \
  }

template <int PROD3, int DMODE, int OMODE, int DUAL>
__global__ __launch_bounds__(256)
void k_bmm(const u16* __restrict__ Ah, const u16* __restrict__ Al,
           const u16* __restrict__ Bh, const u16* __restrict__ Bl,
           const u16* __restrict__ Dh, const u16* __restrict__ Dl,
           u16* __restrict__ Cnh, u16* __restrict__ Cnl,
           u16* __restrict__ Cth, u16* __restrict__ Ctl,
           float cd, float cs,
           const float* __restrict__ cdp, const float* __restrict__ csp,
           const float* __restrict__ cvsrc, u16* __restrict__ cvdst, int zmm,
           const u16* __restrict__ A2, const u16* __restrict__ B2,
           const u16* __restrict__ D2, u16* __restrict__ C2) {
  __shared__ __align__(16) u16 sA[4 * 2048], sB[4 * 2048];
  __shared__ __align__(16) u16 sAl[PROD3 ? 4 * 2048 : 8];
  __shared__ __align__(16) u16 sBl[PROD3 ? 4 * 2048 : 8];

  if ((int)blockIdx.z >= zmm) {   // conversion side-channel
    const int zi = ((int)blockIdx.z - zmm) * 64 + blockIdx.y * 8 + blockIdx.x;
    const int chunk = zi >> 7;                     // 128 blocks per 4M chunk
    const int base = (zi & 127) * 256 + (int)threadIdx.x;
    const float* src = cvsrc + (size_t)chunk * 4194304;
    u16* dst = cvdst + (size_t)chunk * 4194304;
#pragma unroll
    for (int e = 0; e < 16; ++e) {
      const size_t g = (size_t)(base + e * 32768) * 8;
      float4 f0 = *reinterpret_cast<const float4*>(src + g);
      float4 f1 = *reinterpret_cast<const float4*>(src + g + 4);
      u16x8 w;
      w[0] = f2bf(f0.x); w[1] = f2bf(f0.y); w[2] = f2bf(f0.z); w[3] = f2bf(f0.w);
      w[4] = f2bf(f1.x); w[5] = f2bf(f1.y); w[6] = f2bf(f1.z); w[7] = f2bf(f1.w);
      *reinterpret_cast<u16x8*>(dst + g) = w;
    }
    return;
  }

  const int zq = DUAL ? ((blockIdx.z >> 3) & 1) : 0;   // 0: job A, 1: job B
  const u16* Ah_ = (DUAL && zq) ? A2 : Ah;
  const u16* Bh_ = (DUAL && zq) ? B2 : Bh;
  const u16* Dh_ = (DUAL && zq) ? D2 : Dh;
  u16* Cnh_ = (DUAL && zq) ? C2 : Cnh;
  const size_t zb = (size_t)(blockIdx.z & 7) * 262144;
  const int tid = threadIdx.x, lane = tid & 63, wave = tid >> 6;
  const int m0 = blockIdx.y * 64, n0 = blockIdx.x * 64;
  const int wr = wave >> 1, wc = wave & 1;
  const int c15 = lane & 15, lk = lane >> 4;
  const int srow = tid >> 2;
  const int sg = (tid & 3) ^ (srow & 3);            // granule-XOR (involution)
  f32x4 acc[2][2] = {};
  const u16* pa = Ah_ + zb + (size_t)(m0 + srow) * 512 + sg * 8;
  const u16* pb = Bh_ + zb + (size_t)(n0 + srow) * 512 + sg * 8;
  const u16* pal = PROD3 ? Al + zb + (size_t)(m0 + srow) * 512 + sg * 8 : pa;
  const u16* pbl = PROD3 ? Bl + zb + (size_t)(n0 + srow) * 512 + sg * 8 : pb;

  int jn = 0, js = 0;
  auto STG = [&]() {
    if (jn < 16) {
      const int off = jn << 5;
      __builtin_amdgcn_global_load_lds((const AS1 void*)(pa + off),
                                       (AS3 void*)(sA + js * 2048 + tid * 8), 16, 0, 0);
      __builtin_amdgcn_global_load_lds((const AS1 void*)(pb + off),
                                       (AS3 void*)(sB + js * 2048 + tid * 8), 16, 0, 0);
      if constexpr (PROD3) {
        __builtin_amdgcn_global_load_lds((const AS1 void*)(pal + off),
                                         (AS3 void*)(sAl + js * 2048 + tid * 8), 16, 0, 0);
        __builtin_amdgcn_global_load_lds((const AS1 void*)(pbl + off),
                                         (AS3 void*)(sBl + js * 2048 + tid * 8), 16, 0, 0);
      }
    }
    ++jn; js = (js + 1) & 3;
  };

  STG(); STG();                 // prefetch steps 0,1
  int rs = 0;
  for (int t = 0; t < 14; ++t) {
    STG();                      // stage step t+2
    BMM_WAIT(0)                 // step t landed (2 steps in flight)
    __builtin_amdgcn_s_barrier();
    BMM_FRAGS(rs)
    rs = (rs + 1) & 3;
  }
  STG();                        // no-op (jn=16)
  BMM_WAIT(1)
  __builtin_amdgcn_s_barrier();
  { BMM_FRAGS(rs) }
  rs = (rs + 1) & 3;
  STG();                        // no-op
  BMM_WAIT(2)
  __builtin_amdgcn_s_barrier();
  { BMM_FRAGS(rs) }

  const float cdL = cdp ? cdp[blockIdx.z & 7] : cd;
  const float csL = csp ? csp[blockIdx.z & 7] : cs;
  // epilogue (C/D map: col=lane&15, row=(lane>>4)*4+r)
#pragma unroll
  for (int i = 0; i < 2; ++i)
#pragma unroll
    for (int j = 0; j < 2; ++j) {
      const int rowb = m0 + wr * 32 + i * 16 + lk * 4;
      const int col  = n0 + wc * 32 + j * 16 + c15;
      u16 hv[4], lv[4];
#pragma unroll
      for (int r = 0; r < 4; ++r) {
        float val = csL * acc[i][j][r];
        if constexpr (DMODE >= 1) {
          float d = bf2f(Dh_[zb + (size_t)(rowb + r) * 512 + col]);
          if constexpr (DMODE == 2) d += bf2f(Dl[zb + (size_t)(rowb + r) * 512 + col]);
          val += cdL * d;
        }
        u16 h = f2bf(val);
        if constexpr (OMODE & 1) Cnh_[zb + (size_t)(rowb + r) * 512 + col] = h;
        u16 l = 0;
        if constexpr (OMODE & 10) l = f2bf(val - bf2f(h));
        if constexpr (OMODE & 2) Cnl[zb + (size_t)(rowb + r) * 512 + col] = l;
        hv[r] = h; lv[r] = l;
      }
      if constexpr (OMODE & 4) {
        u16x4 v; v[0] = hv[0]; v[1] = hv[1]; v[2] = hv[2]; v[3] = hv[3];
        *reinterpret_cast<u16x4*>(&Cth[zb + (size_t)col * 512 + rowb]) = v;
      }
      if constexpr (OMODE & 8) {
        u16x4 v; v[0] = lv[0]; v[1] = lv[1]; v[2] = lv[2]; v[3] = lv[3];
        *reinterpret_cast<u16x4*>(&Ctl[zb + (size_t)col * 512 + rowb]) = v;
      }
    }
}

// ---------------- tw = W_bf @ blockdiag(Q)  (via B = Qt, same ring) ---------
__global__ __launch_bounds__(256)
void k_twmm(const u16* __restrict__ W, const u16* __restrict__ Qt,
            u16* __restrict__ tw) {
  __shared__ __align__(16) u16 sA[4 * 2048], sB[4 * 2048];
  const int z = blockIdx.z;
  const size_t zb = (size_t)z * 262144;
  const int tid = threadIdx.x, lane = tid & 63, wave = tid >> 6;
  const int m0 = blockIdx.y * 64, n0 = blockIdx.x * 64;
  const int wr = wave >> 1, wc = wave & 1;
  const int c15 = lane & 15, lk = lane >> 4;
  const int srow = tid >> 2;
  const int sg = (tid & 3) ^ (srow & 3);
  f32x4 acc[2][2] = {};
  const u16* pa = W + (size_t)(m0 + srow) * 4096 + z * 512 + sg * 8;
  const u16* pb = Qt + zb + (size_t)(n0 + srow) * 512 + sg * 8;

  int jn = 0, js = 0;
  auto STG = [&]() {
    if (jn < 16) {
      const int off = jn << 5;
      __builtin_amdgcn_global_load_lds((const AS1 void*)(pa + off),
                                       (AS3 void*)(sA + js * 2048 + tid * 8), 16, 0, 0);
      __builtin_amdgcn_global_load_lds((const AS1 void*)(pb + off),
                                       (AS3 void*)(sB + js * 2048 + tid * 8), 16, 0, 0);
    }
    ++jn; js = (js + 1) & 3;
  };

#define TW_FRAGS(rs)                                                           \
  {                                                                            \
    bf16x8 a[2], b[2];                                                         \
    _Pragma("unroll")                                                          \
    for (int i = 0; i < 2; ++i) {                                              \
      const int fr = wr * 32 + i * 16 + c15;                                   \
      a[i] = *reinterpret_cast<const bf16x8*>(                                 \
          &sA[(rs) * 2048 + fr * 32 + ((lk ^ (fr & 3)) * 8)]);                 \
    }                                                                          \
    _Pragma("unroll")                                                          \
    for (int j = 0; j < 2; ++j) {                                              \
      const int fc = wc * 32 + j * 16 + c15;                                   \
      b[j] = *reinterpret_cast<const bf16x8*>(                                 \
          &sB[(rs) * 2048 + fc * 32 + ((lk ^ (fc & 3)) * 8)]);                 \
    }                                                                          \
    _Pragma("unroll")                                                          \
    for (int i = 0; i < 2; ++i)                                                \
      _Pragma("unroll")                                                        \
      for (int j = 0; j < 2; ++j)                                              \
        acc[i][j] = __builtin_amdgcn_mfma_f32_16x16x32_bf16(a[i], b[j], acc[i][j], 0, 0, 0); \
  }

  STG(); STG();
  int rs = 0;
  for (int t = 0; t < 14; ++t) {
    STG();
    asm volatile("s_waitcnt vmcnt(4)" ::: "memory");
    __builtin_amdgcn_s_barrier();
    TW_FRAGS(rs)
    rs = (rs + 1) & 3;
  }
  STG();
  asm volatile("s_waitcnt vmcnt(2)" ::: "memory");
  __builtin_amdgcn_s_barrier();
  TW_FRAGS(rs)
  rs = (rs + 1) & 3;
  STG();
  asm volatile("s_waitcnt vmcnt(0)" ::: "memory");
  __builtin_amdgcn_s_barrier();
  TW_FRAGS(rs)

#pragma unroll
  for (int i = 0; i < 2; ++i)
#pragma unroll
    for (int j = 0; j < 2; ++j) {
      const int rowb = m0 + wr * 32 + i * 16 + lk * 4;
      const int col  = z * 512 + n0 + wc * 32 + j * 16 + c15;
#pragma unroll
      for (int r = 0; r < 4; ++r)
        tw[(size_t)(rowb + r) * 4096 + col] = f2bf(acc[i][j][r]);
    }
}

// ---------------- out = x_bf @ tw^T + bias (round-6, verbatim) --------------
#define NSL 18

#define RD_A3(dst, MH)                                                         \
  _Pragma("unroll")                                                            \
  for (int m = 0; m < 4; ++m)                                                  \
    dst[m] = *reinterpret_cast<const bf16x8*>(                                 \
        &lds[aslot * 4096 + ((MH) * 64 + m * 16 + c15) * 32 + gsw * 8]);

#define RD_B3(dst)                                                             \
  _Pragma("unroll")                                                            \
  for (int n = 0; n < 4; ++n)                                                  \
    dst[n] = *reinterpret_cast<const bf16x8*>(                                 \
        &lds[bslot * 4096 + (bq64 + n * 16 + c15) * 32 + gsw * 8]);

#define MFMA16(afX, bfX, MH)                                                   \
  __builtin_amdgcn_s_setprio(1);                                               \
  _Pragma("unroll")                                                            \
  for (int m = 0; m < 4; ++m)                                                  \
    _Pragma("unroll")                                                          \
    for (int n = 0; n < 4; ++n)                                                \
      acc[(MH) * 4 + m][n] = __builtin_amdgcn_mfma_f32_16x16x32_bf16(          \
          afX[m], bfX[n], acc[(MH) * 4 + m][n], 0, 0, 0);                      \
  __builtin_amdgcn_s_setprio(0);

// WM: 1 steady vmcnt(8) | 2 vmcnt(4) | 3 vmcnt(0) | 0 none (last tile)
#define TILE32(WM)                                                             \
  {                                                                            \
    int aslot = s0 + wr;            if (aslot >= NSL) aslot -= NSL;            \
    int bslot = s0 + 2 + (wc >> 1); if (bslot >= NSL) bslot -= NSL;            \
    STAGE(); STAGE();                                                          \
    RD_B3(bfr)                                                                 \
    RD_A3(afA, 0)                                                              \
    MFMA16(afA, bfr, 0)                                                        \
    STAGE(); STAGE();                                                          \
    RD_A3(afB, 1)                                                              \
    MFMA16(afB, bfr, 1)                                                        \
    if ((WM) == 1) asm volatile("s_waitcnt vmcnt(8)" ::: "memory");            \
    if ((WM) == 2) asm volatile("s_waitcnt vmcnt(4)" ::: "memory");            \
    if ((WM) == 3) asm volatile("s_waitcnt vmcnt(0)" ::: "memory");            \
    if ((WM) != 0) {                                                           \
      __builtin_amdgcn_s_barrier();                                            \
      __builtin_amdgcn_sched_barrier(0);                                       \
    }                                                                          \
    s0 += 4; if (s0 >= NSL) s0 -= NSL;                                         \
  }

__global__ __launch_bounds__(512, 2)
void k_gemm256(const u16* __restrict__ A, const u16* __restrict__ B,
               const float* __restrict__ bias,
               float* __restrict__ C, int N, int K) {
  __shared__ __align__(16) u16 lds[NSL * 4096];   // 144 KiB
  const int tid = threadIdx.x, lane = tid & 63, wave = tid >> 6;
  int bid = blockIdx.y * gridDim.x + blockIdx.x;
  const int cpx = (gridDim.x * gridDim.y) >> 3;
  bid = (bid & 7) * cpx + (bid >> 3);
  const int nbx = N >> 8;
  const int bx = bid % nbx, by = bid / nbx;
  const int m0 = by << 8, n0 = bx << 8;
  const int wr = wave >> 2, wc = wave & 3;          // 2 x 4 wave grid
  const int srow = tid >> 2;
  const int sgc  = (tid & 3) ^ ((srow >> 1) & 3);
  const int c15 = lane & 15, lq = lane >> 4;
  const int gsw = lq ^ ((c15 >> 1) & 3);
  const int bq64 = (wc & 1) * 64;
  const int NT = K >> 5;                            // 128

  f32x4 acc[8][4] = {};
  bf16x8 afA[4], afB[4], bfr[4];

  int jn = 0, js = 0;
  auto STAGE = [&]() {
    if (jn < 4 * NT) {
      const int t = jn >> 2, q = jn & 3;
      const u16* srcb = (q < 2)
          ? A + (size_t)(m0 + q * 128 + srow) * (size_t)K
          : B + (size_t)(n0 + (q - 2) * 128 + srow) * (size_t)K;
      const u16* src = srcb + (t << 5) + sgc * 8;
      u16* dst = (u16*)lds + js * 4096 + tid * 8;
      __builtin_amdgcn_global_load_lds(
          (const AS1 void*)src, (AS3 void*)dst, 16, 0, 0);
    }
    ++jn; js = (js == NSL - 1) ? 0 : js + 1;
  };

#pragma unroll
  for (int i = 0; i < 12; ++i) STAGE();
  asm volatile("s_waitcnt vmcnt(8)" ::: "memory");
  __builtin_amdgcn_s_barrier();
  __builtin_amdgcn_sched_barrier(0);

  int s0 = 0;
  for (int tau = 0; tau < NT - 3; ++tau) {
    TILE32(1)
  }
  TILE32(2)
  TILE32(3)
  TILE32(0)

#pragma unroll
  for (int n = 0; n < 4; ++n) {
    const int col = n0 + wc * 64 + n * 16 + c15;
    const float bv = bias[col];
#pragma unroll
    for (int mi = 0; mi < 8; ++mi) {
      const int rowb = m0 + wr * 128 + mi * 16 + (lq << 2);
#pragma unroll
      for (int r = 0; r < 4; ++r)
        C[(size_t)(rowb + r) * N + col] = acc[mi][n][r] + bv;
    }
  }
}

extern "C" void kernel_launch(void* const* d_in, const int* in_sizes, int n_in,
                              void* d_out, int out_size, void* d_ws, size_t ws_size,
                              hipStream_t stream) {
  const float* W    = (const float*)d_in[0];   // [4096,4096]
  const float* bias = (const float*)d_in[1];   // [4096]
  const float* x    = (const float*)d_in[2];   // [4,2048,4096]
  const float* R    = (const float*)d_in[3];   // [8,512,512]
  float* out = (float*)d_out;

  char* ws = (char*)d_ws;
  u16* x_bf = (u16*)(ws);                      //  64 MiB
  u16* tw   = (u16*)(ws + 67108864);           //  32 MiB
  u16* W_bf = (u16*)(ws + 100663296);          //  32 MiB

  // scratch arena = d_out (128 MiB; fully overwritten by k_gemm256)
  char* arena = (char*)d_out;
  auto slot = [&](int i) -> u16* { return (u16*)(arena + (size_t)i * 4194304); };
  u16 *Mh = slot(0), *Ml = slot(1);
  u16 *G = slot(2), *G2 = slot(3), *G4 = slot(4);
  u16 *X0 = slot(5), *T2 = slot(6), *X1 = slot(7), *X2 = slot(8), *T3 = slot(9);
  u16 *X3h = slot(10), *X3l = slot(11), *X3th = slot(12), *X3tl = slot(13);
  u16 *Tpth = slot(14), *Tptl = slot(15);
  u16 *X4h = slot(16), *X4l = slot(17), *X4th = slot(18), *X4tl = slot(19);
  u16 *Qt = slot(20);
  float* coef = (float*)(arena + (size_t)21 * 4194304);   // 72 floats

  const u16* NUL = nullptr;
  const float* NULF = nullptr;
  u16* NULW = nullptr;
  const dim3 gC1(8, 8, 10);     // 8 mm batches + 2 conv planes (1 chunk)
  const dim3 gC2(8, 8, 12);     // 8 mm + 4 conv planes (2 chunks)

  // 1) M pair
  k_build_M<<<dim3(16, 16, 8), 256, 0, stream>>>(R, Mh, Ml);
  // 2) G = M@M^T ; G2 = G@G^T ; G4 = G2@G2^T  (+ W conversion chunks 0-2)
  k_bmm<0, 0, 1, 0><<<gC1, 256, 0, stream>>>(Mh, NUL, Mh, NUL, NUL, NUL,
      G, NULW, NULW, NULW, 0.f, 1.f, NULF, NULF, W, W_bf, 8, NUL, NUL, NUL, NULW);
  k_bmm<0, 0, 1, 0><<<gC1, 256, 0, stream>>>(G, NUL, G, NUL, NUL, NUL,
      G2, NULW, NULW, NULW, 0.f, 1.f, NULF, NULF,
      W + 4194304, W_bf + 4194304, 8, NUL, NUL, NUL, NULW);
  k_bmm<0, 0, 1, 0><<<gC1, 256, 0, stream>>>(G2, NUL, G2, NUL, NUL, NUL,
      G4, NULW, NULW, NULW, 0.f, 1.f, NULF, NULF,
      W + 2 * 4194304, W_bf + 2 * 4194304, 8, NUL, NUL, NUL, NULW);
  // 3) coefficients ; X0 + T2 (elementwise)
  k_frob_alpha<<<8, 1024, 0, stream>>>(G4, coef);
  k_init<<<8192, 256, 0, stream>>>(Mh, Ml, G, G2, coef, X0, T2);
  // 4) X1 = 2c1*X0 - c1*a*(X0@G)   [T1 = a*G, free]  (+ W chunk 3)
  k_bmm<0, 1, 1, 0><<<gC1, 256, 0, stream>>>(X0, NUL, G, NUL, X0, NUL,
      X1, NULW, NULW, NULW, 0.f, 0.f, coef + 8, coef + 16,
      W + 3 * 4194304, W_bf + 3 * 4194304, 8, NUL, NUL, NUL, NULW);
  // 5) DUAL: X2 = 2c2*X1 - c2*(X1@T2)  ||  T3 = 2c2*T2 - c2*(T2@T2)
  //    (+ x chunks 0-1)
  k_bmm<0, 1, 1, 1><<<dim3(8, 8, 20), 256, 0, stream>>>(X1, NUL, T2, NUL, X1, NUL,
      X2, NULW, NULW, NULW, 0.f, 0.f, coef + 40, coef + 48,
      x, x_bf, 16, T2, T2, T2, T3);
  // 6) X3 = 2c3*X2 - c3*(X2@T3), pairs + transposed pairs  (+ x chunks 2-3)
  k_bmm<0, 1, 15, 0><<<gC2, 256, 0, stream>>>(X2, NUL, T3, NUL, X2, NUL,
      X3h, X3l, X3th, X3tl, 0.f, 0.f, coef + 56, coef + 64,
      x + (size_t)2 * 4194304, x_bf + (size_t)2 * 4194304, 8, NUL, NUL, NUL, NULW);
  // 7) split polish: Tp^T = (M@X3)^T pairs  (+ x chunks 4-5)
  k_bmm<1, 0, 12, 0><<<gC2, 256, 0, stream>>>(Mh, Ml, X3th, X3tl, NUL, NUL,
      NULW, NULW, Tpth, Tptl, 0.f, 1.f, NULF, NULF,
      x + (size_t)4 * 4194304, x_bf + (size_t)4 * 4194304, 8, NUL, NUL, NUL, NULW);
  //    X4 = 2*X3 - X3@Tp, pairs + transposed pairs  (+ x chunk 6)
  k_bmm<1, 2, 15, 0><<<gC1, 256, 0, stream>>>(X3h, X3l, Tpth, Tptl, X3h, X3l,
      X4h, X4l, X4th, X4tl, 2.f, -1.f, NULF, NULF,
      x + (size_t)6 * 4194304, x_bf + (size_t)6 * 4194304, 8, NUL, NUL, NUL, NULW);
  // 8) Q^T = transpose of (2+1e-6)X4 - M@X4  (+ x chunk 7)
  k_bmm<1, 2, 4, 0><<<gC1, 256, 0, stream>>>(Mh, Ml, X4th, X4tl, X4h, X4l,
      NULW, NULW, Qt, NULW, C1Q, -1.f, NULF, NULF,
      x + (size_t)7 * 4194304, x_bf + (size_t)7 * 4194304, 8, NUL, NUL, NUL, NULW);
  // 9) tw = W_bf @ blockdiag(Q) ; main GEMM (overwrites the arena)
  k_twmm<<<dim3(8, 64, 8), 256, 0, stream>>>(W_bf, Qt, tw);
  k_gemm256<<<dim3(16, 32), 512, 0, stream>>>(x_bf, tw, bias, out, 4096, 4096);
}

// Round 14
// 502.884 us; speedup vs baseline: 1.1596x; 1.0357x over previous
//
#include <hip/hip_runtime.h>
#include <hip/hip_bf16.h>

// EnhancedOFTLinearLayer: out = x @ (W @ blockdiag(cayley(R)))^T + bias
//   cayley(A): S = 0.5(A - A^T); Q = (I - S) @ inv((1+1e-6)I + S)
// Round 13: revert to the round-10 multi-launch structure (known good) and
// drop the G4 launch: lambda bound from ||G2||_F^2 = tr(G^4) (G2 is needed
// for T2 anyway -> bound is free). 14 -> 13 launches. Conversion chunks
// redistributed. All kernels byte-identical to round 10.

typedef unsigned short u16;
typedef __attribute__((ext_vector_type(8))) __bf16 bf16x8;
typedef __attribute__((ext_vector_type(4))) float f32x4;
typedef __attribute__((ext_vector_type(8))) unsigned short u16x8;
typedef __attribute__((ext_vector_type(4))) unsigned short u16x4;

#define C0   1.000001f   /* 1 + 1e-6 */
#define C1Q  2.000001f   /* 1 + C0   */
#define AS1 __attribute__((address_space(1)))
#define AS3 __attribute__((address_space(3)))

__device__ __forceinline__ u16 f2bf(float x) {
  union { float f; unsigned u; } v; v.f = x;
  return (u16)((v.u + 0x7fffu + ((v.u >> 16) & 1u)) >> 16);
}
__device__ __forceinline__ float bf2f(u16 h) {
  union { float f; unsigned u; } v; v.u = ((unsigned)h) << 16; return v.f;
}

// ---------------- 1) M = (1+1e-6)I + 0.5(R - R^T) -> bf16 hi/lo pair --------
__global__ __launch_bounds__(256) void k_build_M(const float* __restrict__ R,
                                                 u16* __restrict__ Mh,
                                                 u16* __restrict__ Ml) {
  __shared__ float t1[32][33];
  const int n = blockIdx.z;
  const int tr = blockIdx.y * 32, tc = blockIdx.x * 32;
  const int ly = threadIdx.x >> 5, lx = threadIdx.x & 31;   // 8 x 32
  const float* Rb = R + (size_t)n * 262144;
  float a[4];
#pragma unroll
  for (int i = 0; i < 4; ++i) {
    a[i] = Rb[(size_t)(tr + ly + i * 8) * 512 + tc + lx];
    t1[ly + i * 8][lx] = Rb[(size_t)(tc + ly + i * 8) * 512 + tr + lx];
  }
  __syncthreads();
#pragma unroll
  for (int i = 0; i < 4; ++i) {
    const int r = tr + ly + i * 8, c = tc + lx;
    float m = 0.5f * (a[i] - t1[lx][ly + i * 8]) + (r == c ? C0 : 0.0f);
    u16 h = f2bf(m);
    const size_t idx = (size_t)n * 262144 + (size_t)r * 512 + c;
    Mh[idx] = h;
    Ml[idx] = f2bf(m - bf2f(h));
  }
}

// ------- 2b) alpha + recentered-Newton coefficient schedule (per batch) -----
// lam_hat = (||G2||_F^2)^(1/4) = tr(G^4)^(1/4) >= lambda_max(M^T M)
// coef layout (floats): [0]=alpha [8]=2c1 [16]=-c1*a [24]=2c1a [32]=-c1*a^2
//                       [40]=2c2 [48]=-c2 [56]=2c3 [64]=-c3   (each x8)
__global__ __launch_bounds__(1024) void k_frob_alpha(const u16* __restrict__ G2,
                                                     float* __restrict__ coef) {
  __shared__ float red[16];
  const int n = blockIdx.x, tid = threadIdx.x;
  const u16* src = G2 + (size_t)n * 262144;
  float s = 0.f;
  for (int i = tid; i < 32768; i += 1024) {
    u16x8 v = reinterpret_cast<const u16x8*>(src)[i];
#pragma unroll
    for (int e = 0; e < 8; ++e) { float f = bf2f(v[e]); s += f * f; }
  }
  for (int off = 32; off; off >>= 1) s += __shfl_down(s, off, 64);
  if ((tid & 63) == 0) red[tid >> 6] = s;
  __syncthreads();
  if (tid == 0) {
    float t = 0.f;
    for (int q = 0; q < 16; ++q) t += red[q];
    float lam = powf(t, 0.25f);             // >= lambda_max(M^T M)
    float a = 2.0f / (C0 * C0 + lam);
    coef[n] = a;
    float e = (lam - C0 * C0) / (lam + C0 * C0);
    float sq = e * e;
    float c1 = 2.0f / (2.0f - sq);
    coef[8 + n]  = 2.0f * c1;
    coef[16 + n] = -c1 * a;
    coef[24 + n] = 2.0f * c1 * a;
    coef[32 + n] = -c1 * a * a;
    e = sq / (2.0f - sq);
    sq = e * e;
    float c2 = 2.0f / (2.0f - sq);
    coef[40 + n] = 2.0f * c2;
    coef[48 + n] = -c2;
    e = sq / (2.0f - sq);
    sq = e * e;
    float c3 = 2.0f / (2.0f - sq);
    coef[56 + n] = 2.0f * c3;
    coef[64 + n] = -c3;
  }
}

// ---- 3a) X0 = alpha*(2c0 I - M) ; T2 = (2c1a)*G + (-c1a^2)*G2 (elemwise) ---
__global__ __launch_bounds__(256) void k_init(const u16* __restrict__ Mh,
                                              const u16* __restrict__ Ml,
                                              const u16* __restrict__ G,
                                              const u16* __restrict__ G2,
                                              const float* __restrict__ coef,
                                              u16* __restrict__ X0,
                                              u16* __restrict__ T2) {
  int idx = blockIdx.x * 256 + threadIdx.x;
  int n = idx >> 18, r = (idx >> 9) & 511, c = idx & 511;
  float m = bf2f(Mh[idx]) + bf2f(Ml[idx]);
  X0[idx] = f2bf(coef[n] * ((r == c ? 2.0f * C0 : 0.0f) - m));
  T2[idx] = f2bf(coef[24 + n] * bf2f(G[idx]) + coef[32 + n] * bf2f(G2[idx]));
}

// ---------------- batched bf16 mm: C = cd*D + cs*(A @ B^T) ------------------
// grid (8,8,Z): z < zmm = mm batches (DUAL: z in [8,16) = second job);
// z >= zmm = f32->bf16 conversion side-channel. Each 2 planes (128 blocks)
// convert one 4M-elem chunk: chunk = zi>>7, base = (zi&127)*256+tid.
// 4-slot LDS ring, 2-step prefetch lead, counted vmcnt, 1 barrier/step.
// PROD3: split hi/lo 3-MFMA product. DMODE 0/1/2. OMODE bits 1/2/4/8.
#define BMM_FRAGS(rs)                                                          \
  bf16x8 a[2], b[2], al2[2], bl2[2];                                           \
  _Pragma("unroll")                                                            \
  for (int i = 0; i < 2; ++i) {                                                \
    const int fr = wr * 32 + i * 16 + c15;                                     \
    const int ia = (rs) * 2048 + fr * 32 + ((lk ^ (fr & 3)) * 8);              \
    a[i] = *reinterpret_cast<const bf16x8*>(&sA[ia]);                          \
    if constexpr (PROD3) al2[i] = *reinterpret_cast<const bf16x8*>(&sAl[ia]);  \
  }                                                                            \
  _Pragma("unroll")                                                            \
  for (int j = 0; j < 2; ++j) {                                                \
    const int fc = wc * 32 + j * 16 + c15;                                     \
    const int ib = (rs) * 2048 + fc * 32 + ((lk ^ (fc & 3)) * 8);              \
    b[j] = *reinterpret_cast<const bf16x8*>(&sB[ib]);                          \
    if constexpr (PROD3) bl2[j] = *reinterpret_cast<const bf16x8*>(&sBl[ib]);  \
  }                                                                            \
  _Pragma("unroll")                                                            \
  for (int i = 0; i < 2; ++i)                                                  \
    _Pragma("unroll")                                                          \
    for (int j = 0; j < 2; ++j) {                                              \
      acc[i][j] = __builtin_amdgcn_mfma_f32_16x16x32_bf16(a[i], b[j], acc[i][j], 0, 0, 0); \
      if constexpr (PROD3) {                                                   \
        acc[i][j] = __builtin_amdgcn_mfma_f32_16x16x32_bf16(a[i],   bl2[j], acc[i][j], 0, 0, 0); \
        acc[i][j] = __builtin_amdgcn_mfma_f32_16x16x32_bf16(al2[i], b[j],   acc[i][j], 0, 0, 0); \
      }                                                                        \
    }

#define BMM_WAIT(SEL)                                                          \
  if ((SEL) == 0) {                                                            \
    if constexpr (PROD3) asm volatile("s_waitcnt vmcnt(8)" ::: "memory");      \
    else                 asm volatile("s_waitcnt vmcnt(4)" ::: "memory");      \
  } else if ((SEL) == 1) {                                                     \
    if constexpr (PROD3) asm volatile("s_waitcnt vmcnt(4)" ::: "memory");      \
    else                 asm volatile("s_waitcnt vmcnt(2)" ::: "memory");      \
  } else {                                                                     \
    asm volatile("s_waitcnt vmcnt(0)" ::: "memory");                           \
  }

template <int PROD3, int DMODE, int OMODE, int DUAL>
__global__ __launch_bounds__(256)
void k_bmm(const u16* __restrict__ Ah, const u16* __restrict__ Al,
           const u16* __restrict__ Bh, const u16* __restrict__ Bl,
           const u16* __restrict__ Dh, const u16* __restrict__ Dl,
           u16* __restrict__ Cnh, u16* __restrict__ Cnl,
           u16* __restrict__ Cth, u16* __restrict__ Ctl,
           float cd, float cs,
           const float* __restrict__ cdp, const float* __restrict__ csp,
           const float* __restrict__ cvsrc, u16* __restrict__ cvdst, int zmm,
           const u16* __restrict__ A2, const u16* __restrict__ B2,
           const u16* __restrict__ D2, u16* __restrict__ C2) {
  __shared__ __align__(16) u16 sA[4 * 2048], sB[4 * 2048];
  __shared__ __align__(16) u16 sAl[PROD3 ? 4 * 2048 : 8];
  __shared__ __align__(16) u16 sBl[PROD3 ? 4 * 2048 : 8];

  if ((int)blockIdx.z >= zmm) {   // conversion side-channel
    const int zi = ((int)blockIdx.z - zmm) * 64 + blockIdx.y * 8 + blockIdx.x;
    const int chunk = zi >> 7;                     // 128 blocks per 4M chunk
    const int base = (zi & 127) * 256 + (int)threadIdx.x;
    const float* src = cvsrc + (size_t)chunk * 4194304;
    u16* dst = cvdst + (size_t)chunk * 4194304;
#pragma unroll
    for (int e = 0; e < 16; ++e) {
      const size_t g = (size_t)(base + e * 32768) * 8;
      float4 f0 = *reinterpret_cast<const float4*>(src + g);
      float4 f1 = *reinterpret_cast<const float4*>(src + g + 4);
      u16x8 w;
      w[0] = f2bf(f0.x); w[1] = f2bf(f0.y); w[2] = f2bf(f0.z); w[3] = f2bf(f0.w);
      w[4] = f2bf(f1.x); w[5] = f2bf(f1.y); w[6] = f2bf(f1.z); w[7] = f2bf(f1.w);
      *reinterpret_cast<u16x8*>(dst + g) = w;
    }
    return;
  }

  const int zq = DUAL ? ((blockIdx.z >> 3) & 1) : 0;   // 0: job A, 1: job B
  const u16* Ah_ = (DUAL && zq) ? A2 : Ah;
  const u16* Bh_ = (DUAL && zq) ? B2 : Bh;
  const u16* Dh_ = (DUAL && zq) ? D2 : Dh;
  u16* Cnh_ = (DUAL && zq) ? C2 : Cnh;
  const size_t zb = (size_t)(blockIdx.z & 7) * 262144;
  const int tid = threadIdx.x, lane = tid & 63, wave = tid >> 6;
  const int m0 = blockIdx.y * 64, n0 = blockIdx.x * 64;
  const int wr = wave >> 1, wc = wave & 1;
  const int c15 = lane & 15, lk = lane >> 4;
  const int srow = tid >> 2;
  const int sg = (tid & 3) ^ (srow & 3);            // granule-XOR (involution)
  f32x4 acc[2][2] = {};
  const u16* pa = Ah_ + zb + (size_t)(m0 + srow) * 512 + sg * 8;
  const u16* pb = Bh_ + zb + (size_t)(n0 + srow) * 512 + sg * 8;
  const u16* pal = PROD3 ? Al + zb + (size_t)(m0 + srow) * 512 + sg * 8 : pa;
  const u16* pbl = PROD3 ? Bl + zb + (size_t)(n0 + srow) * 512 + sg * 8 : pb;

  int jn = 0, js = 0;
  auto STG = [&]() {
    if (jn < 16) {
      const int off = jn << 5;
      __builtin_amdgcn_global_load_lds((const AS1 void*)(pa + off),
                                       (AS3 void*)(sA + js * 2048 + tid * 8), 16, 0, 0);
      __builtin_amdgcn_global_load_lds((const AS1 void*)(pb + off),
                                       (AS3 void*)(sB + js * 2048 + tid * 8), 16, 0, 0);
      if constexpr (PROD3) {
        __builtin_amdgcn_global_load_lds((const AS1 void*)(pal + off),
                                         (AS3 void*)(sAl + js * 2048 + tid * 8), 16, 0, 0);
        __builtin_amdgcn_global_load_lds((const AS1 void*)(pbl + off),
                                         (AS3 void*)(sBl + js * 2048 + tid * 8), 16, 0, 0);
      }
    }
    ++jn; js = (js + 1) & 3;
  };

  STG(); STG();                 // prefetch steps 0,1
  int rs = 0;
  for (int t = 0; t < 14; ++t) {
    STG();                      // stage step t+2
    BMM_WAIT(0)                 // step t landed (2 steps in flight)
    __builtin_amdgcn_s_barrier();
    BMM_FRAGS(rs)
    rs = (rs + 1) & 3;
  }
  STG();                        // no-op (jn=16)
  BMM_WAIT(1)
  __builtin_amdgcn_s_barrier();
  { BMM_FRAGS(rs) }
  rs = (rs + 1) & 3;
  STG();                        // no-op
  BMM_WAIT(2)
  __builtin_amdgcn_s_barrier();
  { BMM_FRAGS(rs) }

  const float cdL = cdp ? cdp[blockIdx.z & 7] : cd;
  const float csL = csp ? csp[blockIdx.z & 7] : cs;
  // epilogue (C/D map: col=lane&15, row=(lane>>4)*4+r)
#pragma unroll
  for (int i = 0; i < 2; ++i)
#pragma unroll
    for (int j = 0; j < 2; ++j) {
      const int rowb = m0 + wr * 32 + i * 16 + lk * 4;
      const int col  = n0 + wc * 32 + j * 16 + c15;
      u16 hv[4], lv[4];
#pragma unroll
      for (int r = 0; r < 4; ++r) {
        float val = csL * acc[i][j][r];
        if constexpr (DMODE >= 1) {
          float d = bf2f(Dh_[zb + (size_t)(rowb + r) * 512 + col]);
          if constexpr (DMODE == 2) d += bf2f(Dl[zb + (size_t)(rowb + r) * 512 + col]);
          val += cdL * d;
        }
        u16 h = f2bf(val);
        if constexpr (OMODE & 1) Cnh_[zb + (size_t)(rowb + r) * 512 + col] = h;
        u16 l = 0;
        if constexpr (OMODE & 10) l = f2bf(val - bf2f(h));
        if constexpr (OMODE & 2) Cnl[zb + (size_t)(rowb + r) * 512 + col] = l;
        hv[r] = h; lv[r] = l;
      }
      if constexpr (OMODE & 4) {
        u16x4 v; v[0] = hv[0]; v[1] = hv[1]; v[2] = hv[2]; v[3] = hv[3];
        *reinterpret_cast<u16x4*>(&Cth[zb + (size_t)col * 512 + rowb]) = v;
      }
      if constexpr (OMODE & 8) {
        u16x4 v; v[0] = lv[0]; v[1] = lv[1]; v[2] = lv[2]; v[3] = lv[3];
        *reinterpret_cast<u16x4*>(&Ctl[zb + (size_t)col * 512 + rowb]) = v;
      }
    }
}

// ---------------- tw = W_bf @ blockdiag(Q)  (via B = Qt, same ring) ---------
__global__ __launch_bounds__(256)
void k_twmm(const u16* __restrict__ W, const u16* __restrict__ Qt,
            u16* __restrict__ tw) {
  __shared__ __align__(16) u16 sA[4 * 2048], sB[4 * 2048];
  const int z = blockIdx.z;
  const size_t zb = (size_t)z * 262144;
  const int tid = threadIdx.x, lane = tid & 63, wave = tid >> 6;
  const int m0 = blockIdx.y * 64, n0 = blockIdx.x * 64;
  const int wr = wave >> 1, wc = wave & 1;
  const int c15 = lane & 15, lk = lane >> 4;
  const int srow = tid >> 2;
  const int sg = (tid & 3) ^ (srow & 3);
  f32x4 acc[2][2] = {};
  const u16* pa = W + (size_t)(m0 + srow) * 4096 + z * 512 + sg * 8;
  const u16* pb = Qt + zb + (size_t)(n0 + srow) * 512 + sg * 8;

  int jn = 0, js = 0;
  auto STG = [&]() {
    if (jn < 16) {
      const int off = jn << 5;
      __builtin_amdgcn_global_load_lds((const AS1 void*)(pa + off),
                                       (AS3 void*)(sA + js * 2048 + tid * 8), 16, 0, 0);
      __builtin_amdgcn_global_load_lds((const AS1 void*)(pb + off),
                                       (AS3 void*)(sB + js * 2048 + tid * 8), 16, 0, 0);
    }
    ++jn; js = (js + 1) & 3;
  };

#define TW_FRAGS(rs)                                                           \
  {                                                                            \
    bf16x8 a[2], b[2];                                                         \
    _Pragma("unroll")                                                          \
    for (int i = 0; i < 2; ++i) {                                              \
      const int fr = wr * 32 + i * 16 + c15;                                   \
      a[i] = *reinterpret_cast<const bf16x8*>(                                 \
          &sA[(rs) * 2048 + fr * 32 + ((lk ^ (fr & 3)) * 8)]);                 \
    }                                                                          \
    _Pragma("unroll")                                                          \
    for (int j = 0; j < 2; ++j) {                                              \
      const int fc = wc * 32 + j * 16 + c15;                                   \
      b[j] = *reinterpret_cast<const bf16x8*>(                                 \
          &sB[(rs) * 2048 + fc * 32 + ((lk ^ (fc & 3)) * 8)]);                 \
    }                                                                          \
    _Pragma("unroll")                                                          \
    for (int i = 0; i < 2; ++i)                                                \
      _Pragma("unroll")                                                        \
      for (int j = 0; j < 2; ++j)                                              \
        acc[i][j] = __builtin_amdgcn_mfma_f32_16x16x32_bf16(a[i], b[j], acc[i][j], 0, 0, 0); \
  }

  STG(); STG();
  int rs = 0;
  for (int t = 0; t < 14; ++t) {
    STG();
    asm volatile("s_waitcnt vmcnt(4)" ::: "memory");
    __builtin_amdgcn_s_barrier();
    TW_FRAGS(rs)
    rs = (rs + 1) & 3;
  }
  STG();
  asm volatile("s_waitcnt vmcnt(2)" ::: "memory");
  __builtin_amdgcn_s_barrier();
  TW_FRAGS(rs)
  rs = (rs + 1) & 3;
  STG();
  asm volatile("s_waitcnt vmcnt(0)" ::: "memory");
  __builtin_amdgcn_s_barrier();
  TW_FRAGS(rs)

#pragma unroll
  for (int i = 0; i < 2; ++i)
#pragma unroll
    for (int j = 0; j < 2; ++j) {
      const int rowb = m0 + wr * 32 + i * 16 + lk * 4;
      const int col  = z * 512 + n0 + wc * 32 + j * 16 + c15;
#pragma unroll
      for (int r = 0; r < 4; ++r)
        tw[(size_t)(rowb + r) * 4096 + col] = f2bf(acc[i][j][r]);
    }
}

// ---------------- out = x_bf @ tw^T + bias (round-6, verbatim) --------------
#define NSL 18

#define RD_A3(dst, MH)                                                         \
  _Pragma("unroll")                                                            \
  for (int m = 0; m < 4; ++m)                                                  \
    dst[m] = *reinterpret_cast<const bf16x8*>(                                 \
        &lds[aslot * 4096 + ((MH) * 64 + m * 16 + c15) * 32 + gsw * 8]);

#define RD_B3(dst)                                                             \
  _Pragma("unroll")                                                            \
  for (int n = 0; n < 4; ++n)                                                  \
    dst[n] = *reinterpret_cast<const bf16x8*>(                                 \
        &lds[bslot * 4096 + (bq64 + n * 16 + c15) * 32 + gsw * 8]);

#define MFMA16(afX, bfX, MH)                                                   \
  __builtin_amdgcn_s_setprio(1);                                               \
  _Pragma("unroll")                                                            \
  for (int m = 0; m < 4; ++m)                                                  \
    _Pragma("unroll")                                                          \
    for (int n = 0; n < 4; ++n)                                                \
      acc[(MH) * 4 + m][n] = __builtin_amdgcn_mfma_f32_16x16x32_bf16(          \
          afX[m], bfX[n], acc[(MH) * 4 + m][n], 0, 0, 0);                      \
  __builtin_amdgcn_s_setprio(0);

// WM: 1 steady vmcnt(8) | 2 vmcnt(4) | 3 vmcnt(0) | 0 none (last tile)
#define TILE32(WM)                                                             \
  {                                                                            \
    int aslot = s0 + wr;            if (aslot >= NSL) aslot -= NSL;            \
    int bslot = s0 + 2 + (wc >> 1); if (bslot >= NSL) bslot -= NSL;            \
    STAGE(); STAGE();                                                          \
    RD_B3(bfr)                                                                 \
    RD_A3(afA, 0)                                                              \
    MFMA16(afA, bfr, 0)                                                        \
    STAGE(); STAGE();                                                          \
    RD_A3(afB, 1)                                                              \
    MFMA16(afB, bfr, 1)                                                        \
    if ((WM) == 1) asm volatile("s_waitcnt vmcnt(8)" ::: "memory");            \
    if ((WM) == 2) asm volatile("s_waitcnt vmcnt(4)" ::: "memory");            \
    if ((WM) == 3) asm volatile("s_waitcnt vmcnt(0)" ::: "memory");            \
    if ((WM) != 0) {                                                           \
      __builtin_amdgcn_s_barrier();                                            \
      __builtin_amdgcn_sched_barrier(0);                                       \
    }                                                                          \
    s0 += 4; if (s0 >= NSL) s0 -= NSL;                                         \
  }

__global__ __launch_bounds__(512, 2)
void k_gemm256(const u16* __restrict__ A, const u16* __restrict__ B,
               const float* __restrict__ bias,
               float* __restrict__ C, int N, int K) {
  __shared__ __align__(16) u16 lds[NSL * 4096];   // 144 KiB
  const int tid = threadIdx.x, lane = tid & 63, wave = tid >> 6;
  int bid = blockIdx.y * gridDim.x + blockIdx.x;
  const int cpx = (gridDim.x * gridDim.y) >> 3;
  bid = (bid & 7) * cpx + (bid >> 3);
  const int nbx = N >> 8;
  const int bx = bid % nbx, by = bid / nbx;
  const int m0 = by << 8, n0 = bx << 8;
  const int wr = wave >> 2, wc = wave & 3;          // 2 x 4 wave grid
  const int srow = tid >> 2;
  const int sgc  = (tid & 3) ^ ((srow >> 1) & 3);
  const int c15 = lane & 15, lq = lane >> 4;
  const int gsw = lq ^ ((c15 >> 1) & 3);
  const int bq64 = (wc & 1) * 64;
  const int NT = K >> 5;                            // 128

  f32x4 acc[8][4] = {};
  bf16x8 afA[4], afB[4], bfr[4];

  int jn = 0, js = 0;
  auto STAGE = [&]() {
    if (jn < 4 * NT) {
      const int t = jn >> 2, q = jn & 3;
      const u16* srcb = (q < 2)
          ? A + (size_t)(m0 + q * 128 + srow) * (size_t)K
          : B + (size_t)(n0 + (q - 2) * 128 + srow) * (size_t)K;
      const u16* src = srcb + (t << 5) + sgc * 8;
      u16* dst = (u16*)lds + js * 4096 + tid * 8;
      __builtin_amdgcn_global_load_lds(
          (const AS1 void*)src, (AS3 void*)dst, 16, 0, 0);
    }
    ++jn; js = (js == NSL - 1) ? 0 : js + 1;
  };

#pragma unroll
  for (int i = 0; i < 12; ++i) STAGE();
  asm volatile("s_waitcnt vmcnt(8)" ::: "memory");
  __builtin_amdgcn_s_barrier();
  __builtin_amdgcn_sched_barrier(0);

  int s0 = 0;
  for (int tau = 0; tau < NT - 3; ++tau) {
    TILE32(1)
  }
  TILE32(2)
  TILE32(3)
  TILE32(0)

#pragma unroll
  for (int n = 0; n < 4; ++n) {
    const int col = n0 + wc * 64 + n * 16 + c15;
    const float bv = bias[col];
#pragma unroll
    for (int mi = 0; mi < 8; ++mi) {
      const int rowb = m0 + wr * 128 + mi * 16 + (lq << 2);
#pragma unroll
      for (int r = 0; r < 4; ++r)
        C[(size_t)(rowb + r) * N + col] = acc[mi][n][r] + bv;
    }
  }
}

extern "C" void kernel_launch(void* const* d_in, const int* in_sizes, int n_in,
                              void* d_out, int out_size, void* d_ws, size_t ws_size,
                              hipStream_t stream) {
  const float* W    = (const float*)d_in[0];   // [4096,4096]
  const float* bias = (const float*)d_in[1];   // [4096]
  const float* x    = (const float*)d_in[2];   // [4,2048,4096]
  const float* R    = (const float*)d_in[3];   // [8,512,512]
  float* out = (float*)d_out;

  char* ws = (char*)d_ws;
  u16* x_bf = (u16*)(ws);                      //  64 MiB
  u16* tw   = (u16*)(ws + 67108864);           //  32 MiB
  u16* W_bf = (u16*)(ws + 100663296);          //  32 MiB

  // scratch arena = d_out (128 MiB; fully overwritten by k_gemm256)
  char* arena = (char*)d_out;
  auto slot = [&](int i) -> u16* { return (u16*)(arena + (size_t)i * 4194304); };
  u16 *Mh = slot(0), *Ml = slot(1);
  u16 *G = slot(2), *G2 = slot(3);
  u16 *X0 = slot(5), *T2 = slot(6), *X1 = slot(7), *X2 = slot(8), *T3 = slot(9);
  u16 *X3h = slot(10), *X3l = slot(11), *X3th = slot(12), *X3tl = slot(13);
  u16 *Tpth = slot(14), *Tptl = slot(15);
  u16 *X4h = slot(16), *X4l = slot(17), *X4th = slot(18), *X4tl = slot(19);
  u16 *Qt = slot(20);
  float* coef = (float*)(arena + (size_t)21 * 4194304);   // 72 floats

  const u16* NUL = nullptr;
  const float* NULF = nullptr;
  u16* NULW = nullptr;
  const dim3 gC0(8, 8, 8);      // 8 mm batches, no conversion planes
  const dim3 gC2(8, 8, 12);     // 8 mm + 4 conv planes (2 chunks)

  // 1) M pair
  k_build_M<<<dim3(16, 16, 8), 256, 0, stream>>>(R, Mh, Ml);
  // 2) G = M@M^T (+ W chunks 0,1) ; G2 = G@G^T (+ W chunks 2,3)
  k_bmm<0, 0, 1, 0><<<gC2, 256, 0, stream>>>(Mh, NUL, Mh, NUL, NUL, NUL,
      G, NULW, NULW, NULW, 0.f, 1.f, NULF, NULF, W, W_bf, 8, NUL, NUL, NUL, NULW);
  k_bmm<0, 0, 1, 0><<<gC2, 256, 0, stream>>>(G, NUL, G, NUL, NUL, NUL,
      G2, NULW, NULW, NULW, 0.f, 1.f, NULF, NULF,
      W + (size_t)2 * 4194304, W_bf + (size_t)2 * 4194304, 8, NUL, NUL, NUL, NULW);
  // 3) coefficients from tr(G^4) = ||G2||_F^2 ; X0 + T2 (elementwise)
  k_frob_alpha<<<8, 1024, 0, stream>>>(G2, coef);
  k_init<<<8192, 256, 0, stream>>>(Mh, Ml, G, G2, coef, X0, T2);
  // 4) X1 = 2c1*X0 - c1*a*(X0@G)   [T1 = a*G, free]  (+ x chunks 0,1)
  k_bmm<0, 1, 1, 0><<<gC2, 256, 0, stream>>>(X0, NUL, G, NUL, X0, NUL,
      X1, NULW, NULW, NULW, 0.f, 0.f, coef + 8, coef + 16,
      x, x_bf, 8, NUL, NUL, NUL, NULW);
  // 5) DUAL: X2 = 2c2*X1 - c2*(X1@T2)  ||  T3 = 2c2*T2 - c2*(T2@T2)
  //    (+ x chunks 2,3)
  k_bmm<0, 1, 1, 1><<<dim3(8, 8, 20), 256, 0, stream>>>(X1, NUL, T2, NUL, X1, NUL,
      X2, NULW, NULW, NULW, 0.f, 0.f, coef + 40, coef + 48,
      x + (size_t)2 * 4194304, x_bf + (size_t)2 * 4194304, 16, T2, T2, T2, T3);
  // 6) X3 = 2c3*X2 - c3*(X2@T3), pairs + transposed pairs  (+ x chunks 4,5)
  k_bmm<0, 1, 15, 0><<<gC2, 256, 0, stream>>>(X2, NUL, T3, NUL, X2, NUL,
      X3h, X3l, X3th, X3tl, 0.f, 0.f, coef + 56, coef + 64,
      x + (size_t)4 * 4194304, x_bf + (size_t)4 * 4194304, 8, NUL, NUL, NUL, NULW);
  // 7) split polish: Tp^T = (M@X3)^T pairs  (+ x chunks 6,7)
  k_bmm<1, 0, 12, 0><<<gC2, 256, 0, stream>>>(Mh, Ml, X3th, X3tl, NUL, NUL,
      NULW, NULW, Tpth, Tptl, 0.f, 1.f, NULF, NULF,
      x + (size_t)6 * 4194304, x_bf + (size_t)6 * 4194304, 8, NUL, NUL, NUL, NULW);
  //    X4 = 2*X3 - X3@Tp, pairs + transposed pairs
  k_bmm<1, 2, 15, 0><<<gC0, 256, 0, stream>>>(X3h, X3l, Tpth, Tptl, X3h, X3l,
      X4h, X4l, X4th, X4tl, 2.f, -1.f, NULF, NULF,
      x, x_bf, 8, NUL, NUL, NUL, NULW);
  // 8) Q^T = transpose of (2+1e-6)X4 - M@X4
  k_bmm<1, 2, 4, 0><<<gC0, 256, 0, stream>>>(Mh, Ml, X4th, X4tl, X4h, X4l,
      NULW, NULW, Qt, NULW, C1Q, -1.f, NULF, NULF,
      x, x_bf, 8, NUL, NUL, NUL, NULW);
  // 9) tw = W_bf @ blockdiag(Q) ; main GEMM (overwrites the arena)
  k_twmm<<<dim3(8, 64, 8), 256, 0, stream>>>(W_bf, Qt, tw);
  k_gemm256<<<dim3(16, 32), 512, 0, stream>>>(x_bf, tw, bias, out, 4096, 4096);
}

// Round 15
// 488.631 us; speedup vs baseline: 1.1935x; 1.0292x over previous
//
#include <hip/hip_runtime.h>
#include <hip/hip_bf16.h>

// EnhancedOFTLinearLayer: out = x @ (W @ blockdiag(cayley(R)))^T + bias
//   cayley(A): S = 0.5(A - A^T); Q = (I - S) @ inv((1+1e-6)I + S)
// Round 14: fold Frobenius reduction into the G2 launch epilogue (per-tile
// deterministic partials) and compute coefficients inside k_init -- deletes
// the k_frob_alpha launch and its G2 re-read. k_init vectorized (8 elem/thr).
// All other kernels byte-identical to round 13.

typedef unsigned short u16;
typedef __attribute__((ext_vector_type(8))) __bf16 bf16x8;
typedef __attribute__((ext_vector_type(4))) float f32x4;
typedef __attribute__((ext_vector_type(8))) unsigned short u16x8;
typedef __attribute__((ext_vector_type(4))) unsigned short u16x4;

#define C0   1.000001f   /* 1 + 1e-6 */
#define C1Q  2.000001f   /* 1 + C0   */
#define AS1 __attribute__((address_space(1)))
#define AS3 __attribute__((address_space(3)))

__device__ __forceinline__ u16 f2bf(float x) {
  union { float f; unsigned u; } v; v.f = x;
  return (u16)((v.u + 0x7fffu + ((v.u >> 16) & 1u)) >> 16);
}
__device__ __forceinline__ float bf2f(u16 h) {
  union { float f; unsigned u; } v; v.u = ((unsigned)h) << 16; return v.f;
}

// ------- recentered-Newton coefficient cascade from t = tr(G^4) -------------
// lam_hat = t^(1/4) >= lambda_max(M^T M)
// C[0]=a C[1]=2c1 C[2]=-c1*a C[3]=2c1a C[4]=-c1a^2 C[5]=2c2 C[6]=-c2
// C[7]=2c3 C[8]=-c3
__device__ __forceinline__ void get_coefs(float t, float* C) {
  float lam = powf(t, 0.25f);
  float a = 2.0f / (C0 * C0 + lam);
  float e = (lam - C0 * C0) / (lam + C0 * C0);
  float sq = e * e, c1 = 2.0f / (2.0f - sq);
  C[0] = a; C[1] = 2.0f * c1; C[2] = -c1 * a;
  C[3] = 2.0f * c1 * a; C[4] = -c1 * a * a;
  e = sq / (2.0f - sq); sq = e * e;
  float c2 = 2.0f / (2.0f - sq);
  C[5] = 2.0f * c2; C[6] = -c2;
  e = sq / (2.0f - sq); sq = e * e;
  float c3 = 2.0f / (2.0f - sq);
  C[7] = 2.0f * c3; C[8] = -c3;
}

// ---------------- 1) M = (1+1e-6)I + 0.5(R - R^T) -> bf16 hi/lo pair --------
__global__ __launch_bounds__(256) void k_build_M(const float* __restrict__ R,
                                                 u16* __restrict__ Mh,
                                                 u16* __restrict__ Ml) {
  __shared__ float t1[32][33];
  const int n = blockIdx.z;
  const int tr = blockIdx.y * 32, tc = blockIdx.x * 32;
  const int ly = threadIdx.x >> 5, lx = threadIdx.x & 31;   // 8 x 32
  const float* Rb = R + (size_t)n * 262144;
  float a[4];
#pragma unroll
  for (int i = 0; i < 4; ++i) {
    a[i] = Rb[(size_t)(tr + ly + i * 8) * 512 + tc + lx];
    t1[ly + i * 8][lx] = Rb[(size_t)(tc + ly + i * 8) * 512 + tr + lx];
  }
  __syncthreads();
#pragma unroll
  for (int i = 0; i < 4; ++i) {
    const int r = tr + ly + i * 8, c = tc + lx;
    float m = 0.5f * (a[i] - t1[lx][ly + i * 8]) + (r == c ? C0 : 0.0f);
    u16 h = f2bf(m);
    const size_t idx = (size_t)n * 262144 + (size_t)r * 512 + c;
    Mh[idx] = h;
    Ml[idx] = f2bf(m - bf2f(h));
  }
}

// ---- 3a) k_init: coefs from part[] + X0 = a(2c0 I - M) ; T2 elementwise ----
// 1024 blocks x 256 thr, 8 elems/thread. Each block: fixed-order sum of its
// batch's 64 tile partials -> coef cascade (redundant identical publishes).
__global__ __launch_bounds__(256) void k_init(const u16* __restrict__ Mh,
                                              const u16* __restrict__ Ml,
                                              const u16* __restrict__ G,
                                              const u16* __restrict__ G2,
                                              const float* __restrict__ part,
                                              float* __restrict__ coef,
                                              u16* __restrict__ X0,
                                              u16* __restrict__ T2) {
  __shared__ float sp[64];
  __shared__ float sc[9];
  const int n = blockIdx.x >> 7;              // 128 blocks per batch
  if (threadIdx.x < 64) sp[threadIdx.x] = part[n * 64 + threadIdx.x];
  __syncthreads();
  if (threadIdx.x == 0) {
    float s = 0.f;
    for (int i = 0; i < 64; ++i) s += sp[i];  // fixed order: deterministic
    float C[9];
    get_coefs(s, C);
#pragma unroll
    for (int k = 0; k < 9; ++k) sc[k] = C[k];
    coef[n] = C[0];
    coef[8 + n]  = C[1]; coef[16 + n] = C[2];
    coef[24 + n] = C[3]; coef[32 + n] = C[4];
    coef[40 + n] = C[5]; coef[48 + n] = C[6];
    coef[56 + n] = C[7]; coef[64 + n] = C[8];
  }
  __syncthreads();
  const size_t base = ((size_t)blockIdx.x * 256 + threadIdx.x) * 8;
  const int r  = (int)((base >> 9) & 511);
  const int c0 = (int)(base & 511);
  u16x8 mh = *reinterpret_cast<const u16x8*>(Mh + base);
  u16x8 ml = *reinterpret_cast<const u16x8*>(Ml + base);
  u16x8 g  = *reinterpret_cast<const u16x8*>(G  + base);
  u16x8 g2 = *reinterpret_cast<const u16x8*>(G2 + base);
  u16x8 x0, t2;
#pragma unroll
  for (int e = 0; e < 8; ++e) {
    float m = bf2f(mh[e]) + bf2f(ml[e]);
    x0[e] = f2bf(sc[0] * ((r == c0 + e ? 2.0f * C0 : 0.0f) - m));
    t2[e] = f2bf(sc[3] * bf2f(g[e]) + sc[4] * bf2f(g2[e]));
  }
  *reinterpret_cast<u16x8*>(X0 + base) = x0;
  *reinterpret_cast<u16x8*>(T2 + base) = t2;
}

// ---------------- batched bf16 mm: C = cd*D + cs*(A @ B^T) ------------------
// grid (8,8,Z): z < zmm = mm batches (DUAL: z in [8,16) = second job);
// z >= zmm = f32->bf16 conversion side-channel. Each 2 planes (128 blocks)
// convert one 4M-elem chunk: chunk = zi>>7, base = (zi&127)*256+tid.
// 4-slot LDS ring, 2-step prefetch lead, counted vmcnt, 1 barrier/step.
// PROD3: split hi/lo 3-MFMA product. DMODE 0/1/2. OMODE bits 1/2/4/8.
// FROB: epilogue also writes per-tile sum of (bf16 output)^2 to part[].
#define BMM_FRAGS(rs)                                                          \
  bf16x8 a[2], b[2], al2[2], bl2[2];                                           \
  _Pragma("unroll")                                                            \
  for (int i = 0; i < 2; ++i) {                                                \
    const int fr = wr * 32 + i * 16 + c15;                                     \
    const int ia = (rs) * 2048 + fr * 32 + ((lk ^ (fr & 3)) * 8);              \
    a[i] = *reinterpret_cast<const bf16x8*>(&sA[ia]);                          \
    if constexpr (PROD3) al2[i] = *reinterpret_cast<const bf16x8*>(&sAl[ia]);  \
  }                                                                            \
  _Pragma("unroll")                                                            \
  for (int j = 0; j < 2; ++j) {                                                \
    const int fc = wc * 32 + j * 16 + c15;                                     \
    const int ib = (rs) * 2048 + fc * 32 + ((lk ^ (fc & 3)) * 8);              \
    b[j] = *reinterpret_cast<const bf16x8*>(&sB[ib]);                          \
    if constexpr (PROD3) bl2[j] = *reinterpret_cast<const bf16x8*>(&sBl[ib]);  \
  }                                                                            \
  _Pragma("unroll")                                                            \
  for (int i = 0; i < 2; ++i)                                                  \
    _Pragma("unroll")                                                          \
    for (int j = 0; j < 2; ++j) {                                              \
      acc[i][j] = __builtin_amdgcn_mfma_f32_16x16x32_bf16(a[i], b[j], acc[i][j], 0, 0, 0); \
      if constexpr (PROD3) {                                                   \
        acc[i][j] = __builtin_amdgcn_mfma_f32_16x16x32_bf16(a[i],   bl2[j], acc[i][j], 0, 0, 0); \
        acc[i][j] = __builtin_amdgcn_mfma_f32_16x16x32_bf16(al2[i], b[j],   acc[i][j], 0, 0, 0); \
      }                                                                        \
    }

#define BMM_WAIT(SEL)                                                          \
  if ((SEL) == 0) {                                                            \
    if constexpr (PROD3) asm volatile("s_waitcnt vmcnt(8)" ::: "memory");      \
    else                 asm volatile("s_waitcnt vmcnt(4)" ::: "memory");      \
  } else if ((SEL) == 1) {                                                     \
    if constexpr (PROD3) asm volatile("s_waitcnt vmcnt(4)" ::: "memory");      \
    else                 asm volatile("s_waitcnt vmcnt(2)" ::: "memory");      \
  } else {                                                                     \
    asm volatile("s_waitcnt vmcnt(0)" ::: "memory");                           \
  }

template <int PROD3, int DMODE, int OMODE, int DUAL, int FROB>
__global__ __launch_bounds__(256)
void k_bmm(const u16* __restrict__ Ah, const u16* __restrict__ Al,
           const u16* __restrict__ Bh, const u16* __restrict__ Bl,
           const u16* __restrict__ Dh, const u16* __restrict__ Dl,
           u16* __restrict__ Cnh, u16* __restrict__ Cnl,
           u16* __restrict__ Cth, u16* __restrict__ Ctl,
           float cd, float cs,
           const float* __restrict__ cdp, const float* __restrict__ csp,
           const float* __restrict__ cvsrc, u16* __restrict__ cvdst, int zmm,
           const u16* __restrict__ A2, const u16* __restrict__ B2,
           const u16* __restrict__ D2, u16* __restrict__ C2,
           float* __restrict__ part) {
  __shared__ __align__(16) u16 sA[4 * 2048], sB[4 * 2048];
  __shared__ __align__(16) u16 sAl[PROD3 ? 4 * 2048 : 8];
  __shared__ __align__(16) u16 sBl[PROD3 ? 4 * 2048 : 8];
  __shared__ float fred[FROB ? 4 : 1];

  if ((int)blockIdx.z >= zmm) {   // conversion side-channel
    const int zi = ((int)blockIdx.z - zmm) * 64 + blockIdx.y * 8 + blockIdx.x;
    const int chunk = zi >> 7;                     // 128 blocks per 4M chunk
    const int base = (zi & 127) * 256 + (int)threadIdx.x;
    const float* src = cvsrc + (size_t)chunk * 4194304;
    u16* dst = cvdst + (size_t)chunk * 4194304;
#pragma unroll
    for (int e = 0; e < 16; ++e) {
      const size_t g = (size_t)(base + e * 32768) * 8;
      float4 f0 = *reinterpret_cast<const float4*>(src + g);
      float4 f1 = *reinterpret_cast<const float4*>(src + g + 4);
      u16x8 w;
      w[0] = f2bf(f0.x); w[1] = f2bf(f0.y); w[2] = f2bf(f0.z); w[3] = f2bf(f0.w);
      w[4] = f2bf(f1.x); w[5] = f2bf(f1.y); w[6] = f2bf(f1.z); w[7] = f2bf(f1.w);
      *reinterpret_cast<u16x8*>(dst + g) = w;
    }
    return;
  }

  const int zq = DUAL ? ((blockIdx.z >> 3) & 1) : 0;   // 0: job A, 1: job B
  const u16* Ah_ = (DUAL && zq) ? A2 : Ah;
  const u16* Bh_ = (DUAL && zq) ? B2 : Bh;
  const u16* Dh_ = (DUAL && zq) ? D2 : Dh;
  u16* Cnh_ = (DUAL && zq) ? C2 : Cnh;
  const size_t zb = (size_t)(blockIdx.z & 7) * 262144;
  const int tid = threadIdx.x, lane = tid & 63, wave = tid >> 6;
  const int m0 = blockIdx.y * 64, n0 = blockIdx.x * 64;
  const int wr = wave >> 1, wc = wave & 1;
  const int c15 = lane & 15, lk = lane >> 4;
  const int srow = tid >> 2;
  const int sg = (tid & 3) ^ (srow & 3);            // granule-XOR (involution)
  f32x4 acc[2][2] = {};
  const u16* pa = Ah_ + zb + (size_t)(m0 + srow) * 512 + sg * 8;
  const u16* pb = Bh_ + zb + (size_t)(n0 + srow) * 512 + sg * 8;
  const u16* pal = PROD3 ? Al + zb + (size_t)(m0 + srow) * 512 + sg * 8 : pa;
  const u16* pbl = PROD3 ? Bl + zb + (size_t)(n0 + srow) * 512 + sg * 8 : pb;

  int jn = 0, js = 0;
  auto STG = [&]() {
    if (jn < 16) {
      const int off = jn << 5;
      __builtin_amdgcn_global_load_lds((const AS1 void*)(pa + off),
                                       (AS3 void*)(sA + js * 2048 + tid * 8), 16, 0, 0);
      __builtin_amdgcn_global_load_lds((const AS1 void*)(pb + off),
                                       (AS3 void*)(sB + js * 2048 + tid * 8), 16, 0, 0);
      if constexpr (PROD3) {
        __builtin_amdgcn_global_load_lds((const AS1 void*)(pal + off),
                                         (AS3 void*)(sAl + js * 2048 + tid * 8), 16, 0, 0);
        __builtin_amdgcn_global_load_lds((const AS1 void*)(pbl + off),
                                         (AS3 void*)(sBl + js * 2048 + tid * 8), 16, 0, 0);
      }
    }
    ++jn; js = (js + 1) & 3;
  };

  STG(); STG();                 // prefetch steps 0,1
  int rs = 0;
  for (int t = 0; t < 14; ++t) {
    STG();                      // stage step t+2
    BMM_WAIT(0)                 // step t landed (2 steps in flight)
    __builtin_amdgcn_s_barrier();
    BMM_FRAGS(rs)
    rs = (rs + 1) & 3;
  }
  STG();                        // no-op (jn=16)
  BMM_WAIT(1)
  __builtin_amdgcn_s_barrier();
  { BMM_FRAGS(rs) }
  rs = (rs + 1) & 3;
  STG();                        // no-op
  BMM_WAIT(2)
  __builtin_amdgcn_s_barrier();
  { BMM_FRAGS(rs) }

  const float cdL = cdp ? cdp[blockIdx.z & 7] : cd;
  const float csL = csp ? csp[blockIdx.z & 7] : cs;
  float fs = 0.f;
  // epilogue (C/D map: col=lane&15, row=(lane>>4)*4+r)
#pragma unroll
  for (int i = 0; i < 2; ++i)
#pragma unroll
    for (int j = 0; j < 2; ++j) {
      const int rowb = m0 + wr * 32 + i * 16 + lk * 4;
      const int col  = n0 + wc * 32 + j * 16 + c15;
      u16 hv[4], lv[4];
#pragma unroll
      for (int r = 0; r < 4; ++r) {
        float val = csL * acc[i][j][r];
        if constexpr (DMODE >= 1) {
          float d = bf2f(Dh_[zb + (size_t)(rowb + r) * 512 + col]);
          if constexpr (DMODE == 2) d += bf2f(Dl[zb + (size_t)(rowb + r) * 512 + col]);
          val += cdL * d;
        }
        u16 h = f2bf(val);
        if constexpr (OMODE & 1) Cnh_[zb + (size_t)(rowb + r) * 512 + col] = h;
        if constexpr (FROB) { float v = bf2f(h); fs += v * v; }
        u16 l = 0;
        if constexpr (OMODE & 10) l = f2bf(val - bf2f(h));
        if constexpr (OMODE & 2) Cnl[zb + (size_t)(rowb + r) * 512 + col] = l;
        hv[r] = h; lv[r] = l;
      }
      if constexpr (OMODE & 4) {
        u16x4 v; v[0] = hv[0]; v[1] = hv[1]; v[2] = hv[2]; v[3] = hv[3];
        *reinterpret_cast<u16x4*>(&Cth[zb + (size_t)col * 512 + rowb]) = v;
      }
      if constexpr (OMODE & 8) {
        u16x4 v; v[0] = lv[0]; v[1] = lv[1]; v[2] = lv[2]; v[3] = lv[3];
        *reinterpret_cast<u16x4*>(&Ctl[zb + (size_t)col * 512 + rowb]) = v;
      }
    }
  if constexpr (FROB) {
    for (int off = 32; off; off >>= 1) fs += __shfl_down(fs, off, 64);
    if ((tid & 63) == 0) fred[tid >> 6] = fs;
    __syncthreads();
    if (tid == 0)
      part[(blockIdx.z & 7) * 64 + blockIdx.y * 8 + blockIdx.x] =
          fred[0] + fred[1] + fred[2] + fred[3];
  }
}

// ---------------- tw = W_bf @ blockdiag(Q)  (via B = Qt, same ring) ---------
__global__ __launch_bounds__(256)
void k_twmm(const u16* __restrict__ W, const u16* __restrict__ Qt,
            u16* __restrict__ tw) {
  __shared__ __align__(16) u16 sA[4 * 2048], sB[4 * 2048];
  const int z = blockIdx.z;
  const size_t zb = (size_t)z * 262144;
  const int tid = threadIdx.x, lane = tid & 63, wave = tid >> 6;
  const int m0 = blockIdx.y * 64, n0 = blockIdx.x * 64;
  const int wr = wave >> 1, wc = wave & 1;
  const int c15 = lane & 15, lk = lane >> 4;
  const int srow = tid >> 2;
  const int sg = (tid & 3) ^ (srow & 3);
  f32x4 acc[2][2] = {};
  const u16* pa = W + (size_t)(m0 + srow) * 4096 + z * 512 + sg * 8;
  const u16* pb = Qt + zb + (size_t)(n0 + srow) * 512 + sg * 8;

  int jn = 0, js = 0;
  auto STG = [&]() {
    if (jn < 16) {
      const int off = jn << 5;
      __builtin_amdgcn_global_load_lds((const AS1 void*)(pa + off),
                                       (AS3 void*)(sA + js * 2048 + tid * 8), 16, 0, 0);
      __builtin_amdgcn_global_load_lds((const AS1 void*)(pb + off),
                                       (AS3 void*)(sB + js * 2048 + tid * 8), 16, 0, 0);
    }
    ++jn; js = (js + 1) & 3;
  };

#define TW_FRAGS(rs)                                                           \
  {                                                                            \
    bf16x8 a[2], b[2];                                                         \
    _Pragma("unroll")                                                          \
    for (int i = 0; i < 2; ++i) {                                              \
      const int fr = wr * 32 + i * 16 + c15;                                   \
      a[i] = *reinterpret_cast<const bf16x8*>(                                 \
          &sA[(rs) * 2048 + fr * 32 + ((lk ^ (fr & 3)) * 8)]);                 \
    }                                                                          \
    _Pragma("unroll")                                                          \
    for (int j = 0; j < 2; ++j) {                                              \
      const int fc = wc * 32 + j * 16 + c15;                                   \
      b[j] = *reinterpret_cast<const bf16x8*>(                                 \
          &sB[(rs) * 2048 + fc * 32 + ((lk ^ (fc & 3)) * 8)]);                 \
    }                                                                          \
    _Pragma("unroll")                                                          \
    for (int i = 0; i < 2; ++i)                                                \
      _Pragma("unroll")                                                        \
      for (int j = 0; j < 2; ++j)                                              \
        acc[i][j] = __builtin_amdgcn_mfma_f32_16x16x32_bf16(a[i], b[j], acc[i][j], 0, 0, 0); \
  }

  STG(); STG();
  int rs = 0;
  for (int t = 0; t < 14; ++t) {
    STG();
    asm volatile("s_waitcnt vmcnt(4)" ::: "memory");
    __builtin_amdgcn_s_barrier();
    TW_FRAGS(rs)
    rs = (rs + 1) & 3;
  }
  STG();
  asm volatile("s_waitcnt vmcnt(2)" ::: "memory");
  __builtin_amdgcn_s_barrier();
  TW_FRAGS(rs)
  rs = (rs + 1) & 3;
  STG();
  asm volatile("s_waitcnt vmcnt(0)" ::: "memory");
  __builtin_amdgcn_s_barrier();
  TW_FRAGS(rs)

#pragma unroll
  for (int i = 0; i < 2; ++i)
#pragma unroll
    for (int j = 0; j < 2; ++j) {
      const int rowb = m0 + wr * 32 + i * 16 + lk * 4;
      const int col  = z * 512 + n0 + wc * 32 + j * 16 + c15;
#pragma unroll
      for (int r = 0; r < 4; ++r)
        tw[(size_t)(rowb + r) * 4096 + col] = f2bf(acc[i][j][r]);
    }
}

// ---------------- out = x_bf @ tw^T + bias (round-6, verbatim) --------------
#define NSL 18

#define RD_A3(dst, MH)                                                         \
  _Pragma("unroll")                                                            \
  for (int m = 0; m < 4; ++m)                                                  \
    dst[m] = *reinterpret_cast<const bf16x8*>(                                 \
        &lds[aslot * 4096 + ((MH) * 64 + m * 16 + c15) * 32 + gsw * 8]);

#define RD_B3(dst)                                                             \
  _Pragma("unroll")                                                            \
  for (int n = 0; n < 4; ++n)                                                  \
    dst[n] = *reinterpret_cast<const bf16x8*>(                                 \
        &lds[bslot * 4096 + (bq64 + n * 16 + c15) * 32 + gsw * 8]);

#define MFMA16(afX, bfX, MH)                                                   \
  __builtin_amdgcn_s_setprio(1);                                               \
  _Pragma("unroll")                                                            \
  for (int m = 0; m < 4; ++m)                                                  \
    _Pragma("unroll")                                                          \
    for (int n = 0; n < 4; ++n)                                                \
      acc[(MH) * 4 + m][n] = __builtin_amdgcn_mfma_f32_16x16x32_bf16(          \
          afX[m], bfX[n], acc[(MH) * 4 + m][n], 0, 0, 0);                      \
  __builtin_amdgcn_s_setprio(0);

// WM: 1 steady vmcnt(8) | 2 vmcnt(4) | 3 vmcnt(0) | 0 none (last tile)
#define TILE32(WM)                                                             \
  {                                                                            \
    int aslot = s0 + wr;            if (aslot >= NSL) aslot -= NSL;            \
    int bslot = s0 + 2 + (wc >> 1); if (bslot >= NSL) bslot -= NSL;            \
    STAGE(); STAGE();                                                          \
    RD_B3(bfr)                                                                 \
    RD_A3(afA, 0)                                                              \
    MFMA16(afA, bfr, 0)                                                        \
    STAGE(); STAGE();                                                          \
    RD_A3(afB, 1)                                                              \
    MFMA16(afB, bfr, 1)                                                        \
    if ((WM) == 1) asm volatile("s_waitcnt vmcnt(8)" ::: "memory");            \
    if ((WM) == 2) asm volatile("s_waitcnt vmcnt(4)" ::: "memory");            \
    if ((WM) == 3) asm volatile("s_waitcnt vmcnt(0)" ::: "memory");            \
    if ((WM) != 0) {                                                           \
      __builtin_amdgcn_s_barrier();                                            \
      __builtin_amdgcn_sched_barrier(0);                                       \
    }                                                                          \
    s0 += 4; if (s0 >= NSL) s0 -= NSL;                                         \
  }

__global__ __launch_bounds__(512, 2)
void k_gemm256(const u16* __restrict__ A, const u16* __restrict__ B,
               const float* __restrict__ bias,
               float* __restrict__ C, int N, int K) {
  __shared__ __align__(16) u16 lds[NSL * 4096];   // 144 KiB
  const int tid = threadIdx.x, lane = tid & 63, wave = tid >> 6;
  int bid = blockIdx.y * gridDim.x + blockIdx.x;
  const int cpx = (gridDim.x * gridDim.y) >> 3;
  bid = (bid & 7) * cpx + (bid >> 3);
  const int nbx = N >> 8;
  const int bx = bid % nbx, by = bid / nbx;
  const int m0 = by << 8, n0 = bx << 8;
  const int wr = wave >> 2, wc = wave & 3;          // 2 x 4 wave grid
  const int srow = tid >> 2;
  const int sgc  = (tid & 3) ^ ((srow >> 1) & 3);
  const int c15 = lane & 15, lq = lane >> 4;
  const int gsw = lq ^ ((c15 >> 1) & 3);
  const int bq64 = (wc & 1) * 64;
  const int NT = K >> 5;                            // 128

  f32x4 acc[8][4] = {};
  bf16x8 afA[4], afB[4], bfr[4];

  int jn = 0, js = 0;
  auto STAGE = [&]() {
    if (jn < 4 * NT) {
      const int t = jn >> 2, q = jn & 3;
      const u16* srcb = (q < 2)
          ? A + (size_t)(m0 + q * 128 + srow) * (size_t)K
          : B + (size_t)(n0 + (q - 2) * 128 + srow) * (size_t)K;
      const u16* src = srcb + (t << 5) + sgc * 8;
      u16* dst = (u16*)lds + js * 4096 + tid * 8;
      __builtin_amdgcn_global_load_lds(
          (const AS1 void*)src, (AS3 void*)dst, 16, 0, 0);
    }
    ++jn; js = (js == NSL - 1) ? 0 : js + 1;
  };

#pragma unroll
  for (int i = 0; i < 12; ++i) STAGE();
  asm volatile("s_waitcnt vmcnt(8)" ::: "memory");
  __builtin_amdgcn_s_barrier();
  __builtin_amdgcn_sched_barrier(0);

  int s0 = 0;
  for (int tau = 0; tau < NT - 3; ++tau) {
    TILE32(1)
  }
  TILE32(2)
  TILE32(3)
  TILE32(0)

#pragma unroll
  for (int n = 0; n < 4; ++n) {
    const int col = n0 + wc * 64 + n * 16 + c15;
    const float bv = bias[col];
#pragma unroll
    for (int mi = 0; mi < 8; ++mi) {
      const int rowb = m0 + wr * 128 + mi * 16 + (lq << 2);
#pragma unroll
      for (int r = 0; r < 4; ++r)
        C[(size_t)(rowb + r) * N + col] = acc[mi][n][r] + bv;
    }
  }
}

extern "C" void kernel_launch(void* const* d_in, const int* in_sizes, int n_in,
                              void* d_out, int out_size, void* d_ws, size_t ws_size,
                              hipStream_t stream) {
  const float* W    = (const float*)d_in[0];   // [4096,4096]
  const float* bias = (const float*)d_in[1];   // [4096]
  const float* x    = (const float*)d_in[2];   // [4,2048,4096]
  const float* R    = (const float*)d_in[3];   // [8,512,512]
  float* out = (float*)d_out;

  char* ws = (char*)d_ws;
  u16* x_bf = (u16*)(ws);                      //  64 MiB
  u16* tw   = (u16*)(ws + 67108864);           //  32 MiB
  u16* W_bf = (u16*)(ws + 100663296);          //  32 MiB

  // scratch arena = d_out (128 MiB; fully overwritten by k_gemm256)
  char* arena = (char*)d_out;
  auto slot = [&](int i) -> u16* { return (u16*)(arena + (size_t)i * 4194304); };
  u16 *Mh = slot(0), *Ml = slot(1);
  u16 *G = slot(2), *G2 = slot(3);
  u16 *X0 = slot(5), *T2 = slot(6), *X1 = slot(7), *X2 = slot(8), *T3 = slot(9);
  u16 *X3h = slot(10), *X3l = slot(11), *X3th = slot(12), *X3tl = slot(13);
  u16 *Tpth = slot(14), *Tptl = slot(15);
  u16 *X4h = slot(16), *X4l = slot(17), *X4th = slot(18), *X4tl = slot(19);
  u16 *Qt = slot(20);
  float* coef = (float*)(arena + (size_t)21 * 4194304);   // 72 floats
  float* part = coef + 1024;                              // 512 floats

  const u16* NUL = nullptr;
  const float* NULF = nullptr;
  u16* NULW = nullptr;
  float* NULP = nullptr;
  const dim3 gC0(8, 8, 8);      // 8 mm batches, no conversion planes
  const dim3 gC2(8, 8, 12);     // 8 mm + 4 conv planes (2 chunks)

  // 1) M pair
  k_build_M<<<dim3(16, 16, 8), 256, 0, stream>>>(R, Mh, Ml);
  // 2) G = M@M^T (+ W chunks 0,1) ; G2 = G@G^T + Frobenius partials
  //    (+ W chunks 2,3)
  k_bmm<0, 0, 1, 0, 0><<<gC2, 256, 0, stream>>>(Mh, NUL, Mh, NUL, NUL, NUL,
      G, NULW, NULW, NULW, 0.f, 1.f, NULF, NULF, W, W_bf, 8,
      NUL, NUL, NUL, NULW, NULP);
  k_bmm<0, 0, 1, 0, 1><<<gC2, 256, 0, stream>>>(G, NUL, G, NUL, NUL, NUL,
      G2, NULW, NULW, NULW, 0.f, 1.f, NULF, NULF,
      W + (size_t)2 * 4194304, W_bf + (size_t)2 * 4194304, 8,
      NUL, NUL, NUL, NULW, part);
  // 3) coefficients (in-kernel, from part) ; X0 + T2 (elementwise, vectorized)
  k_init<<<1024, 256, 0, stream>>>(Mh, Ml, G, G2, part, coef, X0, T2);
  // 4) X1 = 2c1*X0 - c1*a*(X0@G)   [T1 = a*G, free]  (+ x chunks 0,1)
  k_bmm<0, 1, 1, 0, 0><<<gC2, 256, 0, stream>>>(X0, NUL, G, NUL, X0, NUL,
      X1, NULW, NULW, NULW, 0.f, 0.f, coef + 8, coef + 16,
      x, x_bf, 8, NUL, NUL, NUL, NULW, NULP);
  // 5) DUAL: X2 = 2c2*X1 - c2*(X1@T2)  ||  T3 = 2c2*T2 - c2*(T2@T2)
  //    (+ x chunks 2,3)
  k_bmm<0, 1, 1, 1, 0><<<dim3(8, 8, 20), 256, 0, stream>>>(X1, NUL, T2, NUL, X1, NUL,
      X2, NULW, NULW, NULW, 0.f, 0.f, coef + 40, coef + 48,
      x + (size_t)2 * 4194304, x_bf + (size_t)2 * 4194304, 16,
      T2, T2, T2, T3, NULP);
  // 6) X3 = 2c3*X2 - c3*(X2@T3), pairs + transposed pairs  (+ x chunks 4,5)
  k_bmm<0, 1, 15, 0, 0><<<gC2, 256, 0, stream>>>(X2, NUL, T3, NUL, X2, NUL,
      X3h, X3l, X3th, X3tl, 0.f, 0.f, coef + 56, coef + 64,
      x + (size_t)4 * 4194304, x_bf + (size_t)4 * 4194304, 8,
      NUL, NUL, NUL, NULW, NULP);
  // 7) split polish: Tp^T = (M@X3)^T pairs  (+ x chunks 6,7)
  k_bmm<1, 0, 12, 0, 0><<<gC2, 256, 0, stream>>>(Mh, Ml, X3th, X3tl, NUL, NUL,
      NULW, NULW, Tpth, Tptl, 0.f, 1.f, NULF, NULF,
      x + (size_t)6 * 4194304, x_bf + (size_t)6 * 4194304, 8,
      NUL, NUL, NUL, NULW, NULP);
  //    X4 = 2*X3 - X3@Tp, pairs + transposed pairs
  k_bmm<1, 2, 15, 0, 0><<<gC0, 256, 0, stream>>>(X3h, X3l, Tpth, Tptl, X3h, X3l,
      X4h, X4l, X4th, X4tl, 2.f, -1.f, NULF, NULF,
      x, x_bf, 8, NUL, NUL, NUL, NULW, NULP);
  // 8) Q^T = transpose of (2+1e-6)X4 - M@X4
  k_bmm<1, 2, 4, 0, 0><<<gC0, 256, 0, stream>>>(Mh, Ml, X4th, X4tl, X4h, X4l,
      NULW, NULW, Qt, NULW, C1Q, -1.f, NULF, NULF,
      x, x_bf, 8, NUL, NUL, NUL, NULW, NULP);
  // 9) tw = W_bf @ blockdiag(Q) ; main GEMM (overwrites the arena)
  k_twmm<<<dim3(8, 64, 8), 256, 0, stream>>>(W_bf, Qt, tw);
  k_gemm256<<<dim3(16, 32), 512, 0, stream>>>(x_bf, tw, bias, out, 4096, 4096);
}

// Round 16
// 487.628 us; speedup vs baseline: 1.1959x; 1.0021x over previous
//
#include <hip/hip_runtime.h>
#include <hip/hip_bf16.h>

// EnhancedOFTLinearLayer: out = x @ (W @ blockdiag(cayley(R)))^T + bias
//   cayley(A): S = 0.5(A - A^T); Q = (I - S) @ inv((1+1e-6)I + S)
// Round 15: k_bmm / k_twmm prefetch lead 2 -> 3 steps (5-slot ring).
// Hazard-checked: slots {t-1,t,t+1,t+2,t+3} distinct mod 5; tail waits
// 3L/2L/L/0 exact. Math identical to round 14. k_gemm256 frozen.

typedef unsigned short u16;
typedef __attribute__((ext_vector_type(8))) __bf16 bf16x8;
typedef __attribute__((ext_vector_type(4))) float f32x4;
typedef __attribute__((ext_vector_type(8))) unsigned short u16x8;
typedef __attribute__((ext_vector_type(4))) unsigned short u16x4;

#define C0   1.000001f   /* 1 + 1e-6 */
#define C1Q  2.000001f   /* 1 + C0   */
#define AS1 __attribute__((address_space(1)))
#define AS3 __attribute__((address_space(3)))

__device__ __forceinline__ u16 f2bf(float x) {
  union { float f; unsigned u; } v; v.f = x;
  return (u16)((v.u + 0x7fffu + ((v.u >> 16) & 1u)) >> 16);
}
__device__ __forceinline__ float bf2f(u16 h) {
  union { float f; unsigned u; } v; v.u = ((unsigned)h) << 16; return v.f;
}

// ------- recentered-Newton coefficient cascade from t = tr(G^4) -------------
__device__ __forceinline__ void get_coefs(float t, float* C) {
  float lam = powf(t, 0.25f);
  float a = 2.0f / (C0 * C0 + lam);
  float e = (lam - C0 * C0) / (lam + C0 * C0);
  float sq = e * e, c1 = 2.0f / (2.0f - sq);
  C[0] = a; C[1] = 2.0f * c1; C[2] = -c1 * a;
  C[3] = 2.0f * c1 * a; C[4] = -c1 * a * a;
  e = sq / (2.0f - sq); sq = e * e;
  float c2 = 2.0f / (2.0f - sq);
  C[5] = 2.0f * c2; C[6] = -c2;
  e = sq / (2.0f - sq); sq = e * e;
  float c3 = 2.0f / (2.0f - sq);
  C[7] = 2.0f * c3; C[8] = -c3;
}

// ---------------- 1) M = (1+1e-6)I + 0.5(R - R^T) -> bf16 hi/lo pair --------
__global__ __launch_bounds__(256) void k_build_M(const float* __restrict__ R,
                                                 u16* __restrict__ Mh,
                                                 u16* __restrict__ Ml) {
  __shared__ float t1[32][33];
  const int n = blockIdx.z;
  const int tr = blockIdx.y * 32, tc = blockIdx.x * 32;
  const int ly = threadIdx.x >> 5, lx = threadIdx.x & 31;   // 8 x 32
  const float* Rb = R + (size_t)n * 262144;
  float a[4];
#pragma unroll
  for (int i = 0; i < 4; ++i) {
    a[i] = Rb[(size_t)(tr + ly + i * 8) * 512 + tc + lx];
    t1[ly + i * 8][lx] = Rb[(size_t)(tc + ly + i * 8) * 512 + tr + lx];
  }
  __syncthreads();
#pragma unroll
  for (int i = 0; i < 4; ++i) {
    const int r = tr + ly + i * 8, c = tc + lx;
    float m = 0.5f * (a[i] - t1[lx][ly + i * 8]) + (r == c ? C0 : 0.0f);
    u16 h = f2bf(m);
    const size_t idx = (size_t)n * 262144 + (size_t)r * 512 + c;
    Mh[idx] = h;
    Ml[idx] = f2bf(m - bf2f(h));
  }
}

// ---- 3a) k_init: coefs from part[] + X0 = a(2c0 I - M) ; T2 elementwise ----
__global__ __launch_bounds__(256) void k_init(const u16* __restrict__ Mh,
                                              const u16* __restrict__ Ml,
                                              const u16* __restrict__ G,
                                              const u16* __restrict__ G2,
                                              const float* __restrict__ part,
                                              float* __restrict__ coef,
                                              u16* __restrict__ X0,
                                              u16* __restrict__ T2) {
  __shared__ float sp[64];
  __shared__ float sc[9];
  const int n = blockIdx.x >> 7;              // 128 blocks per batch
  if (threadIdx.x < 64) sp[threadIdx.x] = part[n * 64 + threadIdx.x];
  __syncthreads();
  if (threadIdx.x == 0) {
    float s = 0.f;
    for (int i = 0; i < 64; ++i) s += sp[i];  // fixed order: deterministic
    float C[9];
    get_coefs(s, C);
#pragma unroll
    for (int k = 0; k < 9; ++k) sc[k] = C[k];
    coef[n] = C[0];
    coef[8 + n]  = C[1]; coef[16 + n] = C[2];
    coef[24 + n] = C[3]; coef[32 + n] = C[4];
    coef[40 + n] = C[5]; coef[48 + n] = C[6];
    coef[56 + n] = C[7]; coef[64 + n] = C[8];
  }
  __syncthreads();
  const size_t base = ((size_t)blockIdx.x * 256 + threadIdx.x) * 8;
  const int r  = (int)((base >> 9) & 511);
  const int c0 = (int)(base & 511);
  u16x8 mh = *reinterpret_cast<const u16x8*>(Mh + base);
  u16x8 ml = *reinterpret_cast<const u16x8*>(Ml + base);
  u16x8 g  = *reinterpret_cast<const u16x8*>(G  + base);
  u16x8 g2 = *reinterpret_cast<const u16x8*>(G2 + base);
  u16x8 x0, t2;
#pragma unroll
  for (int e = 0; e < 8; ++e) {
    float m = bf2f(mh[e]) + bf2f(ml[e]);
    x0[e] = f2bf(sc[0] * ((r == c0 + e ? 2.0f * C0 : 0.0f) - m));
    t2[e] = f2bf(sc[3] * bf2f(g[e]) + sc[4] * bf2f(g2[e]));
  }
  *reinterpret_cast<u16x8*>(X0 + base) = x0;
  *reinterpret_cast<u16x8*>(T2 + base) = t2;
}

// ---------------- batched bf16 mm: C = cd*D + cs*(A @ B^T) ------------------
// 5-slot LDS ring, 3-step prefetch lead, counted vmcnt, 1 barrier/step.
// Tail waits: steady 3L, then 2L / L / 0 (L = loads/step = 2, PROD3: 4).
#define BMM_FRAGS(rs)                                                          \
  bf16x8 a[2], b[2], al2[2], bl2[2];                                           \
  _Pragma("unroll")                                                            \
  for (int i = 0; i < 2; ++i) {                                                \
    const int fr = wr * 32 + i * 16 + c15;                                     \
    const int ia = (rs) * 2048 + fr * 32 + ((lk ^ (fr & 3)) * 8);              \
    a[i] = *reinterpret_cast<const bf16x8*>(&sA[ia]);                          \
    if constexpr (PROD3) al2[i] = *reinterpret_cast<const bf16x8*>(&sAl[ia]);  \
  }                                                                            \
  _Pragma("unroll")                                                            \
  for (int j = 0; j < 2; ++j) {                                                \
    const int fc = wc * 32 + j * 16 + c15;                                     \
    const int ib = (rs) * 2048 + fc * 32 + ((lk ^ (fc & 3)) * 8);              \
    b[j] = *reinterpret_cast<const bf16x8*>(&sB[ib]);                          \
    if constexpr (PROD3) bl2[j] = *reinterpret_cast<const bf16x8*>(&sBl[ib]);  \
  }                                                                            \
  _Pragma("unroll")                                                            \
  for (int i = 0; i < 2; ++i)                                                  \
    _Pragma("unroll")                                                          \
    for (int j = 0; j < 2; ++j) {                                              \
      acc[i][j] = __builtin_amdgcn_mfma_f32_16x16x32_bf16(a[i], b[j], acc[i][j], 0, 0, 0); \
      if constexpr (PROD3) {                                                   \
        acc[i][j] = __builtin_amdgcn_mfma_f32_16x16x32_bf16(a[i],   bl2[j], acc[i][j], 0, 0, 0); \
        acc[i][j] = __builtin_amdgcn_mfma_f32_16x16x32_bf16(al2[i], b[j],   acc[i][j], 0, 0, 0); \
      }                                                                        \
    }

#define BMM_WAIT(SEL)                                                          \
  if ((SEL) == 0) {                                                            \
    if constexpr (PROD3) asm volatile("s_waitcnt vmcnt(12)" ::: "memory");     \
    else                 asm volatile("s_waitcnt vmcnt(6)" ::: "memory");      \
  } else if ((SEL) == 1) {                                                     \
    if constexpr (PROD3) asm volatile("s_waitcnt vmcnt(8)" ::: "memory");      \
    else                 asm volatile("s_waitcnt vmcnt(4)" ::: "memory");      \
  } else if ((SEL) == 2) {                                                     \
    if constexpr (PROD3) asm volatile("s_waitcnt vmcnt(4)" ::: "memory");      \
    else                 asm volatile("s_waitcnt vmcnt(2)" ::: "memory");      \
  } else {                                                                     \
    asm volatile("s_waitcnt vmcnt(0)" ::: "memory");                           \
  }

template <int PROD3, int DMODE, int OMODE, int DUAL, int FROB>
__global__ __launch_bounds__(256)
void k_bmm(const u16* __restrict__ Ah, const u16* __restrict__ Al,
           const u16* __restrict__ Bh, const u16* __restrict__ Bl,
           const u16* __restrict__ Dh, const u16* __restrict__ Dl,
           u16* __restrict__ Cnh, u16* __restrict__ Cnl,
           u16* __restrict__ Cth, u16* __restrict__ Ctl,
           float cd, float cs,
           const float* __restrict__ cdp, const float* __restrict__ csp,
           const float* __restrict__ cvsrc, u16* __restrict__ cvdst, int zmm,
           const u16* __restrict__ A2, const u16* __restrict__ B2,
           const u16* __restrict__ D2, u16* __restrict__ C2,
           float* __restrict__ part) {
  __shared__ __align__(16) u16 sA[5 * 2048], sB[5 * 2048];
  __shared__ __align__(16) u16 sAl[PROD3 ? 5 * 2048 : 8];
  __shared__ __align__(16) u16 sBl[PROD3 ? 5 * 2048 : 8];
  __shared__ float fred[FROB ? 4 : 1];

  if ((int)blockIdx.z >= zmm) {   // conversion side-channel
    const int zi = ((int)blockIdx.z - zmm) * 64 + blockIdx.y * 8 + blockIdx.x;
    const int chunk = zi >> 7;                     // 128 blocks per 4M chunk
    const int base = (zi & 127) * 256 + (int)threadIdx.x;
    const float* src = cvsrc + (size_t)chunk * 4194304;
    u16* dst = cvdst + (size_t)chunk * 4194304;
#pragma unroll
    for (int e = 0; e < 16; ++e) {
      const size_t g = (size_t)(base + e * 32768) * 8;
      float4 f0 = *reinterpret_cast<const float4*>(src + g);
      float4 f1 = *reinterpret_cast<const float4*>(src + g + 4);
      u16x8 w;
      w[0] = f2bf(f0.x); w[1] = f2bf(f0.y); w[2] = f2bf(f0.z); w[3] = f2bf(f0.w);
      w[4] = f2bf(f1.x); w[5] = f2bf(f1.y); w[6] = f2bf(f1.z); w[7] = f2bf(f1.w);
      *reinterpret_cast<u16x8*>(dst + g) = w;
    }
    return;
  }

  const int zq = DUAL ? ((blockIdx.z >> 3) & 1) : 0;   // 0: job A, 1: job B
  const u16* Ah_ = (DUAL && zq) ? A2 : Ah;
  const u16* Bh_ = (DUAL && zq) ? B2 : Bh;
  const u16* Dh_ = (DUAL && zq) ? D2 : Dh;
  u16* Cnh_ = (DUAL && zq) ? C2 : Cnh;
  const size_t zb = (size_t)(blockIdx.z & 7) * 262144;
  const int tid = threadIdx.x, lane = tid & 63, wave = tid >> 6;
  const int m0 = blockIdx.y * 64, n0 = blockIdx.x * 64;
  const int wr = wave >> 1, wc = wave & 1;
  const int c15 = lane & 15, lk = lane >> 4;
  const int srow = tid >> 2;
  const int sg = (tid & 3) ^ (srow & 3);            // granule-XOR (involution)
  f32x4 acc[2][2] = {};
  const u16* pa = Ah_ + zb + (size_t)(m0 + srow) * 512 + sg * 8;
  const u16* pb = Bh_ + zb + (size_t)(n0 + srow) * 512 + sg * 8;
  const u16* pal = PROD3 ? Al + zb + (size_t)(m0 + srow) * 512 + sg * 8 : pa;
  const u16* pbl = PROD3 ? Bl + zb + (size_t)(n0 + srow) * 512 + sg * 8 : pb;

  int jn = 0, js = 0;
  auto STG = [&]() {
    if (jn < 16) {
      const int off = jn << 5;
      __builtin_amdgcn_global_load_lds((const AS1 void*)(pa + off),
                                       (AS3 void*)(sA + js * 2048 + tid * 8), 16, 0, 0);
      __builtin_amdgcn_global_load_lds((const AS1 void*)(pb + off),
                                       (AS3 void*)(sB + js * 2048 + tid * 8), 16, 0, 0);
      if constexpr (PROD3) {
        __builtin_amdgcn_global_load_lds((const AS1 void*)(pal + off),
                                         (AS3 void*)(sAl + js * 2048 + tid * 8), 16, 0, 0);
        __builtin_amdgcn_global_load_lds((const AS1 void*)(pbl + off),
                                         (AS3 void*)(sBl + js * 2048 + tid * 8), 16, 0, 0);
      }
    }
    ++jn; js = (js == 4) ? 0 : js + 1;
  };

  STG(); STG(); STG();          // prefetch steps 0,1,2 (lead 3)
  int rs = 0;
  for (int t = 0; t < 13; ++t) {
    STG();                      // stage step t+3
    BMM_WAIT(0)                 // step t landed (3 steps in flight)
    __builtin_amdgcn_s_barrier();
    BMM_FRAGS(rs)
    rs = (rs == 4) ? 0 : rs + 1;
  }
  STG();                        // t=13: stage jn=16 (no-op), 2 steps out
  BMM_WAIT(1)
  __builtin_amdgcn_s_barrier();
  { BMM_FRAGS(rs) }
  rs = (rs == 4) ? 0 : rs + 1;
  STG();                        // t=14: no-op, 1 step out
  BMM_WAIT(2)
  __builtin_amdgcn_s_barrier();
  { BMM_FRAGS(rs) }
  rs = (rs == 4) ? 0 : rs + 1;
  STG();                        // t=15: no-op, full drain
  BMM_WAIT(3)
  __builtin_amdgcn_s_barrier();
  { BMM_FRAGS(rs) }

  const float cdL = cdp ? cdp[blockIdx.z & 7] : cd;
  const float csL = csp ? csp[blockIdx.z & 7] : cs;
  float fs = 0.f;
  // epilogue (C/D map: col=lane&15, row=(lane>>4)*4+r)
#pragma unroll
  for (int i = 0; i < 2; ++i)
#pragma unroll
    for (int j = 0; j < 2; ++j) {
      const int rowb = m0 + wr * 32 + i * 16 + lk * 4;
      const int col  = n0 + wc * 32 + j * 16 + c15;
      u16 hv[4], lv[4];
#pragma unroll
      for (int r = 0; r < 4; ++r) {
        float val = csL * acc[i][j][r];
        if constexpr (DMODE >= 1) {
          float d = bf2f(Dh_[zb + (size_t)(rowb + r) * 512 + col]);
          if constexpr (DMODE == 2) d += bf2f(Dl[zb + (size_t)(rowb + r) * 512 + col]);
          val += cdL * d;
        }
        u16 h = f2bf(val);
        if constexpr (OMODE & 1) Cnh_[zb + (size_t)(rowb + r) * 512 + col] = h;
        if constexpr (FROB) { float v = bf2f(h); fs += v * v; }
        u16 l = 0;
        if constexpr (OMODE & 10) l = f2bf(val - bf2f(h));
        if constexpr (OMODE & 2) Cnl[zb + (size_t)(rowb + r) * 512 + col] = l;
        hv[r] = h; lv[r] = l;
      }
      if constexpr (OMODE & 4) {
        u16x4 v; v[0] = hv[0]; v[1] = hv[1]; v[2] = hv[2]; v[3] = hv[3];
        *reinterpret_cast<u16x4*>(&Cth[zb + (size_t)col * 512 + rowb]) = v;
      }
      if constexpr (OMODE & 8) {
        u16x4 v; v[0] = lv[0]; v[1] = lv[1]; v[2] = lv[2]; v[3] = lv[3];
        *reinterpret_cast<u16x4*>(&Ctl[zb + (size_t)col * 512 + rowb]) = v;
      }
    }
  if constexpr (FROB) {
    for (int off = 32; off; off >>= 1) fs += __shfl_down(fs, off, 64);
    if ((tid & 63) == 0) fred[tid >> 6] = fs;
    __syncthreads();
    if (tid == 0)
      part[(blockIdx.z & 7) * 64 + blockIdx.y * 8 + blockIdx.x] =
          fred[0] + fred[1] + fred[2] + fred[3];
  }
}

// ---------------- tw = W_bf @ blockdiag(Q)  (B = Qt, 5-slot ring) -----------
__global__ __launch_bounds__(256)
void k_twmm(const u16* __restrict__ W, const u16* __restrict__ Qt,
            u16* __restrict__ tw) {
  __shared__ __align__(16) u16 sA[5 * 2048], sB[5 * 2048];
  const int z = blockIdx.z;
  const size_t zb = (size_t)z * 262144;
  const int tid = threadIdx.x, lane = tid & 63, wave = tid >> 6;
  const int m0 = blockIdx.y * 64, n0 = blockIdx.x * 64;
  const int wr = wave >> 1, wc = wave & 1;
  const int c15 = lane & 15, lk = lane >> 4;
  const int srow = tid >> 2;
  const int sg = (tid & 3) ^ (srow & 3);
  f32x4 acc[2][2] = {};
  const u16* pa = W + (size_t)(m0 + srow) * 4096 + z * 512 + sg * 8;
  const u16* pb = Qt + zb + (size_t)(n0 + srow) * 512 + sg * 8;

  int jn = 0, js = 0;
  auto STG = [&]() {
    if (jn < 16) {
      const int off = jn << 5;
      __builtin_amdgcn_global_load_lds((const AS1 void*)(pa + off),
                                       (AS3 void*)(sA + js * 2048 + tid * 8), 16, 0, 0);
      __builtin_amdgcn_global_load_lds((const AS1 void*)(pb + off),
                                       (AS3 void*)(sB + js * 2048 + tid * 8), 16, 0, 0);
    }
    ++jn; js = (js == 4) ? 0 : js + 1;
  };

#define TW_FRAGS(rs)                                                           \
  {                                                                            \
    bf16x8 a[2], b[2];                                                         \
    _Pragma("unroll")                                                          \
    for (int i = 0; i < 2; ++i) {                                              \
      const int fr = wr * 32 + i * 16 + c15;                                   \
      a[i] = *reinterpret_cast<const bf16x8*>(                                 \
          &sA[(rs) * 2048 + fr * 32 + ((lk ^ (fr & 3)) * 8)]);                 \
    }                                                                          \
    _Pragma("unroll")                                                          \
    for (int j = 0; j < 2; ++j) {                                              \
      const int fc = wc * 32 + j * 16 + c15;                                   \
      b[j] = *reinterpret_cast<const bf16x8*>(                                 \
          &sB[(rs) * 2048 + fc * 32 + ((lk ^ (fc & 3)) * 8)]);                 \
    }                                                                          \
    _Pragma("unroll")                                                          \
    for (int i = 0; i < 2; ++i)                                                \
      _Pragma("unroll")                                                        \
      for (int j = 0; j < 2; ++j)                                              \
        acc[i][j] = __builtin_amdgcn_mfma_f32_16x16x32_bf16(a[i], b[j], acc[i][j], 0, 0, 0); \
  }

  STG(); STG(); STG();
  int rs = 0;
  for (int t = 0; t < 13; ++t) {
    STG();
    asm volatile("s_waitcnt vmcnt(6)" ::: "memory");
    __builtin_amdgcn_s_barrier();
    TW_FRAGS(rs)
    rs = (rs == 4) ? 0 : rs + 1;
  }
  STG();
  asm volatile("s_waitcnt vmcnt(4)" ::: "memory");
  __builtin_amdgcn_s_barrier();
  TW_FRAGS(rs)
  rs = (rs == 4) ? 0 : rs + 1;
  STG();
  asm volatile("s_waitcnt vmcnt(2)" ::: "memory");
  __builtin_amdgcn_s_barrier();
  TW_FRAGS(rs)
  rs = (rs == 4) ? 0 : rs + 1;
  STG();
  asm volatile("s_waitcnt vmcnt(0)" ::: "memory");
  __builtin_amdgcn_s_barrier();
  TW_FRAGS(rs)

#pragma unroll
  for (int i = 0; i < 2; ++i)
#pragma unroll
    for (int j = 0; j < 2; ++j) {
      const int rowb = m0 + wr * 32 + i * 16 + lk * 4;
      const int col  = z * 512 + n0 + wc * 32 + j * 16 + c15;
#pragma unroll
      for (int r = 0; r < 4; ++r)
        tw[(size_t)(rowb + r) * 4096 + col] = f2bf(acc[i][j][r]);
    }
}

// ---------------- out = x_bf @ tw^T + bias (round-6, verbatim) --------------
#define NSL 18

#define RD_A3(dst, MH)                                                         \
  _Pragma("unroll")                                                            \
  for (int m = 0; m < 4; ++m)                                                  \
    dst[m] = *reinterpret_cast<const bf16x8*>(                                 \
        &lds[aslot * 4096 + ((MH) * 64 + m * 16 + c15) * 32 + gsw * 8]);

#define RD_B3(dst)                                                             \
  _Pragma("unroll")                                                            \
  for (int n = 0; n < 4; ++n)                                                  \
    dst[n] = *reinterpret_cast<const bf16x8*>(                                 \
        &lds[bslot * 4096 + (bq64 + n * 16 + c15) * 32 + gsw * 8]);

#define MFMA16(afX, bfX, MH)                                                   \
  __builtin_amdgcn_s_setprio(1);                                               \
  _Pragma("unroll")                                                            \
  for (int m = 0; m < 4; ++m)                                                  \
    _Pragma("unroll")                                                          \
    for (int n = 0; n < 4; ++n)                                                \
      acc[(MH) * 4 + m][n] = __builtin_amdgcn_mfma_f32_16x16x32_bf16(          \
          afX[m], bfX[n], acc[(MH) * 4 + m][n], 0, 0, 0);                      \
  __builtin_amdgcn_s_setprio(0);

// WM: 1 steady vmcnt(8) | 2 vmcnt(4) | 3 vmcnt(0) | 0 none (last tile)
#define TILE32(WM)                                                             \
  {                                                                            \
    int aslot = s0 + wr;            if (aslot >= NSL) aslot -= NSL;            \
    int bslot = s0 + 2 + (wc >> 1); if (bslot >= NSL) bslot -= NSL;            \
    STAGE(); STAGE();                                                          \
    RD_B3(bfr)                                                                 \
    RD_A3(afA, 0)                                                              \
    MFMA16(afA, bfr, 0)                                                        \
    STAGE(); STAGE();                                                          \
    RD_A3(afB, 1)                                                              \
    MFMA16(afB, bfr, 1)                                                        \
    if ((WM) == 1) asm volatile("s_waitcnt vmcnt(8)" ::: "memory");            \
    if ((WM) == 2) asm volatile("s_waitcnt vmcnt(4)" ::: "memory");            \
    if ((WM) == 3) asm volatile("s_waitcnt vmcnt(0)" ::: "memory");            \
    if ((WM) != 0) {                                                           \
      __builtin_amdgcn_s_barrier();                                            \
      __builtin_amdgcn_sched_barrier(0);                                       \
    }                                                                          \
    s0 += 4; if (s0 >= NSL) s0 -= NSL;                                         \
  }

__global__ __launch_bounds__(512, 2)
void k_gemm256(const u16* __restrict__ A, const u16* __restrict__ B,
               const float* __restrict__ bias,
               float* __restrict__ C, int N, int K) {
  __shared__ __align__(16) u16 lds[NSL * 4096];   // 144 KiB
  const int tid = threadIdx.x, lane = tid & 63, wave = tid >> 6;
  int bid = blockIdx.y * gridDim.x + blockIdx.x;
  const int cpx = (gridDim.x * gridDim.y) >> 3;
  bid = (bid & 7) * cpx + (bid >> 3);
  const int nbx = N >> 8;
  const int bx = bid % nbx, by = bid / nbx;
  const int m0 = by << 8, n0 = bx << 8;
  const int wr = wave >> 2, wc = wave & 3;          // 2 x 4 wave grid
  const int srow = tid >> 2;
  const int sgc  = (tid & 3) ^ ((srow >> 1) & 3);
  const int c15 = lane & 15, lq = lane >> 4;
  const int gsw = lq ^ ((c15 >> 1) & 3);
  const int bq64 = (wc & 1) * 64;
  const int NT = K >> 5;                            // 128

  f32x4 acc[8][4] = {};
  bf16x8 afA[4], afB[4], bfr[4];

  int jn = 0, js = 0;
  auto STAGE = [&]() {
    if (jn < 4 * NT) {
      const int t = jn >> 2, q = jn & 3;
      const u16* srcb = (q < 2)
          ? A + (size_t)(m0 + q * 128 + srow) * (size_t)K
          : B + (size_t)(n0 + (q - 2) * 128 + srow) * (size_t)K;
      const u16* src = srcb + (t << 5) + sgc * 8;
      u16* dst = (u16*)lds + js * 4096 + tid * 8;
      __builtin_amdgcn_global_load_lds(
          (const AS1 void*)src, (AS3 void*)dst, 16, 0, 0);
    }
    ++jn; js = (js == NSL - 1) ? 0 : js + 1;
  };

#pragma unroll
  for (int i = 0; i < 12; ++i) STAGE();
  asm volatile("s_waitcnt vmcnt(8)" ::: "memory");
  __builtin_amdgcn_s_barrier();
  __builtin_amdgcn_sched_barrier(0);

  int s0 = 0;
  for (int tau = 0; tau < NT - 3; ++tau) {
    TILE32(1)
  }
  TILE32(2)
  TILE32(3)
  TILE32(0)

#pragma unroll
  for (int n = 0; n < 4; ++n) {
    const int col = n0 + wc * 64 + n * 16 + c15;
    const float bv = bias[col];
#pragma unroll
    for (int mi = 0; mi < 8; ++mi) {
      const int rowb = m0 + wr * 128 + mi * 16 + (lq << 2);
#pragma unroll
      for (int r = 0; r < 4; ++r)
        C[(size_t)(rowb + r) * N + col] = acc[mi][n][r] + bv;
    }
  }
}

extern "C" void kernel_launch(void* const* d_in, const int* in_sizes, int n_in,
                              void* d_out, int out_size, void* d_ws, size_t ws_size,
                              hipStream_t stream) {
  const float* W    = (const float*)d_in[0];   // [4096,4096]
  const float* bias = (const float*)d_in[1];   // [4096]
  const float* x    = (const float*)d_in[2];   // [4,2048,4096]
  const float* R    = (const float*)d_in[3];   // [8,512,512]
  float* out = (float*)d_out;

  char* ws = (char*)d_ws;
  u16* x_bf = (u16*)(ws);                      //  64 MiB
  u16* tw   = (u16*)(ws + 67108864);           //  32 MiB
  u16* W_bf = (u16*)(ws + 100663296);          //  32 MiB

  // scratch arena = d_out (128 MiB; fully overwritten by k_gemm256)
  char* arena = (char*)d_out;
  auto slot = [&](int i) -> u16* { return (u16*)(arena + (size_t)i * 4194304); };
  u16 *Mh = slot(0), *Ml = slot(1);
  u16 *G = slot(2), *G2 = slot(3);
  u16 *X0 = slot(5), *T2 = slot(6), *X1 = slot(7), *X2 = slot(8), *T3 = slot(9);
  u16 *X3h = slot(10), *X3l = slot(11), *X3th = slot(12), *X3tl = slot(13);
  u16 *Tpth = slot(14), *Tptl = slot(15);
  u16 *X4h = slot(16), *X4l = slot(17), *X4th = slot(18), *X4tl = slot(19);
  u16 *Qt = slot(20);
  float* coef = (float*)(arena + (size_t)21 * 4194304);   // 72 floats
  float* part = coef + 1024;                              // 512 floats

  const u16* NUL = nullptr;
  const float* NULF = nullptr;
  u16* NULW = nullptr;
  float* NULP = nullptr;
  const dim3 gC0(8, 8, 8);      // 8 mm batches, no conversion planes
  const dim3 gC2(8, 8, 12);     // 8 mm + 4 conv planes (2 chunks)

  // 1) M pair
  k_build_M<<<dim3(16, 16, 8), 256, 0, stream>>>(R, Mh, Ml);
  // 2) G = M@M^T (+ W chunks 0,1) ; G2 = G@G^T + Frobenius partials
  //    (+ W chunks 2,3)
  k_bmm<0, 0, 1, 0, 0><<<gC2, 256, 0, stream>>>(Mh, NUL, Mh, NUL, NUL, NUL,
      G, NULW, NULW, NULW, 0.f, 1.f, NULF, NULF, W, W_bf, 8,
      NUL, NUL, NUL, NULW, NULP);
  k_bmm<0, 0, 1, 0, 1><<<gC2, 256, 0, stream>>>(G, NUL, G, NUL, NUL, NUL,
      G2, NULW, NULW, NULW, 0.f, 1.f, NULF, NULF,
      W + (size_t)2 * 4194304, W_bf + (size_t)2 * 4194304, 8,
      NUL, NUL, NUL, NULW, part);
  // 3) coefficients (in-kernel, from part) ; X0 + T2 (elementwise, vectorized)
  k_init<<<1024, 256, 0, stream>>>(Mh, Ml, G, G2, part, coef, X0, T2);
  // 4) X1 = 2c1*X0 - c1*a*(X0@G)   [T1 = a*G, free]  (+ x chunks 0,1)
  k_bmm<0, 1, 1, 0, 0><<<gC2, 256, 0, stream>>>(X0, NUL, G, NUL, X0, NUL,
      X1, NULW, NULW, NULW, 0.f, 0.f, coef + 8, coef + 16,
      x, x_bf, 8, NUL, NUL, NUL, NULW, NULP);
  // 5) DUAL: X2 = 2c2*X1 - c2*(X1@T2)  ||  T3 = 2c2*T2 - c2*(T2@T2)
  //    (+ x chunks 2,3)
  k_bmm<0, 1, 1, 1, 0><<<dim3(8, 8, 20), 256, 0, stream>>>(X1, NUL, T2, NUL, X1, NUL,
      X2, NULW, NULW, NULW, 0.f, 0.f, coef + 40, coef + 48,
      x + (size_t)2 * 4194304, x_bf + (size_t)2 * 4194304, 16,
      T2, T2, T2, T3, NULP);
  // 6) X3 = 2c3*X2 - c3*(X2@T3), pairs + transposed pairs  (+ x chunks 4,5)
  k_bmm<0, 1, 15, 0, 0><<<gC2, 256, 0, stream>>>(X2, NUL, T3, NUL, X2, NUL,
      X3h, X3l, X3th, X3tl, 0.f, 0.f, coef + 56, coef + 64,
      x + (size_t)4 * 4194304, x_bf + (size_t)4 * 4194304, 8,
      NUL, NUL, NUL, NULW, NULP);
  // 7) split polish: Tp^T = (M@X3)^T pairs  (+ x chunks 6,7)
  k_bmm<1, 0, 12, 0, 0><<<gC2, 256, 0, stream>>>(Mh, Ml, X3th, X3tl, NUL, NUL,
      NULW, NULW, Tpth, Tptl, 0.f, 1.f, NULF, NULF,
      x + (size_t)6 * 4194304, x_bf + (size_t)6 * 4194304, 8,
      NUL, NUL, NUL, NULW, NULP);
  //    X4 = 2*X3 - X3@Tp, pairs + transposed pairs
  k_bmm<1, 2, 15, 0, 0><<<gC0, 256, 0, stream>>>(X3h, X3l, Tpth, Tptl, X3h, X3l,
      X4h, X4l, X4th, X4tl, 2.f, -1.f, NULF, NULF,
      x, x_bf, 8, NUL, NUL, NUL, NULW, NULP);
  // 8) Q^T = transpose of (2+1e-6)X4 - M@X4
  k_bmm<1, 2, 4, 0, 0><<<gC0, 256, 0, stream>>>(Mh, Ml, X4th, X4tl, X4h, X4l,
      NULW, NULW, Qt, NULW, C1Q, -1.f, NULF, NULF,
      x, x_bf, 8, NUL, NUL, NUL, NULW, NULP);
  // 9) tw = W_bf @ blockdiag(Q) ; main GEMM (overwrites the arena)
  k_twmm<<<dim3(8, 64, 8), 256, 0, stream>>>(W_bf, Qt, tw);
  k_gemm256<<<dim3(16, 32), 512, 0, stream>>>(x_bf, tw, bias, out, 4096, 4096);
}

// Round 17
// 468.750 us; speedup vs baseline: 1.2441x; 1.0403x over previous
//
#include <hip/hip_runtime.h>
#include <hip/hip_bf16.h>

// EnhancedOFTLinearLayer: out = x @ (W @ blockdiag(cayley(R)))^T + bias
//   cayley(A): S = 0.5(A - A^T); Q = (I - S) @ inv((1+1e-6)I + S)
// Round 16: two serial mm slots removed algebraically.
//   (a) H = M@G computed as the DUAL job of the G2 launch; X1 becomes
//       elementwise in k_init: X1 = g0*I + g1*M + g2*G + g3*H.
//   (b) V-trick: V = C1Q*X3 - Tp emitted by the Tp launch's epilogue
//       (VOUT mode); Q = 2V - V@Tp. X4 launch deleted.
// 12 -> 10 dispatches. k_gemm256 / k_twmm / ring structure frozen (round 15).

typedef unsigned short u16;
typedef __attribute__((ext_vector_type(8))) __bf16 bf16x8;
typedef __attribute__((ext_vector_type(4))) float f32x4;
typedef __attribute__((ext_vector_type(8))) unsigned short u16x8;
typedef __attribute__((ext_vector_type(4))) unsigned short u16x4;

#define C0   1.000001f   /* 1 + 1e-6 */
#define C1Q  2.000001f   /* 1 + C0   */
#define AS1 __attribute__((address_space(1)))
#define AS3 __attribute__((address_space(3)))

__device__ __forceinline__ u16 f2bf(float x) {
  union { float f; unsigned u; } v; v.f = x;
  return (u16)((v.u + 0x7fffu + ((v.u >> 16) & 1u)) >> 16);
}
__device__ __forceinline__ float bf2f(u16 h) {
  union { float f; unsigned u; } v; v.u = ((unsigned)h) << 16; return v.f;
}

// ------- recentered-Newton coefficient cascade from t = tr(G^4) -------------
// C[0]=a C[1]=2c1 C[2]=-c1*a C[3]=2c1a C[4]=-c1a^2 C[5]=2c2 C[6]=-c2
// C[7]=2c3 C[8]=-c3
__device__ __forceinline__ void get_coefs(float t, float* C) {
  float lam = powf(t, 0.25f);
  float a = 2.0f / (C0 * C0 + lam);
  float e = (lam - C0 * C0) / (lam + C0 * C0);
  float sq = e * e, c1 = 2.0f / (2.0f - sq);
  C[0] = a; C[1] = 2.0f * c1; C[2] = -c1 * a;
  C[3] = 2.0f * c1 * a; C[4] = -c1 * a * a;
  e = sq / (2.0f - sq); sq = e * e;
  float c2 = 2.0f / (2.0f - sq);
  C[5] = 2.0f * c2; C[6] = -c2;
  e = sq / (2.0f - sq); sq = e * e;
  float c3 = 2.0f / (2.0f - sq);
  C[7] = 2.0f * c3; C[8] = -c3;
}

// ---------------- 1) M = (1+1e-6)I + 0.5(R - R^T) -> bf16 hi/lo pair --------
__global__ __launch_bounds__(256) void k_build_M(const float* __restrict__ R,
                                                 u16* __restrict__ Mh,
                                                 u16* __restrict__ Ml) {
  __shared__ float t1[32][33];
  const int n = blockIdx.z;
  const int tr = blockIdx.y * 32, tc = blockIdx.x * 32;
  const int ly = threadIdx.x >> 5, lx = threadIdx.x & 31;   // 8 x 32
  const float* Rb = R + (size_t)n * 262144;
  float a[4];
#pragma unroll
  for (int i = 0; i < 4; ++i) {
    a[i] = Rb[(size_t)(tr + ly + i * 8) * 512 + tc + lx];
    t1[ly + i * 8][lx] = Rb[(size_t)(tc + ly + i * 8) * 512 + tr + lx];
  }
  __syncthreads();
#pragma unroll
  for (int i = 0; i < 4; ++i) {
    const int r = tr + ly + i * 8, c = tc + lx;
    float m = 0.5f * (a[i] - t1[lx][ly + i * 8]) + (r == c ? C0 : 0.0f);
    u16 h = f2bf(m);
    const size_t idx = (size_t)n * 262144 + (size_t)r * 512 + c;
    Mh[idx] = h;
    Ml[idx] = f2bf(m - bf2f(h));
  }
}

// ---- 3a) k_init: coefs; X1 = g0 I + g1 M + g2 G + g3 H ; T2 elementwise ----
__global__ __launch_bounds__(256) void k_init(const u16* __restrict__ Mh,
                                              const u16* __restrict__ Ml,
                                              const u16* __restrict__ G,
                                              const u16* __restrict__ G2,
                                              const u16* __restrict__ H,
                                              const float* __restrict__ part,
                                              float* __restrict__ coef,
                                              u16* __restrict__ X1,
                                              u16* __restrict__ T2) {
  __shared__ float sp[64];
  __shared__ float sc[13];
  const int n = blockIdx.x >> 7;              // 128 blocks per batch
  if (threadIdx.x < 64) sp[threadIdx.x] = part[n * 64 + threadIdx.x];
  __syncthreads();
  if (threadIdx.x == 0) {
    float s = 0.f;
    for (int i = 0; i < 64; ++i) s += sp[i];  // fixed order: deterministic
    float C[9];
    get_coefs(s, C);
#pragma unroll
    for (int k = 0; k < 9; ++k) sc[k] = C[k];
    // X1 = 2c1*X0 - c1a*(X0@G); X0 = a(2c0 I - M); X0@G = 2c0a G - a H
    sc[9]  = 2.0f * C0 * C[3];   // g0 = 4 c0 c1 a        (diagonal)
    sc[10] = -C[3];              // g1 = -2 c1 a          (M term)
    sc[11] = 2.0f * C0 * C[4];   // g2 = -2 c0 c1 a^2     (G term)
    sc[12] = -C[4];              // g3 =  c1 a^2          (H term)
    coef[n] = C[0];
    coef[8 + n]  = C[1]; coef[16 + n] = C[2];
    coef[24 + n] = C[3]; coef[32 + n] = C[4];
    coef[40 + n] = C[5]; coef[48 + n] = C[6];
    coef[56 + n] = C[7]; coef[64 + n] = C[8];
  }
  __syncthreads();
  const size_t base = ((size_t)blockIdx.x * 256 + threadIdx.x) * 8;
  const int r  = (int)((base >> 9) & 511);
  const int c0 = (int)(base & 511);
  u16x8 mh = *reinterpret_cast<const u16x8*>(Mh + base);
  u16x8 ml = *reinterpret_cast<const u16x8*>(Ml + base);
  u16x8 g  = *reinterpret_cast<const u16x8*>(G  + base);
  u16x8 g2 = *reinterpret_cast<const u16x8*>(G2 + base);
  u16x8 hh = *reinterpret_cast<const u16x8*>(H  + base);
  u16x8 x1, t2;
#pragma unroll
  for (int e = 0; e < 8; ++e) {
    float m = bf2f(mh[e]) + bf2f(ml[e]);
    float gv = bf2f(g[e]);
    x1[e] = f2bf((r == c0 + e ? sc[9] : 0.0f) + sc[10] * m + sc[11] * gv +
                 sc[12] * bf2f(hh[e]));
    t2[e] = f2bf(sc[3] * gv + sc[4] * bf2f(g2[e]));
  }
  *reinterpret_cast<u16x8*>(X1 + base) = x1;
  *reinterpret_cast<u16x8*>(T2 + base) = t2;
}

// ---------------- batched bf16 mm: C = cd*D + cs*(A @ B^T) ------------------
// 5-slot LDS ring, 3-step prefetch lead, counted vmcnt, 1 barrier/step.
// PROD3: split hi/lo 3-MFMA product. DMODE 0/1/2. OMODE bits 1/2/4/8.
// DUAL: z in [8,16) = second job. FROB: per-tile sum((bf16 out)^2) -> part
// (job A only). VOUT: normal outputs get cd*D - val, transposed get val.
#define BMM_FRAGS(rs)                                                          \
  bf16x8 a[2], b[2], al2[2], bl2[2];                                           \
  _Pragma("unroll")                                                            \
  for (int i = 0; i < 2; ++i) {                                                \
    const int fr = wr * 32 + i * 16 + c15;                                     \
    const int ia = (rs) * 2048 + fr * 32 + ((lk ^ (fr & 3)) * 8);              \
    a[i] = *reinterpret_cast<const bf16x8*>(&sA[ia]);                          \
    if constexpr (PROD3) al2[i] = *reinterpret_cast<const bf16x8*>(&sAl[ia]);  \
  }                                                                            \
  _Pragma("unroll")                                                            \
  for (int j = 0; j < 2; ++j) {                                                \
    const int fc = wc * 32 + j * 16 + c15;                                     \
    const int ib = (rs) * 2048 + fc * 32 + ((lk ^ (fc & 3)) * 8);              \
    b[j] = *reinterpret_cast<const bf16x8*>(&sB[ib]);                          \
    if constexpr (PROD3) bl2[j] = *reinterpret_cast<const bf16x8*>(&sBl[ib]);  \
  }                                                                            \
  _Pragma("unroll")                                                            \
  for (int i = 0; i < 2; ++i)                                                  \
    _Pragma("unroll")                                                          \
    for (int j = 0; j < 2; ++j) {                                              \
      acc[i][j] = __builtin_amdgcn_mfma_f32_16x16x32_bf16(a[i], b[j], acc[i][j], 0, 0, 0); \
      if constexpr (PROD3) {                                                   \
        acc[i][j] = __builtin_amdgcn_mfma_f32_16x16x32_bf16(a[i],   bl2[j], acc[i][j], 0, 0, 0); \
        acc[i][j] = __builtin_amdgcn_mfma_f32_16x16x32_bf16(al2[i], b[j],   acc[i][j], 0, 0, 0); \
      }                                                                        \
    }

#define BMM_WAIT(SEL)                                                          \
  if ((SEL) == 0) {                                                            \
    if constexpr (PROD3) asm volatile("s_waitcnt vmcnt(12)" ::: "memory");     \
    else                 asm volatile("s_waitcnt vmcnt(6)" ::: "memory");      \
  } else if ((SEL) == 1) {                                                     \
    if constexpr (PROD3) asm volatile("s_waitcnt vmcnt(8)" ::: "memory");      \
    else                 asm volatile("s_waitcnt vmcnt(4)" ::: "memory");      \
  } else if ((SEL) == 2) {                                                     \
    if constexpr (PROD3) asm volatile("s_waitcnt vmcnt(4)" ::: "memory");      \
    else                 asm volatile("s_waitcnt vmcnt(2)" ::: "memory");      \
  } else {                                                                     \
    asm volatile("s_waitcnt vmcnt(0)" ::: "memory");                           \
  }

template <int PROD3, int DMODE, int OMODE, int DUAL, int FROB, int VOUT = 0>
__global__ __launch_bounds__(256)
void k_bmm(const u16* __restrict__ Ah, const u16* __restrict__ Al,
           const u16* __restrict__ Bh, const u16* __restrict__ Bl,
           const u16* __restrict__ Dh, const u16* __restrict__ Dl,
           u16* __restrict__ Cnh, u16* __restrict__ Cnl,
           u16* __restrict__ Cth, u16* __restrict__ Ctl,
           float cd, float cs,
           const float* __restrict__ cdp, const float* __restrict__ csp,
           const float* __restrict__ cvsrc, u16* __restrict__ cvdst, int zmm,
           const u16* __restrict__ A2, const u16* __restrict__ B2,
           const u16* __restrict__ D2, u16* __restrict__ C2,
           float* __restrict__ part) {
  __shared__ __align__(16) u16 sA[5 * 2048], sB[5 * 2048];
  __shared__ __align__(16) u16 sAl[PROD3 ? 5 * 2048 : 8];
  __shared__ __align__(16) u16 sBl[PROD3 ? 5 * 2048 : 8];
  __shared__ float fred[FROB ? 4 : 1];

  if ((int)blockIdx.z >= zmm) {   // conversion side-channel
    const int zi = ((int)blockIdx.z - zmm) * 64 + blockIdx.y * 8 + blockIdx.x;
    const int chunk = zi >> 7;                     // 128 blocks per 4M chunk
    const int base = (zi & 127) * 256 + (int)threadIdx.x;
    const float* src = cvsrc + (size_t)chunk * 4194304;
    u16* dst = cvdst + (size_t)chunk * 4194304;
#pragma unroll
    for (int e = 0; e < 16; ++e) {
      const size_t g = (size_t)(base + e * 32768) * 8;
      float4 f0 = *reinterpret_cast<const float4*>(src + g);
      float4 f1 = *reinterpret_cast<const float4*>(src + g + 4);
      u16x8 w;
      w[0] = f2bf(f0.x); w[1] = f2bf(f0.y); w[2] = f2bf(f0.z); w[3] = f2bf(f0.w);
      w[4] = f2bf(f1.x); w[5] = f2bf(f1.y); w[6] = f2bf(f1.z); w[7] = f2bf(f1.w);
      *reinterpret_cast<u16x8*>(dst + g) = w;
    }
    return;
  }

  const int zq = DUAL ? ((blockIdx.z >> 3) & 1) : 0;   // 0: job A, 1: job B
  const u16* Ah_ = (DUAL && zq) ? A2 : Ah;
  const u16* Bh_ = (DUAL && zq) ? B2 : Bh;
  const u16* Dh_ = (DUAL && zq) ? D2 : Dh;
  u16* Cnh_ = (DUAL && zq) ? C2 : Cnh;
  const size_t zb = (size_t)(blockIdx.z & 7) * 262144;
  const int tid = threadIdx.x, lane = tid & 63, wave = tid >> 6;
  const int m0 = blockIdx.y * 64, n0 = blockIdx.x * 64;
  const int wr = wave >> 1, wc = wave & 1;
  const int c15 = lane & 15, lk = lane >> 4;
  const int srow = tid >> 2;
  const int sg = (tid & 3) ^ (srow & 3);            // granule-XOR (involution)
  f32x4 acc[2][2] = {};
  const u16* pa = Ah_ + zb + (size_t)(m0 + srow) * 512 + sg * 8;
  const u16* pb = Bh_ + zb + (size_t)(n0 + srow) * 512 + sg * 8;
  const u16* pal = PROD3 ? Al + zb + (size_t)(m0 + srow) * 512 + sg * 8 : pa;
  const u16* pbl = PROD3 ? Bl + zb + (size_t)(n0 + srow) * 512 + sg * 8 : pb;

  int jn = 0, js = 0;
  auto STG = [&]() {
    if (jn < 16) {
      const int off = jn << 5;
      __builtin_amdgcn_global_load_lds((const AS1 void*)(pa + off),
                                       (AS3 void*)(sA + js * 2048 + tid * 8), 16, 0, 0);
      __builtin_amdgcn_global_load_lds((const AS1 void*)(pb + off),
                                       (AS3 void*)(sB + js * 2048 + tid * 8), 16, 0, 0);
      if constexpr (PROD3) {
        __builtin_amdgcn_global_load_lds((const AS1 void*)(pal + off),
                                         (AS3 void*)(sAl + js * 2048 + tid * 8), 16, 0, 0);
        __builtin_amdgcn_global_load_lds((const AS1 void*)(pbl + off),
                                         (AS3 void*)(sBl + js * 2048 + tid * 8), 16, 0, 0);
      }
    }
    ++jn; js = (js == 4) ? 0 : js + 1;
  };

  STG(); STG(); STG();          // prefetch steps 0,1,2 (lead 3)
  int rs = 0;
  for (int t = 0; t < 13; ++t) {
    STG();                      // stage step t+3
    BMM_WAIT(0)                 // step t landed (3 steps in flight)
    __builtin_amdgcn_s_barrier();
    BMM_FRAGS(rs)
    rs = (rs == 4) ? 0 : rs + 1;
  }
  STG();                        // t=13: no-op, 2 steps out
  BMM_WAIT(1)
  __builtin_amdgcn_s_barrier();
  { BMM_FRAGS(rs) }
  rs = (rs == 4) ? 0 : rs + 1;
  STG();                        // t=14: no-op, 1 step out
  BMM_WAIT(2)
  __builtin_amdgcn_s_barrier();
  { BMM_FRAGS(rs) }
  rs = (rs == 4) ? 0 : rs + 1;
  STG();                        // t=15: no-op, full drain
  BMM_WAIT(3)
  __builtin_amdgcn_s_barrier();
  { BMM_FRAGS(rs) }

  const float cdL = cdp ? cdp[blockIdx.z & 7] : cd;
  const float csL = csp ? csp[blockIdx.z & 7] : cs;
  float fs = 0.f;
  // epilogue (C/D map: col=lane&15, row=(lane>>4)*4+r)
#pragma unroll
  for (int i = 0; i < 2; ++i)
#pragma unroll
    for (int j = 0; j < 2; ++j) {
      const int rowb = m0 + wr * 32 + i * 16 + lk * 4;
      const int col  = n0 + wc * 32 + j * 16 + c15;
      u16 hv[4], lv[4];
#pragma unroll
      for (int r = 0; r < 4; ++r) {
        float val = csL * acc[i][j][r];
        float dv = 0.f;
        if constexpr (DMODE >= 1) {
          dv = bf2f(Dh_[zb + (size_t)(rowb + r) * 512 + col]);
          if constexpr (DMODE == 2) dv += bf2f(Dl[zb + (size_t)(rowb + r) * 512 + col]);
        }
        float nval, tval;
        if constexpr (VOUT) { tval = val; nval = cdL * dv - val; }
        else { nval = tval = val + cdL * dv; }
        u16 nh = f2bf(nval);
        if constexpr (OMODE & 1) Cnh_[zb + (size_t)(rowb + r) * 512 + col] = nh;
        if constexpr (FROB) { float v = bf2f(nh); fs += v * v; }
        if constexpr (OMODE & 2)
          Cnl[zb + (size_t)(rowb + r) * 512 + col] = f2bf(nval - bf2f(nh));
        if constexpr (OMODE & 12) {
          u16 th = f2bf(tval);
          hv[r] = th;
          if constexpr (OMODE & 8) lv[r] = f2bf(tval - bf2f(th));
        }
      }
      if constexpr (OMODE & 4) {
        u16x4 v; v[0] = hv[0]; v[1] = hv[1]; v[2] = hv[2]; v[3] = hv[3];
        *reinterpret_cast<u16x4*>(&Cth[zb + (size_t)col * 512 + rowb]) = v;
      }
      if constexpr (OMODE & 8) {
        u16x4 v; v[0] = lv[0]; v[1] = lv[1]; v[2] = lv[2]; v[3] = lv[3];
        *reinterpret_cast<u16x4*>(&Ctl[zb + (size_t)col * 512 + rowb]) = v;
      }
    }
  if constexpr (FROB) {
    for (int off = 32; off; off >>= 1) fs += __shfl_down(fs, off, 64);
    if ((tid & 63) == 0) fred[tid >> 6] = fs;
    __syncthreads();
    if (tid == 0 && (int)blockIdx.z < 8)   // job A only
      part[(blockIdx.z & 7) * 64 + blockIdx.y * 8 + blockIdx.x] =
          fred[0] + fred[1] + fred[2] + fred[3];
  }
}

// ---------------- tw = W_bf @ blockdiag(Q)  (B = Qt, 5-slot ring) -----------
__global__ __launch_bounds__(256)
void k_twmm(const u16* __restrict__ W, const u16* __restrict__ Qt,
            u16* __restrict__ tw) {
  __shared__ __align__(16) u16 sA[5 * 2048], sB[5 * 2048];
  const int z = blockIdx.z;
  const size_t zb = (size_t)z * 262144;
  const int tid = threadIdx.x, lane = tid & 63, wave = tid >> 6;
  const int m0 = blockIdx.y * 64, n0 = blockIdx.x * 64;
  const int wr = wave >> 1, wc = wave & 1;
  const int c15 = lane & 15, lk = lane >> 4;
  const int srow = tid >> 2;
  const int sg = (tid & 3) ^ (srow & 3);
  f32x4 acc[2][2] = {};
  const u16* pa = W + (size_t)(m0 + srow) * 4096 + z * 512 + sg * 8;
  const u16* pb = Qt + zb + (size_t)(n0 + srow) * 512 + sg * 8;

  int jn = 0, js = 0;
  auto STG = [&]() {
    if (jn < 16) {
      const int off = jn << 5;
      __builtin_amdgcn_global_load_lds((const AS1 void*)(pa + off),
                                       (AS3 void*)(sA + js * 2048 + tid * 8), 16, 0, 0);
      __builtin_amdgcn_global_load_lds((const AS1 void*)(pb + off),
                                       (AS3 void*)(sB + js * 2048 + tid * 8), 16, 0, 0);
    }
    ++jn; js = (js == 4) ? 0 : js + 1;
  };

#define TW_FRAGS(rs)                                                           \
  {                                                                            \
    bf16x8 a[2], b[2];                                                         \
    _Pragma("unroll")                                                          \
    for (int i = 0; i < 2; ++i) {                                              \
      const int fr = wr * 32 + i * 16 + c15;                                   \
      a[i] = *reinterpret_cast<const bf16x8*>(                                 \
          &sA[(rs) * 2048 + fr * 32 + ((lk ^ (fr & 3)) * 8)]);                 \
    }                                                                          \
    _Pragma("unroll")                                                          \
    for (int j = 0; j < 2; ++j) {                                              \
      const int fc = wc * 32 + j * 16 + c15;                                   \
      b[j] = *reinterpret_cast<const bf16x8*>(                                 \
          &sB[(rs) * 2048 + fc * 32 + ((lk ^ (fc & 3)) * 8)]);                 \
    }                                                                          \
    _Pragma("unroll")                                                          \
    for (int i = 0; i < 2; ++i)                                                \
      _Pragma("unroll")                                                        \
      for (int j = 0; j < 2; ++j)                                              \
        acc[i][j] = __builtin_amdgcn_mfma_f32_16x16x32_bf16(a[i], b[j], acc[i][j], 0, 0, 0); \
  }

  STG(); STG(); STG();
  int rs = 0;
  for (int t = 0; t < 13; ++t) {
    STG();
    asm volatile("s_waitcnt vmcnt(6)" ::: "memory");
    __builtin_amdgcn_s_barrier();
    TW_FRAGS(rs)
    rs = (rs == 4) ? 0 : rs + 1;
  }
  STG();
  asm volatile("s_waitcnt vmcnt(4)" ::: "memory");
  __builtin_amdgcn_s_barrier();
  TW_FRAGS(rs)
  rs = (rs == 4) ? 0 : rs + 1;
  STG();
  asm volatile("s_waitcnt vmcnt(2)" ::: "memory");
  __builtin_amdgcn_s_barrier();
  TW_FRAGS(rs)
  rs = (rs == 4) ? 0 : rs + 1;
  STG();
  asm volatile("s_waitcnt vmcnt(0)" ::: "memory");
  __builtin_amdgcn_s_barrier();
  TW_FRAGS(rs)

#pragma unroll
  for (int i = 0; i < 2; ++i)
#pragma unroll
    for (int j = 0; j < 2; ++j) {
      const int rowb = m0 + wr * 32 + i * 16 + lk * 4;
      const int col  = z * 512 + n0 + wc * 32 + j * 16 + c15;
#pragma unroll
      for (int r = 0; r < 4; ++r)
        tw[(size_t)(rowb + r) * 4096 + col] = f2bf(acc[i][j][r]);
    }
}

// ---------------- out = x_bf @ tw^T + bias (round-6, verbatim) --------------
#define NSL 18

#define RD_A3(dst, MH)                                                         \
  _Pragma("unroll")                                                            \
  for (int m = 0; m < 4; ++m)                                                  \
    dst[m] = *reinterpret_cast<const bf16x8*>(                                 \
        &lds[aslot * 4096 + ((MH) * 64 + m * 16 + c15) * 32 + gsw * 8]);

#define RD_B3(dst)                                                             \
  _Pragma("unroll")                                                            \
  for (int n = 0; n < 4; ++n)                                                  \
    dst[n] = *reinterpret_cast<const bf16x8*>(                                 \
        &lds[bslot * 4096 + (bq64 + n * 16 + c15) * 32 + gsw * 8]);

#define MFMA16(afX, bfX, MH)                                                   \
  __builtin_amdgcn_s_setprio(1);                                               \
  _Pragma("unroll")                                                            \
  for (int m = 0; m < 4; ++m)                                                  \
    _Pragma("unroll")                                                          \
    for (int n = 0; n < 4; ++n)                                                \
      acc[(MH) * 4 + m][n] = __builtin_amdgcn_mfma_f32_16x16x32_bf16(          \
          afX[m], bfX[n], acc[(MH) * 4 + m][n], 0, 0, 0);                      \
  __builtin_amdgcn_s_setprio(0);

// WM: 1 steady vmcnt(8) | 2 vmcnt(4) | 3 vmcnt(0) | 0 none (last tile)
#define TILE32(WM)                                                             \
  {                                                                            \
    int aslot = s0 + wr;            if (aslot >= NSL) aslot -= NSL;            \
    int bslot = s0 + 2 + (wc >> 1); if (bslot >= NSL) bslot -= NSL;            \
    STAGE(); STAGE();                                                          \
    RD_B3(bfr)                                                                 \
    RD_A3(afA, 0)                                                              \
    MFMA16(afA, bfr, 0)                                                        \
    STAGE(); STAGE();                                                          \
    RD_A3(afB, 1)                                                              \
    MFMA16(afB, bfr, 1)                                                        \
    if ((WM) == 1) asm volatile("s_waitcnt vmcnt(8)" ::: "memory");            \
    if ((WM) == 2) asm volatile("s_waitcnt vmcnt(4)" ::: "memory");            \
    if ((WM) == 3) asm volatile("s_waitcnt vmcnt(0)" ::: "memory");            \
    if ((WM) != 0) {                                                           \
      __builtin_amdgcn_s_barrier();                                            \
      __builtin_amdgcn_sched_barrier(0);                                       \
    }                                                                          \
    s0 += 4; if (s0 >= NSL) s0 -= NSL;                                         \
  }

__global__ __launch_bounds__(512, 2)
void k_gemm256(const u16* __restrict__ A, const u16* __restrict__ B,
               const float* __restrict__ bias,
               float* __restrict__ C, int N, int K) {
  __shared__ __align__(16) u16 lds[NSL * 4096];   // 144 KiB
  const int tid = threadIdx.x, lane = tid & 63, wave = tid >> 6;
  int bid = blockIdx.y * gridDim.x + blockIdx.x;
  const int cpx = (gridDim.x * gridDim.y) >> 3;
  bid = (bid & 7) * cpx + (bid >> 3);
  const int nbx = N >> 8;
  const int bx = bid % nbx, by = bid / nbx;
  const int m0 = by << 8, n0 = bx << 8;
  const int wr = wave >> 2, wc = wave & 3;          // 2 x 4 wave grid
  const int srow = tid >> 2;
  const int sgc  = (tid & 3) ^ ((srow >> 1) & 3);
  const int c15 = lane & 15, lq = lane >> 4;
  const int gsw = lq ^ ((c15 >> 1) & 3);
  const int bq64 = (wc & 1) * 64;
  const int NT = K >> 5;                            // 128

  f32x4 acc[8][4] = {};
  bf16x8 afA[4], afB[4], bfr[4];

  int jn = 0, js = 0;
  auto STAGE = [&]() {
    if (jn < 4 * NT) {
      const int t = jn >> 2, q = jn & 3;
      const u16* srcb = (q < 2)
          ? A + (size_t)(m0 + q * 128 + srow) * (size_t)K
          : B + (size_t)(n0 + (q - 2) * 128 + srow) * (size_t)K;
      const u16* src = srcb + (t << 5) + sgc * 8;
      u16* dst = (u16*)lds + js * 4096 + tid * 8;
      __builtin_amdgcn_global_load_lds(
          (const AS1 void*)src, (AS3 void*)dst, 16, 0, 0);
    }
    ++jn; js = (js == NSL - 1) ? 0 : js + 1;
  };

#pragma unroll
  for (int i = 0; i < 12; ++i) STAGE();
  asm volatile("s_waitcnt vmcnt(8)" ::: "memory");
  __builtin_amdgcn_s_barrier();
  __builtin_amdgcn_sched_barrier(0);

  int s0 = 0;
  for (int tau = 0; tau < NT - 3; ++tau) {
    TILE32(1)
  }
  TILE32(2)
  TILE32(3)
  TILE32(0)

#pragma unroll
  for (int n = 0; n < 4; ++n) {
    const int col = n0 + wc * 64 + n * 16 + c15;
    const float bv = bias[col];
#pragma unroll
    for (int mi = 0; mi < 8; ++mi) {
      const int rowb = m0 + wr * 128 + mi * 16 + (lq << 2);
#pragma unroll
      for (int r = 0; r < 4; ++r)
        C[(size_t)(rowb + r) * N + col] = acc[mi][n][r] + bv;
    }
  }
}

extern "C" void kernel_launch(void* const* d_in, const int* in_sizes, int n_in,
                              void* d_out, int out_size, void* d_ws, size_t ws_size,
                              hipStream_t stream) {
  const float* W    = (const float*)d_in[0];   // [4096,4096]
  const float* bias = (const float*)d_in[1];   // [4096]
  const float* x    = (const float*)d_in[2];   // [4,2048,4096]
  const float* R    = (const float*)d_in[3];   // [8,512,512]
  float* out = (float*)d_out;

  char* ws = (char*)d_ws;
  u16* x_bf = (u16*)(ws);                      //  64 MiB
  u16* tw   = (u16*)(ws + 67108864);           //  32 MiB
  u16* W_bf = (u16*)(ws + 100663296);          //  32 MiB

  // scratch arena = d_out (128 MiB; fully overwritten by k_gemm256)
  char* arena = (char*)d_out;
  auto slot = [&](int i) -> u16* { return (u16*)(arena + (size_t)i * 4194304); };
  u16 *Mh = slot(0), *Ml = slot(1);
  u16 *G = slot(2), *G2 = slot(3), *H = slot(4);
  u16 *T2 = slot(6), *X1 = slot(7), *X2 = slot(8), *T3 = slot(9);
  u16 *X3h = slot(10), *X3l = slot(11), *X3th = slot(12), *X3tl = slot(13);
  u16 *Tpth = slot(14), *Tptl = slot(15);
  u16 *Vh = slot(16), *Vl = slot(17);
  u16 *Qt = slot(20);
  float* coef = (float*)(arena + (size_t)21 * 4194304);   // 72 floats
  float* part = coef + 1024;                              // 512 floats

  const u16* NUL = nullptr;
  const float* NULF = nullptr;
  u16* NULW = nullptr;
  float* NULP = nullptr;
  const dim3 gC2(8, 8, 12);     // 8 mm + 4 conv planes (2 chunks)
  const dim3 gD2(8, 8, 20);     // 16 mm (DUAL) + 4 conv planes (2 chunks)

  // 1) M pair
  k_build_M<<<dim3(16, 16, 8), 256, 0, stream>>>(R, Mh, Ml);
  // 2) G = M@M^T (+ W chunks 0,1)
  k_bmm<0, 0, 1, 0, 0><<<gC2, 256, 0, stream>>>(Mh, NUL, Mh, NUL, NUL, NUL,
      G, NULW, NULW, NULW, 0.f, 1.f, NULF, NULF, W, W_bf, 8,
      NUL, NUL, NUL, NULW, NULP);
  // 3) DUAL: G2 = G@G (+frob partials)  ||  H = M@G   (+ W chunks 2,3)
  k_bmm<0, 0, 1, 1, 1><<<gD2, 256, 0, stream>>>(G, NUL, G, NUL, NUL, NUL,
      G2, NULW, NULW, NULW, 0.f, 1.f, NULF, NULF,
      W + (size_t)2 * 4194304, W_bf + (size_t)2 * 4194304, 16,
      Mh, G, NUL, H, part);
  // 4) coefficients ; X1 (elementwise: g0 I + g1 M + g2 G + g3 H) + T2
  k_init<<<1024, 256, 0, stream>>>(Mh, Ml, G, G2, H, part, coef, X1, T2);
  // 5) DUAL: X2 = 2c2*X1 - c2*(X1@T2)  ||  T3 = 2c2*T2 - c2*(T2@T2)
  //    (+ x chunks 0,1)
  k_bmm<0, 1, 1, 1, 0><<<gD2, 256, 0, stream>>>(X1, NUL, T2, NUL, X1, NUL,
      X2, NULW, NULW, NULW, 0.f, 0.f, coef + 40, coef + 48,
      x, x_bf, 16, T2, T2, T2, T3, NULP);
  // 6) X3 = 2c3*X2 - c3*(X2@T3), pairs + transposed pairs  (+ x chunks 2,3)
  k_bmm<0, 1, 15, 0, 0><<<gC2, 256, 0, stream>>>(X2, NUL, T3, NUL, X2, NUL,
      X3h, X3l, X3th, X3tl, 0.f, 0.f, coef + 56, coef + 64,
      x + (size_t)2 * 4194304, x_bf + (size_t)2 * 4194304, 8,
      NUL, NUL, NUL, NULW, NULP);
  // 7) VOUT: Tp^T = (M@X3)^T pairs  AND  V = C1Q*X3 - Tp pairs
  //    (+ x chunks 4,5)
  k_bmm<1, 2, 15, 0, 0, 1><<<gC2, 256, 0, stream>>>(Mh, Ml, X3th, X3tl,
      X3h, X3l, Vh, Vl, Tpth, Tptl, C1Q, 1.f, NULF, NULF,
      x + (size_t)4 * 4194304, x_bf + (size_t)4 * 4194304, 8,
      NUL, NUL, NUL, NULW, NULP);
  // 8) Q^T = transpose of (2V - V@Tp)  (+ x chunks 6,7)
  k_bmm<1, 2, 4, 0, 0><<<gC2, 256, 0, stream>>>(Vh, Vl, Tpth, Tptl, Vh, Vl,
      NULW, NULW, Qt, NULW, 2.f, -1.f, NULF, NULF,
      x + (size_t)6 * 4194304, x_bf + (size_t)6 * 4194304, 8,
      NUL, NUL, NUL, NULW, NULP);
  // 9) tw = W_bf @ blockdiag(Q) ; main GEMM (overwrites the arena)
  k_twmm<<<dim3(8, 64, 8), 256, 0, stream>>>(W_bf, Qt, tw);
  k_gemm256<<<dim3(16, 32), 512, 0, stream>>>(x_bf, tw, bias, out, 4096, 4096);
}